// Round 1
// baseline (8602.058 us; speedup 1.0000x reference)
//
#include <hip/hip_runtime.h>
#include <math.h>

// Problem dims
constexpr int S_   = 70;
constexpr int B_   = 16;
constexpr int SB_  = 1120;     // S*B
constexpr int NT_  = 32000;    // NTOKEN
constexpr int W1S_ = 32001;    // odeW1 row stride (NTOKEN+1)
constexpr int DHP_ = 1152;     // padded hidden row count for transposed buffers

__device__ __forceinline__ float sigm(float x){ return 1.f/(1.f+__expf(-x)); }
__device__ __forceinline__ float softplusf(float x){ return x > 15.f ? x : log1pf(__expf(x)); }

// ---------------------------------------------------------------------------
// Embedding gather, transposed: x0T[t][d][b] = emb[tok[t,b]][d]
__global__ __launch_bounds__(256) void embed_k(const int* __restrict__ tok,
                                               const float* __restrict__ emb,
                                               float* __restrict__ x0T)
{
    int t = blockIdx.x;
    __shared__ int tk[16];
    if (threadIdx.x < 16) tk[threadIdx.x] = tok[t*16 + threadIdx.x];
    __syncthreads();
    for (int idx = threadIdx.x; idx < 400*16; idx += 256){
        int b = idx / 400, d = idx - b*400;
        x0T[t*6400 + d*16 + b] = emb[(size_t)tk[b]*400 + d];
    }
}

// dst[j*16+b] = src[b*dh+j]
__global__ __launch_bounds__(256) void transpose16_k(const float* __restrict__ src,
                                                     float* __restrict__ dst, int dh)
{
    int idx = blockIdx.x*256 + threadIdx.x;
    if (idx < dh*16){ int j = idx >> 4, b = idx & 15; dst[idx] = src[b*dh + j]; }
}

// ---------------------------------------------------------------------------
// One wavefront step of the 3-layer LSTM pipeline.
// Wave = one hidden unit j of one layer; lane = (g = k-cohort 0..3, b = batch 0..15).
__device__ __forceinline__ void dot4(const float* __restrict__ W, int Dh, int j, int K,
                                     const float* __restrict__ VT, int b, int g,
                                     float& a0, float& a1, float& a2, float& a3)
{
    const float* w0 = W + (size_t)(0*Dh + j)*K;
    const float* w1 = W + (size_t)(1*Dh + j)*K;
    const float* w2 = W + (size_t)(2*Dh + j)*K;
    const float* w3 = W + (size_t)(3*Dh + j)*K;
    int k4max = K >> 2;
    for (int k4 = g; k4 < k4max; k4 += 4){
        int d = k4 << 2;
        float v0 = VT[(d+0)*16+b], v1 = VT[(d+1)*16+b];
        float v2 = VT[(d+2)*16+b], v3 = VT[(d+3)*16+b];
        a0 += w0[d]*v0 + w0[d+1]*v1 + w0[d+2]*v2 + w0[d+3]*v3;
        a1 += w1[d]*v0 + w1[d+1]*v1 + w1[d+2]*v2 + w1[d+3]*v3;
        a2 += w2[d]*v0 + w2[d+1]*v1 + w2[d+2]*v2 + w2[d+3]*v3;
        a3 += w3[d]*v0 + w3[d+1]*v1 + w3[d+2]*v2 + w3[d+3]*v3;
    }
    int dt_ = (k4max << 2) + g;
    if (dt_ < K){
        float v = VT[dt_*16+b];
        a0 += w0[dt_]*v; a1 += w1[dt_]*v; a2 += w2[dt_]*v; a3 += w3[dt_]*v;
    }
}

__global__ __launch_bounds__(256) void lstm_step_k(int u,
    const float* __restrict__ x0T, float* __restrict__ ys0T, float* __restrict__ ys1T,
    float* __restrict__ x3,
    float* __restrict__ hT0, float* __restrict__ cT0,
    float* __restrict__ hT1, float* __restrict__ cT1,
    float* __restrict__ hT2, float* __restrict__ cT2,
    const float* __restrict__ Wih0, const float* __restrict__ Whh0,
    const float* __restrict__ bih0, const float* __restrict__ bhh0,
    const float* __restrict__ Wih1, const float* __restrict__ Whh1,
    const float* __restrict__ bih1, const float* __restrict__ bhh1,
    const float* __restrict__ Wih2, const float* __restrict__ Whh2,
    const float* __restrict__ bih2, const float* __restrict__ bhh2)
{
    int blk = blockIdx.x;
    int layer, jb;
    if      (blk < 288){ layer = 0; jb = blk*4; }
    else if (blk < 576){ layer = 1; jb = (blk-288)*4; }
    else               { layer = 2; jb = (blk-576)*4; }
    int t = u - layer;
    if (t < 0 || t >= S_) return;

    int j    = jb + (threadIdx.x >> 6);
    int lane = threadIdx.x & 63;
    int b = lane & 15, g = lane >> 4;

    const float *xT, *Wih, *Whh, *bih, *bhh; float *hTb, *cTb;
    int Din, Dh;
    float* outT = nullptr; float* outP = nullptr;
    if (layer == 0){
        xT = x0T + t*(400*16); Din = 400;  Dh = 1150;
        Wih = Wih0; Whh = Whh0; bih = bih0; bhh = bhh0; hTb = hT0; cTb = cT0;
        outT = ys0T + (size_t)t*(DHP_*16);
    } else if (layer == 1){
        xT = ys0T + (size_t)t*(DHP_*16); Din = 1150; Dh = 1150;
        Wih = Wih1; Whh = Whh1; bih = bih1; bhh = bhh1; hTb = hT1; cTb = cT1;
        outT = ys1T + (size_t)t*(DHP_*16);
    } else {
        xT = ys1T + (size_t)t*(DHP_*16); Din = 1150; Dh = 400;
        Wih = Wih2; Whh = Whh2; bih = bih2; bhh = bhh2; hTb = hT2; cTb = cT2;
        outP = x3 + (size_t)t*16*400;
    }
    if (j >= Dh) return;

    const float* hRead  = hTb + (t & 1)     * (DHP_*16);
    float*       hWrite = hTb + ((t+1) & 1) * (DHP_*16);

    float a0 = 0.f, a1 = 0.f, a2 = 0.f, a3 = 0.f;
    dot4(Wih, Dh, j, Din, xT,    b, g, a0, a1, a2, a3);   // x @ Wih^T (folded)
    dot4(Whh, Dh, j, Dh,  hRead, b, g, a0, a1, a2, a3);   // h @ Whh^T

    a0 += __shfl_xor(a0, 16); a0 += __shfl_xor(a0, 32);
    a1 += __shfl_xor(a1, 16); a1 += __shfl_xor(a1, 32);
    a2 += __shfl_xor(a2, 16); a2 += __shfl_xor(a2, 32);
    a3 += __shfl_xor(a3, 16); a3 += __shfl_xor(a3, 32);

    float pi = a0 + bih[j]        + bhh[j];
    float pf = a1 + bih[Dh+j]     + bhh[Dh+j];
    float pg = a2 + bih[2*Dh+j]   + bhh[2*Dh+j];
    float po = a3 + bih[3*Dh+j]   + bhh[3*Dh+j];

    float cold = cTb[j*16+b];
    float cnew = sigm(pf)*cold + sigm(pi)*tanhf(pg);
    float h    = sigm(po)*tanhf(cnew);
    if (g == 0){
        cTb[j*16+b]    = cnew;
        hWrite[j*16+b] = h;
        if (outT) outT[j*16+b]    = h;
        if (outP) outP[b*400 + j] = h;
    }
}

// ---------------------------------------------------------------------------
// dvec[j] = Wx[j,:]·decb ; bvec[j] = Wx[j,:]·b2 ; wtd[j] = odeW1[j,0]
__global__ __launch_bounds__(256) void vecs_k(const float* __restrict__ odeW1,
                                              const float* __restrict__ decb,
                                              const float* __restrict__ b2v,
                                              float* __restrict__ dvec,
                                              float* __restrict__ bvec,
                                              float* __restrict__ wtd)
{
    int jrow = blockIdx.x;
    __shared__ float r1[256], r2[256];
    const float* wx = odeW1 + (size_t)jrow*W1S_ + 1;
    float s1 = 0.f, s2 = 0.f;
    for (int v = threadIdx.x; v < NT_; v += 256){
        float w = wx[v]; s1 += w*decb[v]; s2 += w*b2v[v];
    }
    r1[threadIdx.x] = s1; r2[threadIdx.x] = s2; __syncthreads();
    for (int s = 128; s > 0; s >>= 1){
        if (threadIdx.x < s){ r1[threadIdx.x] += r1[threadIdx.x+s]; r2[threadIdx.x] += r2[threadIdx.x+s]; }
        __syncthreads();
    }
    if (threadIdx.x == 0){ dvec[jrow] = r1[0]; bvec[jrow] = r2[0]; wtd[jrow] = odeW1[(size_t)jrow*W1S_]; }
}

// C_partial[slab][m,n] = sum_{v in slab} Wx[m,v]*B[v,n]   (M=N=400, K=32000, 16 slabs)
__global__ __launch_bounds__(256) void gemm_ode_k(const float* __restrict__ odeW1,
                                                  const float* __restrict__ Bm,
                                                  float* __restrict__ partials)
{
    __shared__ float As[16][68];
    __shared__ float Bs[16][68];
    int m0 = blockIdx.y*64, n0 = blockIdx.x*64;
    int v0 = blockIdx.z*2000;
    int tid = threadIdx.x, tx = tid & 15, ty = tid >> 4;
    int rowA = tid >> 2, kqA = tid & 3;
    int krB  = tid >> 4, n4B = tid & 15;
    float acc[4][4] = {};
    for (int kk = 0; kk < 2000; kk += 16){
        int m = m0 + rowA;
        if (m < 400){
            const float* ap = odeW1 + (size_t)m*W1S_ + 1 + v0 + kk + kqA*4;
            As[kqA*4+0][rowA] = ap[0]; As[kqA*4+1][rowA] = ap[1];
            As[kqA*4+2][rowA] = ap[2]; As[kqA*4+3][rowA] = ap[3];
        } else {
            As[kqA*4+0][rowA] = 0.f; As[kqA*4+1][rowA] = 0.f;
            As[kqA*4+2][rowA] = 0.f; As[kqA*4+3][rowA] = 0.f;
        }
        int v = v0 + kk + krB;
        int n = n0 + n4B*4;
        if (n < 400){
            float4 vb = *(const float4*)(Bm + (size_t)v*400 + n);
            Bs[krB][n4B*4+0] = vb.x; Bs[krB][n4B*4+1] = vb.y;
            Bs[krB][n4B*4+2] = vb.z; Bs[krB][n4B*4+3] = vb.w;
        } else {
            Bs[krB][n4B*4+0] = 0.f; Bs[krB][n4B*4+1] = 0.f;
            Bs[krB][n4B*4+2] = 0.f; Bs[krB][n4B*4+3] = 0.f;
        }
        __syncthreads();
        #pragma unroll
        for (int k = 0; k < 16; ++k){
            float4 a4 = *(const float4*)&As[k][tx*4];
            float4 b4 = *(const float4*)&Bs[k][ty*4];
            float av[4] = {a4.x,a4.y,a4.z,a4.w};
            float bv[4] = {b4.x,b4.y,b4.z,b4.w};
            #pragma unroll
            for (int i = 0; i < 4; ++i)
                #pragma unroll
                for (int jj = 0; jj < 4; ++jj) acc[i][jj] += av[i]*bv[jj];
        }
        __syncthreads();
    }
    float* outp = partials + (size_t)blockIdx.z*160000;
    #pragma unroll
    for (int i = 0; i < 4; ++i){
        int m = m0 + tx*4 + i; if (m >= 400) continue;
        #pragma unroll
        for (int jj = 0; jj < 4; ++jj){
            int n = n0 + ty*4 + jj; if (n >= 400) continue;
            outp[m*400 + n] = acc[i][jj];
        }
    }
}

__global__ __launch_bounds__(256) void reduce16_k(const float* __restrict__ p, float* __restrict__ out)
{
    int i = blockIdx.x*256 + threadIdx.x;
    if (i < 160000){
        float s = 0.f;
        #pragma unroll
        for (int k = 0; k < 16; ++k) s += p[k*160000 + i];
        out[i] = s;
    }
}

// ---------------------------------------------------------------------------
// OUT[m,n] = maybe_softplus( dotc*sum_k A[m,k]*B[n,k] + Gbase + vcoef*vec[n] + tval*wt[n] + b1[n] )
// M=1120, N=400, K=400 (NT layout: both K-contiguous)
__global__ __launch_bounds__(256) void fused_small_k(
    const float* __restrict__ A, const float* __restrict__ Bm,
    const float* __restrict__ Gbase, float* __restrict__ OUT,
    const float* __restrict__ vec, float vcoef,
    const float* __restrict__ wt, float tval,
    const float* __restrict__ b1, float dotc, int do_sp)
{
    __shared__ float As[16][68];
    __shared__ float Bs[16][68];
    int m0 = blockIdx.y*64, n0 = blockIdx.x*64;
    int tid = threadIdx.x, tx = tid & 15, ty = tid >> 4;
    int row = tid >> 2, kq = tid & 3;
    float acc[4][4] = {};
    for (int k0 = 0; k0 < 400; k0 += 16){
        int m = m0 + row;
        if (m < SB_){
            float4 va = *(const float4*)(A + (size_t)m*400 + k0 + kq*4);
            As[kq*4+0][row] = va.x; As[kq*4+1][row] = va.y;
            As[kq*4+2][row] = va.z; As[kq*4+3][row] = va.w;
        } else {
            As[kq*4+0][row] = 0.f; As[kq*4+1][row] = 0.f;
            As[kq*4+2][row] = 0.f; As[kq*4+3][row] = 0.f;
        }
        int n = n0 + row;
        if (n < 400){
            float4 vb = *(const float4*)(Bm + (size_t)n*400 + k0 + kq*4);
            Bs[kq*4+0][row] = vb.x; Bs[kq*4+1][row] = vb.y;
            Bs[kq*4+2][row] = vb.z; Bs[kq*4+3][row] = vb.w;
        } else {
            Bs[kq*4+0][row] = 0.f; Bs[kq*4+1][row] = 0.f;
            Bs[kq*4+2][row] = 0.f; Bs[kq*4+3][row] = 0.f;
        }
        __syncthreads();
        #pragma unroll
        for (int k = 0; k < 16; ++k){
            float4 a4 = *(const float4*)&As[k][tx*4];
            float4 b4 = *(const float4*)&Bs[k][ty*4];
            float av[4] = {a4.x,a4.y,a4.z,a4.w};
            float bv[4] = {b4.x,b4.y,b4.z,b4.w};
            #pragma unroll
            for (int i = 0; i < 4; ++i)
                #pragma unroll
                for (int jj = 0; jj < 4; ++jj) acc[i][jj] += av[i]*bv[jj];
        }
        __syncthreads();
    }
    #pragma unroll
    for (int i = 0; i < 4; ++i){
        int m = m0 + tx*4 + i; if (m >= SB_) continue;
        #pragma unroll
        for (int jj = 0; jj < 4; ++jj){
            int n = n0 + ty*4 + jj; if (n >= 400) continue;
            float s = dotc*acc[i][jj];
            if (Gbase) s += Gbase[(size_t)m*400 + n];
            if (vec)   s += vcoef*vec[n];
            if (wt)    s += tval*wt[n];
            if (b1)    s += b1[n];
            OUT[(size_t)m*400 + n] = do_sp ? softplusf(s) : s;
        }
    }
}

// H = softplus(Gy + t*wt + b1)   (elementwise, stage 1)
__global__ __launch_bounds__(256) void stage1_k(const float* __restrict__ Gy, float* __restrict__ H,
                                                const float* __restrict__ wt, float tval,
                                                const float* __restrict__ b1)
{
    int sb = blockIdx.x;
    for (int n = threadIdx.x; n < 400; n += 256){
        float s = Gy[(size_t)sb*400 + n] + tval*wt[n] + b1[n];
        H[(size_t)sb*400 + n] = softplusf(s);
    }
}

// Hs = dt/6*(H1+2H2+2H3+H4); Hacc += Hs
__global__ __launch_bounds__(256) void hs_k(const float* __restrict__ H1, const float* __restrict__ H2,
                                            const float* __restrict__ H3, const float* __restrict__ H4,
                                            float* __restrict__ Hs, float* __restrict__ Hacc, int n)
{
    int i = blockIdx.x*256 + threadIdx.x;
    if (i < n){
        float v = (1.f/12.f)*(H1[i] + 2.f*H2[i] + 2.f*H3[i] + H4[i]);  // dt/6 = 0.5/6
        Hs[i] = v;
        Hacc[i] += v;
    }
}

// ---------------------------------------------------------------------------
// z[m,v] = x3[m]·decW[v] + Hacc[m]·W2[v] + decb[v] + b2[v]    (M=1120, N=32000, K=2*400)
__global__ __launch_bounds__(256) void decode_k(
    const float* __restrict__ x3, const float* __restrict__ Hacc,
    const float* __restrict__ decW, const float* __restrict__ W2,
    const float* __restrict__ decb, const float* __restrict__ b2v,
    float* __restrict__ z)
{
    __shared__ float As[16][136];
    __shared__ float Bs[16][136];
    int n0 = blockIdx.x*128, m0 = blockIdx.y*128;
    int tid = threadIdx.x, tx = tid & 15, ty = tid >> 4;
    int rowL = tid >> 1, qL = tid & 1;
    float acc[8][8] = {};
    for (int ph = 0; ph < 2; ++ph){
        const float* A  = ph ? Hacc : x3;
        const float* Bw = ph ? W2   : decW;
        for (int k0 = 0; k0 < 400; k0 += 16){
            int m = m0 + rowL;
            if (m < SB_){
                const float* ap = A + (size_t)m*400 + k0 + qL*8;
                float4 u0 = *(const float4*)ap, u1 = *(const float4*)(ap+4);
                As[qL*8+0][rowL] = u0.x; As[qL*8+1][rowL] = u0.y;
                As[qL*8+2][rowL] = u0.z; As[qL*8+3][rowL] = u0.w;
                As[qL*8+4][rowL] = u1.x; As[qL*8+5][rowL] = u1.y;
                As[qL*8+6][rowL] = u1.z; As[qL*8+7][rowL] = u1.w;
            } else {
                #pragma unroll
                for (int i = 0; i < 8; ++i) As[qL*8+i][rowL] = 0.f;
            }
            {
                const float* bp = Bw + (size_t)(n0 + rowL)*400 + k0 + qL*8;  // n < 32000 always
                float4 w0 = *(const float4*)bp, w1 = *(const float4*)(bp+4);
                Bs[qL*8+0][rowL] = w0.x; Bs[qL*8+1][rowL] = w0.y;
                Bs[qL*8+2][rowL] = w0.z; Bs[qL*8+3][rowL] = w0.w;
                Bs[qL*8+4][rowL] = w1.x; Bs[qL*8+5][rowL] = w1.y;
                Bs[qL*8+6][rowL] = w1.z; Bs[qL*8+7][rowL] = w1.w;
            }
            __syncthreads();
            #pragma unroll
            for (int k = 0; k < 16; ++k){
                float a[8], bq[8];
                *(float4*)&a[0]  = *(const float4*)&As[k][tx*8];
                *(float4*)&a[4]  = *(const float4*)&As[k][tx*8+4];
                *(float4*)&bq[0] = *(const float4*)&Bs[k][ty*8];
                *(float4*)&bq[4] = *(const float4*)&Bs[k][ty*8+4];
                #pragma unroll
                for (int i = 0; i < 8; ++i)
                    #pragma unroll
                    for (int jj = 0; jj < 8; ++jj) acc[i][jj] += a[i]*bq[jj];
            }
            __syncthreads();
        }
    }
    float db[8];
    #pragma unroll
    for (int jj = 0; jj < 8; ++jj){
        int n = n0 + ty*8 + jj;
        db[jj] = decb[n] + b2v[n];
    }
    #pragma unroll
    for (int i = 0; i < 8; ++i){
        int m = m0 + tx*8 + i;
        if (m >= SB_) continue;
        float* zrow = z + (size_t)m*NT_;
        #pragma unroll
        for (int jj = 0; jj < 8; ++jj){
            int n = n0 + ty*8 + jj;
            zrow[n] = acc[i][jj] + db[jj];
        }
    }
}

// per-row max and sum(exp(z-max))
__global__ __launch_bounds__(256) void rowred_k(const float* __restrict__ z,
                                                float* __restrict__ rowm, float* __restrict__ rowsum)
{
    int r = blockIdx.x;
    const float* zr = z + (size_t)r*NT_;
    __shared__ float sm[256];
    float m = -1e30f;
    for (int v = threadIdx.x; v < NT_; v += 256) m = fmaxf(m, zr[v]);
    sm[threadIdx.x] = m; __syncthreads();
    for (int s = 128; s > 0; s >>= 1){
        if (threadIdx.x < s) sm[threadIdx.x] = fmaxf(sm[threadIdx.x], sm[threadIdx.x+s]);
        __syncthreads();
    }
    m = sm[0]; __syncthreads();
    float s = 0.f;
    for (int v = threadIdx.x; v < NT_; v += 256) s += __expf(zr[v] - m);
    sm[threadIdx.x] = s; __syncthreads();
    for (int st = 128; st > 0; st >>= 1){
        if (threadIdx.x < st) sm[threadIdx.x] += sm[threadIdx.x+st];
        __syncthreads();
    }
    if (threadIdx.x == 0){ rowm[r] = m; rowsum[r] = sm[0]; }
}

// out = log(exp(z-m)/S + 1e-8), in place
__global__ __launch_bounds__(256) void finalmap_k(float* __restrict__ z,
                                                  const float* __restrict__ rowm,
                                                  const float* __restrict__ rowsum)
{
    int r = blockIdx.y;
    int v = (blockIdx.x*256 + threadIdx.x)*4;
    if (v >= NT_) return;
    float m = rowm[r];
    float sinv = 1.f/rowsum[r];
    float4* p = (float4*)(z + (size_t)r*NT_ + v);
    float4 x = *p;
    x.x = logf(__expf(x.x - m)*sinv + 1e-8f);
    x.y = logf(__expf(x.y - m)*sinv + 1e-8f);
    x.z = logf(__expf(x.z - m)*sinv + 1e-8f);
    x.w = logf(__expf(x.w - m)*sinv + 1e-8f);
    *p = x;
}

// ---------------------------------------------------------------------------
extern "C" void kernel_launch(void* const* d_in, const int* in_sizes, int n_in,
                              void* d_out, int out_size, void* d_ws, size_t ws_size,
                              hipStream_t stream)
{
    const int*   tokens = (const int*)  d_in[0];
    const float* h0_0 = (const float*)d_in[1];
    const float* c0_0 = (const float*)d_in[2];
    const float* Wih0 = (const float*)d_in[3];
    const float* Whh0 = (const float*)d_in[4];
    const float* bih0 = (const float*)d_in[5];
    const float* bhh0 = (const float*)d_in[6];
    const float* h0_1 = (const float*)d_in[7];
    const float* c0_1 = (const float*)d_in[8];
    const float* Wih1 = (const float*)d_in[9];
    const float* Whh1 = (const float*)d_in[10];
    const float* bih1 = (const float*)d_in[11];
    const float* bhh1 = (const float*)d_in[12];
    const float* h0_2 = (const float*)d_in[13];
    const float* c0_2 = (const float*)d_in[14];
    const float* Wih2 = (const float*)d_in[15];
    const float* Whh2 = (const float*)d_in[16];
    const float* bih2 = (const float*)d_in[17];
    const float* bhh2 = (const float*)d_in[18];
    const float* emb  = (const float*)d_in[19];
    const float* decW = (const float*)d_in[20];
    const float* decb = (const float*)d_in[21];
    const float* odeW1= (const float*)d_in[22];
    const float* odeb1= (const float*)d_in[23];
    const float* odeW2= (const float*)d_in[24];
    const float* odeb2= (const float*)d_in[25];

    // workspace carve-up (~39 MB total, all 64B-aligned chunks)
    float* w = (float*)d_ws;
    size_t off = 0;
    auto alloc = [&](size_t n){ float* p = w + off; off += n; return p; };
    float* x0T  = alloc((size_t)S_*400*16);
    float* ys0T = alloc((size_t)S_*DHP_*16);
    float* ys1T = alloc((size_t)S_*DHP_*16);
    float* x3   = alloc((size_t)SB_*400);
    float* hT0  = alloc(2*DHP_*16); float* cT0 = alloc(DHP_*16);
    float* hT1  = alloc(2*DHP_*16); float* cT1 = alloc(DHP_*16);
    float* hT2  = alloc(2*DHP_*16); float* cT2 = alloc(DHP_*16);
    float* P    = alloc(160000);
    float* Q    = alloc(160000);
    float* dvec = alloc(512);
    float* bvec = alloc(512);
    float* wtd  = alloc(512);
    float* Gy   = alloc((size_t)SB_*400);
    float* Hacc = alloc((size_t)SB_*400);
    float* H1   = alloc((size_t)SB_*400);
    float* H2   = alloc((size_t)SB_*400);
    float* H3   = alloc((size_t)SB_*400);
    float* H4   = alloc((size_t)SB_*400);
    float* Hs   = alloc((size_t)SB_*400);
    float* rowm = alloc(1280);
    float* rsum = alloc(1280);
    float* partials = alloc((size_t)16*160000);
    (void)ws_size; (void)in_sizes; (void)n_in; (void)out_size;

    float* zout = (float*)d_out;

    hipMemsetAsync(Hacc, 0, (size_t)SB_*400*sizeof(float), stream);

    // embed + state init
    embed_k<<<S_, 256, 0, stream>>>(tokens, emb, x0T);
    transpose16_k<<<(1150*16+255)/256, 256, 0, stream>>>(h0_0, hT0, 1150);
    transpose16_k<<<(1150*16+255)/256, 256, 0, stream>>>(c0_0, cT0, 1150);
    transpose16_k<<<(1150*16+255)/256, 256, 0, stream>>>(h0_1, hT1, 1150);
    transpose16_k<<<(1150*16+255)/256, 256, 0, stream>>>(c0_1, cT1, 1150);
    transpose16_k<<<(400*16+255)/256, 256, 0, stream>>>(h0_2, hT2, 400);
    transpose16_k<<<(400*16+255)/256, 256, 0, stream>>>(c0_2, cT2, 400);

    // 3-layer LSTM, layer-pipelined wavefront
    for (int u = 0; u < S_ + 2; ++u)
        lstm_step_k<<<676, 256, 0, stream>>>(u, x0T, ys0T, ys1T, x3,
            hT0, cT0, hT1, cT1, hT2, cT2,
            Wih0, Whh0, bih0, bhh0, Wih1, Whh1, bih1, bhh1, Wih2, Whh2, bih2, bhh2);

    // ODE factorization precompute: P = Wx@W2, Q = Wx@decW, vecs
    vecs_k<<<400, 256, 0, stream>>>(odeW1, decb, odeb2, dvec, bvec, wtd);
    gemm_ode_k<<<dim3(7,7,16), 256, 0, stream>>>(odeW1, odeW2, partials);
    reduce16_k<<<(160000+255)/256, 256, 0, stream>>>(partials, P);
    gemm_ode_k<<<dim3(7,7,16), 256, 0, stream>>>(odeW1, decW, partials);
    reduce16_k<<<(160000+255)/256, 256, 0, stream>>>(partials, Q);

    // G0 = x3 @ Q^T + dvec
    fused_small_k<<<dim3(7,18), 256, 0, stream>>>(x3, Q, nullptr, Gy,
        dvec, 1.f, nullptr, 0.f, nullptr, 1.f, 0);

    // RK4 in G-space, 2 steps, dt = 0.5
    const float dt = 0.5f;
    for (int n = 0; n < 2; ++n){
        float t0 = n * dt;
        stage1_k<<<SB_, 256, 0, stream>>>(Gy, H1, wtd, t0, odeb1);
        fused_small_k<<<dim3(7,18), 256, 0, stream>>>(H1, P, Gy, H2,
            bvec, 0.25f, wtd, t0 + 0.25f, odeb1, 0.25f, 1);
        fused_small_k<<<dim3(7,18), 256, 0, stream>>>(H2, P, Gy, H3,
            bvec, 0.25f, wtd, t0 + 0.25f, odeb1, 0.25f, 1);
        fused_small_k<<<dim3(7,18), 256, 0, stream>>>(H3, P, Gy, H4,
            bvec, 0.5f, wtd, t0 + 0.5f, odeb1, 0.5f, 1);
        hs_k<<<((SB_*400)+255)/256, 256, 0, stream>>>(H1, H2, H3, H4, Hs, Hacc, SB_*400);
        if (n == 0)
            fused_small_k<<<dim3(7,18), 256, 0, stream>>>(Hs, P, Gy, Gy,
                bvec, dt, nullptr, 0.f, nullptr, 1.f, 0);
    }

    // fused logits + ODE delta, then log-softmax(+1e-8) in place on d_out
    decode_k<<<dim3(250,9), 256, 0, stream>>>(x3, Hacc, decW, odeW2, decb, odeb2, zout);
    rowred_k<<<SB_, 256, 0, stream>>>(zout, rowm, rsum);
    finalmap_k<<<dim3(32,SB_), 256, 0, stream>>>(zout, rowm, rsum);
}

// Round 2
// 4050.459 us; speedup vs baseline: 2.1237x; 2.1237x over previous
//
#include <hip/hip_runtime.h>
#include <math.h>

// Problem dims
constexpr int S_   = 70;
constexpr int B_   = 16;
constexpr int SB_  = 1120;     // S*B
constexpr int NT_  = 32000;    // NTOKEN
constexpr int W1S_ = 32001;    // odeW1 row stride (NTOKEN+1)
constexpr int DHP_ = 1152;     // padded hidden row count for transposed buffers

typedef __attribute__((ext_vector_type(8))) short bf16x8;
typedef __attribute__((ext_vector_type(4))) float f32x4;

__device__ __forceinline__ float sigm(float x){ return 1.f/(1.f+__expf(-x)); }
__device__ __forceinline__ float softplusf(float x){ return x > 15.f ? x : log1pf(__expf(x)); }

__device__ __forceinline__ unsigned short f2bf(float f){
    union{float f; unsigned u;} c; c.f = f;
    unsigned u = c.u;
    unsigned r = (u + 0x7fffu + ((u >> 16) & 1u)) >> 16;
    return (unsigned short)r;
}
__device__ __forceinline__ float bfu(unsigned short us){
    union{unsigned u; float f;} c; c.u = ((unsigned)us) << 16; return c.f;
}
__device__ __forceinline__ float bflo(unsigned u){
    union{unsigned u; float f;} c; c.u = u << 16; return c.f;
}
__device__ __forceinline__ float bfhi(unsigned u){
    union{unsigned u; float f;} c; c.u = u & 0xffff0000u; return c.f;
}

// ---------------------------------------------------------------------------
// fp32 [R][K] -> bf16 [R][Kp], zero-padded in K
__global__ __launch_bounds__(256) void cvt_pack_w_k(const float* __restrict__ src,
                                                    unsigned short* __restrict__ dst,
                                                    int R, int K, int Kp)
{
    long long idx = (long long)blockIdx.x*256 + threadIdx.x;
    long long tot = (long long)R*Kp;
    if (idx >= tot) return;
    int r = (int)(idx / Kp), kk = (int)(idx - (long long)r*Kp);
    float v = (kk < K) ? src[(size_t)r*K + kk] : 0.f;
    dst[idx] = f2bf(v);
}

// Abf[1120][800]: k<400 -> x3[m][k], else Hacc[m][k-400]
__global__ __launch_bounds__(256) void cvt_catA_k(const float* __restrict__ x3,
                                                  const float* __restrict__ Hacc,
                                                  unsigned short* __restrict__ Abf)
{
    int idx = blockIdx.x*256 + threadIdx.x;
    if (idx >= SB_*800) return;
    int m = idx / 800, k = idx - m*800;
    float v = (k < 400) ? x3[(size_t)m*400 + k] : Hacc[(size_t)m*400 + (k-400)];
    Abf[idx] = f2bf(v);
}

// Bbf[32000][800]: k<400 -> decW[v][k], else odeW2[v][k-400]
__global__ __launch_bounds__(256) void cvt_catB_k(const float* __restrict__ decW,
                                                  const float* __restrict__ odeW2,
                                                  unsigned short* __restrict__ Bbf)
{
    long long idx = (long long)blockIdx.x*256 + threadIdx.x;
    if (idx >= (long long)NT_*800) return;
    int v = (int)(idx / 800), k = (int)(idx - (long long)v*800);
    float x = (k < 400) ? decW[(size_t)v*400 + k] : odeW2[(size_t)v*400 + (k-400)];
    Bbf[idx] = f2bf(x);
}

// Wxbf[400][32000] = bf16(odeW1[:,1:])
__global__ __launch_bounds__(256) void cvt_wx_k(const float* __restrict__ odeW1,
                                                unsigned short* __restrict__ Wxbf)
{
    long long idx = (long long)blockIdx.x*256 + threadIdx.x;
    if (idx >= (long long)400*NT_) return;
    int m = (int)(idx / NT_), v = (int)(idx - (long long)m*NT_);
    Wxbf[idx] = f2bf(odeW1[(size_t)m*W1S_ + 1 + v]);
}

// ---------------------------------------------------------------------------
// Embedding gather, transposed: x0T[t][d][b] = emb[tok[t,b]][d]
__global__ __launch_bounds__(256) void embed_k(const int* __restrict__ tok,
                                               const float* __restrict__ emb,
                                               float* __restrict__ x0T)
{
    int t = blockIdx.x;
    __shared__ int tk[16];
    if (threadIdx.x < 16) tk[threadIdx.x] = tok[t*16 + threadIdx.x];
    __syncthreads();
    for (int idx = threadIdx.x; idx < 400*16; idx += 256){
        int b = idx / 400, d = idx - b*400;
        x0T[t*6400 + d*16 + b] = emb[(size_t)tk[b]*400 + d];
    }
}

// dst[j*16+b] = src[b*dh+j]
__global__ __launch_bounds__(256) void transpose16_k(const float* __restrict__ src,
                                                     float* __restrict__ dst, int dh)
{
    int idx = blockIdx.x*256 + threadIdx.x;
    if (idx < dh*16){ int j = idx >> 4, b = idx & 15; dst[idx] = src[b*dh + j]; }
}

// ---------------------------------------------------------------------------
// bf16 weights, packed rows of stride Kp (Kp % 8 == 0, zero-padded).
// Wave = one hidden unit j; lane = (g = k-cohort 0..3, b = batch 0..15).
__device__ __forceinline__ void dot4b(const unsigned short* __restrict__ W, int Dh, int j, int Kp,
                                      const float* __restrict__ VT, int b, int g,
                                      float& a0, float& a1, float& a2, float& a3)
{
    const uint4* w0 = (const uint4*)(W + (size_t)(0*Dh + j)*Kp);
    const uint4* w1 = (const uint4*)(W + (size_t)(1*Dh + j)*Kp);
    const uint4* w2 = (const uint4*)(W + (size_t)(2*Dh + j)*Kp);
    const uint4* w3 = (const uint4*)(W + (size_t)(3*Dh + j)*Kp);
    int k8cnt = Kp >> 3;
    #pragma unroll 2
    for (int k8 = g; k8 < k8cnt; k8 += 4){
        int d = k8 << 3;
        uint4 u0 = w0[k8], u1 = w1[k8], u2 = w2[k8], u3 = w3[k8];
        float v0 = VT[(d+0)*16+b], v1 = VT[(d+1)*16+b];
        float v2 = VT[(d+2)*16+b], v3 = VT[(d+3)*16+b];
        float v4 = VT[(d+4)*16+b], v5 = VT[(d+5)*16+b];
        float v6 = VT[(d+6)*16+b], v7 = VT[(d+7)*16+b];
        a0 += bflo(u0.x)*v0 + bfhi(u0.x)*v1 + bflo(u0.y)*v2 + bfhi(u0.y)*v3
            + bflo(u0.z)*v4 + bfhi(u0.z)*v5 + bflo(u0.w)*v6 + bfhi(u0.w)*v7;
        a1 += bflo(u1.x)*v0 + bfhi(u1.x)*v1 + bflo(u1.y)*v2 + bfhi(u1.y)*v3
            + bflo(u1.z)*v4 + bfhi(u1.z)*v5 + bflo(u1.w)*v6 + bfhi(u1.w)*v7;
        a2 += bflo(u2.x)*v0 + bfhi(u2.x)*v1 + bflo(u2.y)*v2 + bfhi(u2.y)*v3
            + bflo(u2.z)*v4 + bfhi(u2.z)*v5 + bflo(u2.w)*v6 + bfhi(u2.w)*v7;
        a3 += bflo(u3.x)*v0 + bfhi(u3.x)*v1 + bflo(u3.y)*v2 + bfhi(u3.y)*v3
            + bflo(u3.z)*v4 + bfhi(u3.z)*v5 + bflo(u3.w)*v6 + bfhi(u3.w)*v7;
    }
}

__global__ __launch_bounds__(256) void lstm_step_k(int u,
    const float* __restrict__ x0T, float* __restrict__ ys0T, float* __restrict__ ys1T,
    float* __restrict__ x3,
    float* __restrict__ hT0, float* __restrict__ cT0,
    float* __restrict__ hT1, float* __restrict__ cT1,
    float* __restrict__ hT2, float* __restrict__ cT2,
    const unsigned short* __restrict__ Wih0p, const unsigned short* __restrict__ Whh0p,
    const float* __restrict__ bih0, const float* __restrict__ bhh0,
    const unsigned short* __restrict__ Wih1p, const unsigned short* __restrict__ Whh1p,
    const float* __restrict__ bih1, const float* __restrict__ bhh1,
    const unsigned short* __restrict__ Wih2p, const unsigned short* __restrict__ Whh2p,
    const float* __restrict__ bih2, const float* __restrict__ bhh2)
{
    int blk = blockIdx.x;
    int layer, jb;
    if      (blk < 288){ layer = 0; jb = blk*4; }
    else if (blk < 576){ layer = 1; jb = (blk-288)*4; }
    else               { layer = 2; jb = (blk-576)*4; }
    int t = u - layer;
    if (t < 0 || t >= S_) return;

    int j    = jb + (threadIdx.x >> 6);
    int lane = threadIdx.x & 63;
    int b = lane & 15, g = lane >> 4;

    const float *xT; const unsigned short *Wih, *Whh; const float *bih, *bhh;
    float *hTb, *cTb;
    int Kpi, Dh, Kph;
    float* outT = nullptr; float* outP = nullptr;
    if (layer == 0){
        xT = x0T + t*(400*16); Kpi = 400;  Dh = 1150; Kph = 1152;
        Wih = Wih0p; Whh = Whh0p; bih = bih0; bhh = bhh0; hTb = hT0; cTb = cT0;
        outT = ys0T + (size_t)t*(DHP_*16);
    } else if (layer == 1){
        xT = ys0T + (size_t)t*(DHP_*16); Kpi = 1152; Dh = 1150; Kph = 1152;
        Wih = Wih1p; Whh = Whh1p; bih = bih1; bhh = bhh1; hTb = hT1; cTb = cT1;
        outT = ys1T + (size_t)t*(DHP_*16);
    } else {
        xT = ys1T + (size_t)t*(DHP_*16); Kpi = 1152; Dh = 400; Kph = 400;
        Wih = Wih2p; Whh = Whh2p; bih = bih2; bhh = bhh2; hTb = hT2; cTb = cT2;
        outP = x3 + (size_t)t*16*400;
    }
    if (j >= Dh) return;

    const float* hRead  = hTb + (t & 1)     * (DHP_*16);
    float*       hWrite = hTb + ((t+1) & 1) * (DHP_*16);

    float a0 = 0.f, a1 = 0.f, a2 = 0.f, a3 = 0.f;
    dot4b(Wih, Dh, j, Kpi, xT,    b, g, a0, a1, a2, a3);   // x @ Wih^T (folded)
    dot4b(Whh, Dh, j, Kph, hRead, b, g, a0, a1, a2, a3);   // h @ Whh^T

    a0 += __shfl_xor(a0, 16); a0 += __shfl_xor(a0, 32);
    a1 += __shfl_xor(a1, 16); a1 += __shfl_xor(a1, 32);
    a2 += __shfl_xor(a2, 16); a2 += __shfl_xor(a2, 32);
    a3 += __shfl_xor(a3, 16); a3 += __shfl_xor(a3, 32);

    float pi = a0 + bih[j]        + bhh[j];
    float pf = a1 + bih[Dh+j]     + bhh[Dh+j];
    float pg = a2 + bih[2*Dh+j]   + bhh[2*Dh+j];
    float po = a3 + bih[3*Dh+j]   + bhh[3*Dh+j];

    float cold = cTb[j*16+b];
    float cnew = sigm(pf)*cold + sigm(pi)*tanhf(pg);
    float h    = sigm(po)*tanhf(cnew);
    if (g == 0){
        cTb[j*16+b]    = cnew;
        hWrite[j*16+b] = h;
        if (outT) outT[j*16+b]    = h;
        if (outP) outP[b*400 + j] = h;
    }
}

// ---------------------------------------------------------------------------
// dvec[j] = Wx[j,:]·decb ; bvec[j] = Wx[j,:]·b2 ; wtd[j] = odeW1[j,0]
__global__ __launch_bounds__(256) void vecs_k(const float* __restrict__ odeW1,
                                              const float* __restrict__ decb,
                                              const float* __restrict__ b2v,
                                              float* __restrict__ dvec,
                                              float* __restrict__ bvec,
                                              float* __restrict__ wtd)
{
    int jrow = blockIdx.x;
    __shared__ float r1[256], r2[256];
    const float* wx = odeW1 + (size_t)jrow*W1S_ + 1;
    float s1 = 0.f, s2 = 0.f;
    for (int v = threadIdx.x; v < NT_; v += 256){
        float w = wx[v]; s1 += w*decb[v]; s2 += w*b2v[v];
    }
    r1[threadIdx.x] = s1; r2[threadIdx.x] = s2; __syncthreads();
    for (int s = 128; s > 0; s >>= 1){
        if (threadIdx.x < s){ r1[threadIdx.x] += r1[threadIdx.x+s]; r2[threadIdx.x] += r2[threadIdx.x+s]; }
        __syncthreads();
    }
    if (threadIdx.x == 0){ dvec[jrow] = r1[0]; bvec[jrow] = r2[0]; wtd[jrow] = odeW1[(size_t)jrow*W1S_]; }
}

// C_partial[slab][m,n] = sum_{v in slab} Wx[m,v]*B[v,n]   bf16 inputs, fp32 math
__global__ __launch_bounds__(256) void gemm_ode_bf_k(const unsigned short* __restrict__ Wxbf,
                                                     const unsigned short* __restrict__ Bbf, int boff,
                                                     float* __restrict__ partials)
{
    __shared__ float As[16][68];
    __shared__ float Bs[16][68];
    int m0 = blockIdx.y*64, n0 = blockIdx.x*64;
    int v0 = blockIdx.z*2000;
    int tid = threadIdx.x, tx = tid & 15, ty = tid >> 4;
    int rowA = tid >> 2, kqA = tid & 3;
    int krB  = tid >> 4, n4B = tid & 15;
    float acc[4][4] = {};
    for (int kk = 0; kk < 2000; kk += 16){
        int m = m0 + rowA;
        if (m < 400){
            ushort4 ap = *(const ushort4*)(Wxbf + (size_t)m*NT_ + v0 + kk + kqA*4);
            As[kqA*4+0][rowA] = bfu(ap.x); As[kqA*4+1][rowA] = bfu(ap.y);
            As[kqA*4+2][rowA] = bfu(ap.z); As[kqA*4+3][rowA] = bfu(ap.w);
        } else {
            As[kqA*4+0][rowA] = 0.f; As[kqA*4+1][rowA] = 0.f;
            As[kqA*4+2][rowA] = 0.f; As[kqA*4+3][rowA] = 0.f;
        }
        int v = v0 + kk + krB;
        int n = n0 + n4B*4;
        if (n < 400){
            ushort4 vb = *(const ushort4*)(Bbf + (size_t)v*800 + boff + n);
            Bs[krB][n4B*4+0] = bfu(vb.x); Bs[krB][n4B*4+1] = bfu(vb.y);
            Bs[krB][n4B*4+2] = bfu(vb.z); Bs[krB][n4B*4+3] = bfu(vb.w);
        } else {
            Bs[krB][n4B*4+0] = 0.f; Bs[krB][n4B*4+1] = 0.f;
            Bs[krB][n4B*4+2] = 0.f; Bs[krB][n4B*4+3] = 0.f;
        }
        __syncthreads();
        #pragma unroll
        for (int k = 0; k < 16; ++k){
            float4 a4 = *(const float4*)&As[k][tx*4];
            float4 b4 = *(const float4*)&Bs[k][ty*4];
            float av[4] = {a4.x,a4.y,a4.z,a4.w};
            float bv[4] = {b4.x,b4.y,b4.z,b4.w};
            #pragma unroll
            for (int i = 0; i < 4; ++i)
                #pragma unroll
                for (int jj = 0; jj < 4; ++jj) acc[i][jj] += av[i]*bv[jj];
        }
        __syncthreads();
    }
    float* outp = partials + (size_t)blockIdx.z*160000;
    #pragma unroll
    for (int i = 0; i < 4; ++i){
        int m = m0 + tx*4 + i; if (m >= 400) continue;
        #pragma unroll
        for (int jj = 0; jj < 4; ++jj){
            int n = n0 + ty*4 + jj; if (n >= 400) continue;
            outp[m*400 + n] = acc[i][jj];
        }
    }
}

__global__ __launch_bounds__(256) void reduce16_k(const float* __restrict__ p, float* __restrict__ out)
{
    int i = blockIdx.x*256 + threadIdx.x;
    if (i < 160000){
        float s = 0.f;
        #pragma unroll
        for (int k = 0; k < 16; ++k) s += p[k*160000 + i];
        out[i] = s;
    }
}

// ---------------------------------------------------------------------------
// OUT[m,n] = maybe_softplus( dotc*sum_k A[m,k]*B[n,k] + Gbase + vcoef*vec[n] + tval*wt[n] + b1[n] )
__global__ __launch_bounds__(256) void fused_small_k(
    const float* __restrict__ A, const float* __restrict__ Bm,
    const float* __restrict__ Gbase, float* __restrict__ OUT,
    const float* __restrict__ vec, float vcoef,
    const float* __restrict__ wt, float tval,
    const float* __restrict__ b1, float dotc, int do_sp)
{
    __shared__ float As[16][68];
    __shared__ float Bs[16][68];
    int m0 = blockIdx.y*64, n0 = blockIdx.x*64;
    int tid = threadIdx.x, tx = tid & 15, ty = tid >> 4;
    int row = tid >> 2, kq = tid & 3;
    float acc[4][4] = {};
    for (int k0 = 0; k0 < 400; k0 += 16){
        int m = m0 + row;
        if (m < SB_){
            float4 va = *(const float4*)(A + (size_t)m*400 + k0 + kq*4);
            As[kq*4+0][row] = va.x; As[kq*4+1][row] = va.y;
            As[kq*4+2][row] = va.z; As[kq*4+3][row] = va.w;
        } else {
            As[kq*4+0][row] = 0.f; As[kq*4+1][row] = 0.f;
            As[kq*4+2][row] = 0.f; As[kq*4+3][row] = 0.f;
        }
        int n = n0 + row;
        if (n < 400){
            float4 vb = *(const float4*)(Bm + (size_t)n*400 + k0 + kq*4);
            Bs[kq*4+0][row] = vb.x; Bs[kq*4+1][row] = vb.y;
            Bs[kq*4+2][row] = vb.z; Bs[kq*4+3][row] = vb.w;
        } else {
            Bs[kq*4+0][row] = 0.f; Bs[kq*4+1][row] = 0.f;
            Bs[kq*4+2][row] = 0.f; Bs[kq*4+3][row] = 0.f;
        }
        __syncthreads();
        #pragma unroll
        for (int k = 0; k < 16; ++k){
            float4 a4 = *(const float4*)&As[k][tx*4];
            float4 b4 = *(const float4*)&Bs[k][ty*4];
            float av[4] = {a4.x,a4.y,a4.z,a4.w};
            float bv[4] = {b4.x,b4.y,b4.z,b4.w};
            #pragma unroll
            for (int i = 0; i < 4; ++i)
                #pragma unroll
                for (int jj = 0; jj < 4; ++jj) acc[i][jj] += av[i]*bv[jj];
        }
        __syncthreads();
    }
    #pragma unroll
    for (int i = 0; i < 4; ++i){
        int m = m0 + tx*4 + i; if (m >= SB_) continue;
        #pragma unroll
        for (int jj = 0; jj < 4; ++jj){
            int n = n0 + ty*4 + jj; if (n >= 400) continue;
            float s = dotc*acc[i][jj];
            if (Gbase) s += Gbase[(size_t)m*400 + n];
            if (vec)   s += vcoef*vec[n];
            if (wt)    s += tval*wt[n];
            if (b1)    s += b1[n];
            OUT[(size_t)m*400 + n] = do_sp ? softplusf(s) : s;
        }
    }
}

// H = softplus(Gy + t*wt + b1)
__global__ __launch_bounds__(256) void stage1_k(const float* __restrict__ Gy, float* __restrict__ H,
                                                const float* __restrict__ wt, float tval,
                                                const float* __restrict__ b1)
{
    int sb = blockIdx.x;
    for (int n = threadIdx.x; n < 400; n += 256){
        float s = Gy[(size_t)sb*400 + n] + tval*wt[n] + b1[n];
        H[(size_t)sb*400 + n] = softplusf(s);
    }
}

// Hs = dt/6*(H1+2H2+2H3+H4); Hacc += Hs
__global__ __launch_bounds__(256) void hs_k(const float* __restrict__ H1, const float* __restrict__ H2,
                                            const float* __restrict__ H3, const float* __restrict__ H4,
                                            float* __restrict__ Hs, float* __restrict__ Hacc, int n)
{
    int i = blockIdx.x*256 + threadIdx.x;
    if (i < n){
        float v = (1.f/12.f)*(H1[i] + 2.f*H2[i] + 2.f*H3[i] + H4[i]);  // dt/6 = 0.5/6
        Hs[i] = v;
        Hacc[i] += v;
    }
}

// ---------------------------------------------------------------------------
// MFMA decode: z[m,v] = Abf[m,:]·Bbf[v,:] + decb[v] + b2[v]   (M=1120,N=32000,K=800)
__global__ __launch_bounds__(256) void decode_mfma_k(
    const unsigned short* __restrict__ Abf,
    const unsigned short* __restrict__ Bbf,
    const float* __restrict__ decb, const float* __restrict__ b2v,
    float* __restrict__ z)
{
    __shared__ unsigned short As[128*40];
    __shared__ unsigned short Bs[128*40];
    int n0 = blockIdx.x*128, m0 = blockIdx.y*128;
    int tid = threadIdx.x;
    int lane = tid & 63, wid = tid >> 6;
    int wr = wid >> 1, wc = wid & 1;
    f32x4 acc[4][4] = {};

    int srow = tid >> 1;           // 0..127
    int sk   = (tid & 1) * 16;     // 0 or 16

    for (int k0 = 0; k0 < 800; k0 += 32){
        uint4 av0 = {0,0,0,0}, av1 = {0,0,0,0};
        int m = m0 + srow;
        if (m < SB_){
            const uint4* ap = (const uint4*)(Abf + (size_t)m*800 + k0 + sk);
            av0 = ap[0]; av1 = ap[1];
        }
        const uint4* bp = (const uint4*)(Bbf + (size_t)(n0 + srow)*800 + k0 + sk);
        uint4 bv0 = bp[0], bv1 = bp[1];

        __syncthreads();   // prev iteration's ds_reads complete
        *(uint4*)&As[srow*40 + sk]     = av0;
        *(uint4*)&As[srow*40 + sk + 8] = av1;
        *(uint4*)&Bs[srow*40 + sk]     = bv0;
        *(uint4*)&Bs[srow*40 + sk + 8] = bv1;
        __syncthreads();

        int kq = (lane >> 4) * 8;
        int rA = wr*64 + (lane & 15);
        int rB = wc*64 + (lane & 15);
        bf16x8 af[4], bfv[4];
        #pragma unroll
        for (int f = 0; f < 4; ++f){
            af[f]  = *(const bf16x8*)&As[(rA + f*16)*40 + kq];
            bfv[f] = *(const bf16x8*)&Bs[(rB + f*16)*40 + kq];
        }
        #pragma unroll
        for (int fm = 0; fm < 4; ++fm)
            #pragma unroll
            for (int fn = 0; fn < 4; ++fn)
                acc[fm][fn] = __builtin_amdgcn_mfma_f32_16x16x32_bf16(af[fm], bfv[fn], acc[fm][fn], 0, 0, 0);
    }

    int cm = (lane >> 4) * 4;      // C/D: row=(lane>>4)*4+reg, col=lane&15
    int cn = lane & 15;
    #pragma unroll
    for (int fm = 0; fm < 4; ++fm){
        int mrow0 = m0 + wr*64 + fm*16 + cm;
        #pragma unroll
        for (int fn = 0; fn < 4; ++fn){
            int n = n0 + wc*64 + fn*16 + cn;
            float db = decb[n] + b2v[n];
            #pragma unroll
            for (int r = 0; r < 4; ++r){
                int mr = mrow0 + r;
                if (mr < SB_) z[(size_t)mr*NT_ + n] = acc[fm][fn][r] + db;
            }
        }
    }
}

// per-row max and sum(exp(z-max))
__global__ __launch_bounds__(256) void rowred_k(const float* __restrict__ z,
                                                float* __restrict__ rowm, float* __restrict__ rowsum)
{
    int r = blockIdx.x;
    const float* zr = z + (size_t)r*NT_;
    __shared__ float sm[256];
    float m = -1e30f;
    for (int v = threadIdx.x; v < NT_; v += 256) m = fmaxf(m, zr[v]);
    sm[threadIdx.x] = m; __syncthreads();
    for (int s = 128; s > 0; s >>= 1){
        if (threadIdx.x < s) sm[threadIdx.x] = fmaxf(sm[threadIdx.x], sm[threadIdx.x+s]);
        __syncthreads();
    }
    m = sm[0]; __syncthreads();
    float s = 0.f;
    for (int v = threadIdx.x; v < NT_; v += 256) s += __expf(zr[v] - m);
    sm[threadIdx.x] = s; __syncthreads();
    for (int st = 128; st > 0; st >>= 1){
        if (threadIdx.x < st) sm[threadIdx.x] += sm[threadIdx.x+st];
        __syncthreads();
    }
    if (threadIdx.x == 0){ rowm[r] = m; rowsum[r] = sm[0]; }
}

// out = log(exp(z-m)/S + 1e-8), in place
__global__ __launch_bounds__(256) void finalmap_k(float* __restrict__ z,
                                                  const float* __restrict__ rowm,
                                                  const float* __restrict__ rowsum)
{
    int r = blockIdx.y;
    int v = (blockIdx.x*256 + threadIdx.x)*4;
    if (v >= NT_) return;
    float m = rowm[r];
    float sinv = 1.f/rowsum[r];
    float4* p = (float4*)(z + (size_t)r*NT_ + v);
    float4 x = *p;
    x.x = logf(__expf(x.x - m)*sinv + 1e-8f);
    x.y = logf(__expf(x.y - m)*sinv + 1e-8f);
    x.z = logf(__expf(x.z - m)*sinv + 1e-8f);
    x.w = logf(__expf(x.w - m)*sinv + 1e-8f);
    *p = x;
}

// ---------------------------------------------------------------------------
extern "C" void kernel_launch(void* const* d_in, const int* in_sizes, int n_in,
                              void* d_out, int out_size, void* d_ws, size_t ws_size,
                              hipStream_t stream)
{
    const int*   tokens = (const int*)  d_in[0];
    const float* h0_0 = (const float*)d_in[1];
    const float* c0_0 = (const float*)d_in[2];
    const float* Wih0 = (const float*)d_in[3];
    const float* Whh0 = (const float*)d_in[4];
    const float* bih0 = (const float*)d_in[5];
    const float* bhh0 = (const float*)d_in[6];
    const float* h0_1 = (const float*)d_in[7];
    const float* c0_1 = (const float*)d_in[8];
    const float* Wih1 = (const float*)d_in[9];
    const float* Whh1 = (const float*)d_in[10];
    const float* bih1 = (const float*)d_in[11];
    const float* bhh1 = (const float*)d_in[12];
    const float* h0_2 = (const float*)d_in[13];
    const float* c0_2 = (const float*)d_in[14];
    const float* Wih2 = (const float*)d_in[15];
    const float* Whh2 = (const float*)d_in[16];
    const float* bih2 = (const float*)d_in[17];
    const float* bhh2 = (const float*)d_in[18];
    const float* emb  = (const float*)d_in[19];
    const float* decW = (const float*)d_in[20];
    const float* decb = (const float*)d_in[21];
    const float* odeW1= (const float*)d_in[22];
    const float* odeb1= (const float*)d_in[23];
    const float* odeW2= (const float*)d_in[24];
    const float* odeb2= (const float*)d_in[25];

    // workspace carve-up (~160 MB), all chunks multiples of 16B
    float* w = (float*)d_ws;
    size_t off = 0;
    auto alloc = [&](size_t n){ float* p = w + off; off += n; return p; };
    auto allocU = [&](size_t nUsh){ return (unsigned short*)alloc(nUsh/2); };  // nUsh even
    float* x0T  = alloc((size_t)S_*400*16);
    float* ys0T = alloc((size_t)S_*DHP_*16);
    float* ys1T = alloc((size_t)S_*DHP_*16);
    float* x3   = alloc((size_t)SB_*400);
    float* hT0  = alloc(2*DHP_*16); float* cT0 = alloc(DHP_*16);
    float* hT1  = alloc(2*DHP_*16); float* cT1 = alloc(DHP_*16);
    float* hT2  = alloc(2*DHP_*16); float* cT2 = alloc(DHP_*16);
    float* P    = alloc(160000);
    float* Q    = alloc(160000);
    float* dvec = alloc(512);
    float* bvec = alloc(512);
    float* wtd  = alloc(512);
    float* Gy   = alloc((size_t)SB_*400);
    float* Hacc = alloc((size_t)SB_*400);
    float* H1   = alloc((size_t)SB_*400);
    float* H2   = alloc((size_t)SB_*400);
    float* H3   = alloc((size_t)SB_*400);
    float* H4   = alloc((size_t)SB_*400);
    float* Hs   = alloc((size_t)SB_*400);
    float* rowm = alloc(1280);
    float* rsum = alloc(1280);
    float* partials = alloc((size_t)16*160000);
    // bf16 buffers
    unsigned short* Wih0p = allocU((size_t)4600*400);
    unsigned short* Whh0p = allocU((size_t)4600*1152);
    unsigned short* Wih1p = allocU((size_t)4600*1152);
    unsigned short* Whh1p = allocU((size_t)4600*1152);
    unsigned short* Wih2p = allocU((size_t)1600*1152);
    unsigned short* Whh2p = allocU((size_t)1600*400);
    unsigned short* Abf   = allocU((size_t)SB_*800);
    unsigned short* Bbf   = allocU((size_t)NT_*800);
    unsigned short* Wxbf  = allocU((size_t)400*NT_);
    (void)ws_size; (void)in_sizes; (void)n_in; (void)out_size;

    float* zout = (float*)d_out;

    hipMemsetAsync(Hacc, 0, (size_t)SB_*400*sizeof(float), stream);

    // weight conversions (bf16)
    auto cvtgrid = [](long long n){ return (unsigned)((n + 255) / 256); };
    cvt_pack_w_k<<<cvtgrid((long long)4600*400),  256, 0, stream>>>(Wih0, Wih0p, 4600, 400, 400);
    cvt_pack_w_k<<<cvtgrid((long long)4600*1152), 256, 0, stream>>>(Whh0, Whh0p, 4600, 1150, 1152);
    cvt_pack_w_k<<<cvtgrid((long long)4600*1152), 256, 0, stream>>>(Wih1, Wih1p, 4600, 1150, 1152);
    cvt_pack_w_k<<<cvtgrid((long long)4600*1152), 256, 0, stream>>>(Whh1, Whh1p, 4600, 1150, 1152);
    cvt_pack_w_k<<<cvtgrid((long long)1600*1152), 256, 0, stream>>>(Wih2, Wih2p, 1600, 1150, 1152);
    cvt_pack_w_k<<<cvtgrid((long long)1600*400),  256, 0, stream>>>(Whh2, Whh2p, 1600, 400, 400);
    cvt_catB_k<<<cvtgrid((long long)NT_*800), 256, 0, stream>>>(decW, odeW2, Bbf);
    cvt_wx_k<<<cvtgrid((long long)400*NT_), 256, 0, stream>>>(odeW1, Wxbf);

    // embed + state init
    embed_k<<<S_, 256, 0, stream>>>(tokens, emb, x0T);
    transpose16_k<<<(1150*16+255)/256, 256, 0, stream>>>(h0_0, hT0, 1150);
    transpose16_k<<<(1150*16+255)/256, 256, 0, stream>>>(c0_0, cT0, 1150);
    transpose16_k<<<(1150*16+255)/256, 256, 0, stream>>>(h0_1, hT1, 1150);
    transpose16_k<<<(1150*16+255)/256, 256, 0, stream>>>(c0_1, cT1, 1150);
    transpose16_k<<<(400*16+255)/256, 256, 0, stream>>>(h0_2, hT2, 400);
    transpose16_k<<<(400*16+255)/256, 256, 0, stream>>>(c0_2, cT2, 400);

    // 3-layer LSTM, layer-pipelined wavefront (bf16 weights)
    for (int u = 0; u < S_ + 2; ++u)
        lstm_step_k<<<676, 256, 0, stream>>>(u, x0T, ys0T, ys1T, x3,
            hT0, cT0, hT1, cT1, hT2, cT2,
            Wih0p, Whh0p, bih0, bhh0, Wih1p, Whh1p, bih1, bhh1, Wih2p, Whh2p, bih2, bhh2);

    // ODE factorization precompute: P = Wx@W2, Q = Wx@decW (bf16 inputs)
    vecs_k<<<400, 256, 0, stream>>>(odeW1, decb, odeb2, dvec, bvec, wtd);
    gemm_ode_bf_k<<<dim3(7,7,16), 256, 0, stream>>>(Wxbf, Bbf, 400, partials);
    reduce16_k<<<(160000+255)/256, 256, 0, stream>>>(partials, P);
    gemm_ode_bf_k<<<dim3(7,7,16), 256, 0, stream>>>(Wxbf, Bbf, 0, partials);
    reduce16_k<<<(160000+255)/256, 256, 0, stream>>>(partials, Q);

    // G0 = x3 @ Q^T + dvec
    fused_small_k<<<dim3(7,18), 256, 0, stream>>>(x3, Q, nullptr, Gy,
        dvec, 1.f, nullptr, 0.f, nullptr, 1.f, 0);

    // RK4 in G-space, 2 steps, dt = 0.5
    const float dt = 0.5f;
    for (int n = 0; n < 2; ++n){
        float t0 = n * dt;
        stage1_k<<<SB_, 256, 0, stream>>>(Gy, H1, wtd, t0, odeb1);
        fused_small_k<<<dim3(7,18), 256, 0, stream>>>(H1, P, Gy, H2,
            bvec, 0.25f, wtd, t0 + 0.25f, odeb1, 0.25f, 1);
        fused_small_k<<<dim3(7,18), 256, 0, stream>>>(H2, P, Gy, H3,
            bvec, 0.25f, wtd, t0 + 0.25f, odeb1, 0.25f, 1);
        fused_small_k<<<dim3(7,18), 256, 0, stream>>>(H3, P, Gy, H4,
            bvec, 0.5f, wtd, t0 + 0.5f, odeb1, 0.5f, 1);
        hs_k<<<((SB_*400)+255)/256, 256, 0, stream>>>(H1, H2, H3, H4, Hs, Hacc, SB_*400);
        if (n == 0)
            fused_small_k<<<dim3(7,18), 256, 0, stream>>>(Hs, P, Gy, Gy,
                bvec, dt, nullptr, 0.f, nullptr, 1.f, 0);
    }

    // A-concat (x3|Hacc) -> bf16, MFMA decode, then log-softmax in place
    cvt_catA_k<<<cvtgrid((long long)SB_*800), 256, 0, stream>>>(x3, Hacc, Abf);
    decode_mfma_k<<<dim3(250,9), 256, 0, stream>>>(Abf, Bbf, decb, odeb2, zout);
    rowred_k<<<SB_, 256, 0, stream>>>(zout, rowm, rsum);
    finalmap_k<<<dim3(32,SB_), 256, 0, stream>>>(zout, rowm, rsum);
}

// Round 4
// 3037.984 us; speedup vs baseline: 2.8315x; 1.3333x over previous
//
#include <hip/hip_runtime.h>
#include <math.h>

// Problem dims
constexpr int S_   = 70;
constexpr int B_   = 16;
constexpr int SB_  = 1120;     // S*B
constexpr int NT_  = 32000;    // NTOKEN
constexpr int W1S_ = 32001;    // odeW1 row stride (NTOKEN+1)

typedef __attribute__((ext_vector_type(8))) short bf16x8;
typedef __attribute__((ext_vector_type(4))) float f32x4;

__device__ __forceinline__ float sigm(float x){ return 1.f/(1.f+__expf(-x)); }
__device__ __forceinline__ float softplusf(float x){ return x > 15.f ? x : log1pf(__expf(x)); }

__device__ __forceinline__ unsigned short f2bf(float f){
    union{float f; unsigned u;} c; c.f = f;
    unsigned u = c.u;
    unsigned r = (u + 0x7fffu + ((u >> 16) & 1u)) >> 16;
    return (unsigned short)r;
}
__device__ __forceinline__ float bfu(unsigned short us){
    union{unsigned u; float f;} c; c.u = ((unsigned)us) << 16; return c.f;
}

// ---------------------------------------------------------------------------
// fp32 [R][K] -> bf16 [R][Kp], zero-padded in K
__global__ __launch_bounds__(256) void cvt_pack_w_k(const float* __restrict__ src,
                                                    unsigned short* __restrict__ dst,
                                                    int R, int K, int Kp)
{
    long long idx = (long long)blockIdx.x*256 + threadIdx.x;
    long long tot = (long long)R*Kp;
    if (idx >= tot) return;
    int r = (int)(idx / Kp), kk = (int)(idx - (long long)r*Kp);
    float v = (kk < K) ? src[(size_t)r*K + kk] : 0.f;
    dst[idx] = f2bf(v);
}

// Abf[1120][800]: k<400 -> x3[m][k], else Hacc[m][k-400]
__global__ __launch_bounds__(256) void cvt_catA_k(const float* __restrict__ x3,
                                                  const float* __restrict__ Hacc,
                                                  unsigned short* __restrict__ Abf)
{
    int idx = blockIdx.x*256 + threadIdx.x;
    if (idx >= SB_*800) return;
    int m = idx / 800, k = idx - m*800;
    float v = (k < 400) ? x3[(size_t)m*400 + k] : Hacc[(size_t)m*400 + (k-400)];
    Abf[idx] = f2bf(v);
}

// Bbf[32000][800]: k<400 -> decW[v][k], else odeW2[v][k-400]
__global__ __launch_bounds__(256) void cvt_catB_k(const float* __restrict__ decW,
                                                  const float* __restrict__ odeW2,
                                                  unsigned short* __restrict__ Bbf)
{
    long long idx = (long long)blockIdx.x*256 + threadIdx.x;
    if (idx >= (long long)NT_*800) return;
    int v = (int)(idx / 800), k = (int)(idx - (long long)v*800);
    float x = (k < 400) ? decW[(size_t)v*400 + k] : odeW2[(size_t)v*400 + (k-400)];
    Bbf[idx] = f2bf(x);
}

// Wxbf[400][32000] = bf16(odeW1[:,1:])
__global__ __launch_bounds__(256) void cvt_wx_k(const float* __restrict__ odeW1,
                                                unsigned short* __restrict__ Wxbf)
{
    long long idx = (long long)blockIdx.x*256 + threadIdx.x;
    if (idx >= (long long)400*NT_) return;
    int m = (int)(idx / NT_), v = (int)(idx - (long long)m*NT_);
    Wxbf[idx] = f2bf(odeW1[(size_t)m*W1S_ + 1 + v]);
}

// ---------------------------------------------------------------------------
// Embedding gather -> bf16 A-layout: x0A[t][b][k] (stride 416, zero-padded)
__global__ __launch_bounds__(256) void embed_bf_k(const int* __restrict__ tok,
                                                  const float* __restrict__ emb,
                                                  unsigned short* __restrict__ x0A)
{
    int t = blockIdx.x;
    __shared__ int tk[16];
    if (threadIdx.x < 16) tk[threadIdx.x] = tok[t*16 + threadIdx.x];
    __syncthreads();
    for (int idx = threadIdx.x; idx < 16*416; idx += 256){
        int b = idx / 416, k = idx - b*416;
        float v = (k < 400) ? emb[(size_t)tk[b]*400 + k] : 0.f;
        x0A[(size_t)t*16*416 + idx] = f2bf(v);
    }
}

// dst[j*16+b] = src[b*dh+j]  (c-state init)
__global__ __launch_bounds__(256) void transpose16_k(const float* __restrict__ src,
                                                     float* __restrict__ dst, int dh)
{
    int idx = blockIdx.x*256 + threadIdx.x;
    if (idx < dh*16){ int j = idx >> 4, b = idx & 15; dst[idx] = src[b*dh + j]; }
}

// h0 [16][Dh] fp32 -> hb [16][SA] bf16 (parity-0 buffer; pads pre-zeroed by memset)
__global__ __launch_bounds__(256) void cvt_h0_k(const float* __restrict__ h0,
                                                unsigned short* __restrict__ hb, int Dh, int SA)
{
    int idx = blockIdx.x*256 + threadIdx.x;
    if (idx >= 16*Dh) return;
    int b = idx / Dh, j = idx - b*Dh;
    hb[(size_t)b*SA + j] = f2bf(h0[idx]);
}

// ---------------------------------------------------------------------------
// One wavefront step of the 3-layer LSTM pipeline, MFMA edition.
// Block = one 16-unit j-tile of one layer; wave w = gate w (i,f,g,o).
// A operand = activations [batch][k] bf16; B operand = weight rows [j][k] bf16.
__global__ __launch_bounds__(256) void lstm_mfma_k(int u,
    const unsigned short* __restrict__ x0A,
    unsigned short* __restrict__ ys0A, unsigned short* __restrict__ ys1A,
    float* __restrict__ x3,
    unsigned short* __restrict__ h0b, float* __restrict__ c0,
    unsigned short* __restrict__ h1b, float* __restrict__ c1,
    unsigned short* __restrict__ h2b, float* __restrict__ c2,
    const unsigned short* __restrict__ Wih0p, const unsigned short* __restrict__ Whh0p,
    const float* __restrict__ bih0, const float* __restrict__ bhh0,
    const unsigned short* __restrict__ Wih1p, const unsigned short* __restrict__ Whh1p,
    const float* __restrict__ bih1, const float* __restrict__ bhh1,
    const unsigned short* __restrict__ Wih2p, const unsigned short* __restrict__ Whh2p,
    const float* __restrict__ bih2, const float* __restrict__ bhh2)
{
    int blk = blockIdx.x;
    int layer, jt;
    if      (blk < 72) { layer = 0; jt = blk; }
    else if (blk < 144){ layer = 1; jt = blk - 72; }
    else               { layer = 2; jt = blk - 144; }
    int t = u - layer;
    if (t < 0 || t >= S_) return;
    int j0 = jt*16;

    const unsigned short *Ax, *Ah, *Wi, *Wh;
    const float *bih, *bhh;
    float *cst, *x3o = nullptr;
    unsigned short *yo = nullptr, *hrec;
    int Kx, Kh, Dh, SAx, SAh;
    if (layer == 0){
        Ax = x0A + (size_t)t*16*416; SAx = 416; Kx = 416;
        Ah = h0b + (size_t)(t&1)*16*1152; SAh = 1152; Kh = 1152;
        Wi = Wih0p; Wh = Whh0p; bih = bih0; bhh = bhh0; Dh = 1150;
        cst = c0; hrec = h0b + (size_t)((t+1)&1)*16*1152;
        yo = ys0A + (size_t)t*16*1152;
    } else if (layer == 1){
        Ax = ys0A + (size_t)t*16*1152; SAx = 1152; Kx = 1152;
        Ah = h1b + (size_t)(t&1)*16*1152; SAh = 1152; Kh = 1152;
        Wi = Wih1p; Wh = Whh1p; bih = bih1; bhh = bhh1; Dh = 1150;
        cst = c1; hrec = h1b + (size_t)((t+1)&1)*16*1152;
        yo = ys1A + (size_t)t*16*1152;
    } else {
        Ax = ys1A + (size_t)t*16*1152; SAx = 1152; Kx = 1152;
        Ah = h2b + (size_t)(t&1)*16*416; SAh = 416; Kh = 416;
        Wi = Wih2p; Wh = Whh2p; bih = bih2; bhh = bhh2; Dh = 400;
        cst = c2; hrec = h2b + (size_t)((t+1)&1)*16*416;
        x3o = x3 + (size_t)t*16*400;
    }

    int lane = threadIdx.x & 63, w = threadIdx.x >> 6;   // wave w = gate
    int am = lane & 15;           // A row (batch)
    int kq = (lane >> 4) * 8;     // k offset within 32-step
    int jn = lane & 15;           // B row (local j)
    int jrow = j0 + jn; if (jrow > Dh-1) jrow = Dh-1;    // clamp (dup rows discarded on write)

    const unsigned short* ax = Ax + (size_t)am*SAx;
    const unsigned short* ah = Ah + (size_t)am*SAh;
    const unsigned short* wx = Wi + (size_t)(w*Dh + jrow)*SAx;  // weight stride == padded K of x-side
    const unsigned short* wh = Wh + (size_t)(w*Dh + jrow)*SAh;  // weight stride == padded K of h-side

    f32x4 acc0 = {0.f,0.f,0.f,0.f}, acc1 = {0.f,0.f,0.f,0.f};
    int k0 = 0;
    for (; k0 + 64 <= Kx; k0 += 64){
        bf16x8 a0 = *(const bf16x8*)(ax + k0 + kq);
        bf16x8 b0 = *(const bf16x8*)(wx + k0 + kq);
        acc0 = __builtin_amdgcn_mfma_f32_16x16x32_bf16(a0, b0, acc0, 0,0,0);
        bf16x8 a1 = *(const bf16x8*)(ax + k0 + 32 + kq);
        bf16x8 b1 = *(const bf16x8*)(wx + k0 + 32 + kq);
        acc1 = __builtin_amdgcn_mfma_f32_16x16x32_bf16(a1, b1, acc1, 0,0,0);
    }
    if (k0 < Kx){
        bf16x8 a0 = *(const bf16x8*)(ax + k0 + kq);
        bf16x8 b0 = *(const bf16x8*)(wx + k0 + kq);
        acc0 = __builtin_amdgcn_mfma_f32_16x16x32_bf16(a0, b0, acc0, 0,0,0);
    }
    k0 = 0;
    for (; k0 + 64 <= Kh; k0 += 64){
        bf16x8 a0 = *(const bf16x8*)(ah + k0 + kq);
        bf16x8 b0 = *(const bf16x8*)(wh + k0 + kq);
        acc0 = __builtin_amdgcn_mfma_f32_16x16x32_bf16(a0, b0, acc0, 0,0,0);
        bf16x8 a1 = *(const bf16x8*)(ah + k0 + 32 + kq);
        bf16x8 b1 = *(const bf16x8*)(wh + k0 + 32 + kq);
        acc1 = __builtin_amdgcn_mfma_f32_16x16x32_bf16(a1, b1, acc1, 0,0,0);
    }
    if (k0 < Kh){
        bf16x8 a0 = *(const bf16x8*)(ah + k0 + kq);
        bf16x8 b0 = *(const bf16x8*)(wh + k0 + kq);
        acc0 = __builtin_amdgcn_mfma_f32_16x16x32_bf16(a0, b0, acc0, 0,0,0);
    }
    f32x4 acc = acc0 + acc1;

    // C/D: row m = (lane>>4)*4 + r (batch), col = lane&15 (local j)
    __shared__ float g4[4][16][17];
    int bm = (lane >> 4) * 4;
    #pragma unroll
    for (int r = 0; r < 4; ++r) g4[w][bm + r][jn] = acc[r];
    __syncthreads();

    int jl = threadIdx.x >> 4, b = threadIdx.x & 15;
    int j = j0 + jl;
    if (j < Dh){
        float pi = g4[0][b][jl] + bih[j]      + bhh[j];
        float pf = g4[1][b][jl] + bih[Dh+j]   + bhh[Dh+j];
        float pg = g4[2][b][jl] + bih[2*Dh+j] + bhh[2*Dh+j];
        float po = g4[3][b][jl] + bih[3*Dh+j] + bhh[3*Dh+j];
        float cold = cst[j*16 + b];
        float cnew = sigm(pf)*cold + sigm(pi)*tanhf(pg);
        float h    = sigm(po)*tanhf(cnew);
        cst[j*16 + b] = cnew;
        unsigned short hb16 = f2bf(h);
        hrec[(size_t)b*SAh + j] = hb16;
        if (yo)  yo[(size_t)b*1152 + j] = hb16;
        if (x3o) x3o[(size_t)b*400 + j] = h;
    }
}

// ---------------------------------------------------------------------------
// dvec[j] = Wx[j,:]·decb ; bvec[j] = Wx[j,:]·b2 ; wtd[j] = odeW1[j,0]
__global__ __launch_bounds__(256) void vecs_k(const float* __restrict__ odeW1,
                                              const float* __restrict__ decb,
                                              const float* __restrict__ b2v,
                                              float* __restrict__ dvec,
                                              float* __restrict__ bvec,
                                              float* __restrict__ wtd)
{
    int jrow = blockIdx.x;
    __shared__ float r1[256], r2[256];
    const float* wx = odeW1 + (size_t)jrow*W1S_ + 1;
    float s1 = 0.f, s2 = 0.f;
    for (int v = threadIdx.x; v < NT_; v += 256){
        float w = wx[v]; s1 += w*decb[v]; s2 += w*b2v[v];
    }
    r1[threadIdx.x] = s1; r2[threadIdx.x] = s2; __syncthreads();
    for (int s = 128; s > 0; s >>= 1){
        if (threadIdx.x < s){ r1[threadIdx.x] += r1[threadIdx.x+s]; r2[threadIdx.x] += r2[threadIdx.x+s]; }
        __syncthreads();
    }
    if (threadIdx.x == 0){ dvec[jrow] = r1[0]; bvec[jrow] = r2[0]; wtd[jrow] = odeW1[(size_t)jrow*W1S_]; }
}

// ---------------------------------------------------------------------------
// Fused P|Q: C[m=400][n=800] = Wx[400][32000] @ Bbf[32000][800], 8 K-slabs.
// 8x8 per-thread tiles, fp32 VALU (Bbf is k-major -> MFMA would need transpose).
__global__ __launch_bounds__(256) void gemm_ode2_k(const unsigned short* __restrict__ Wxbf,
                                                   const unsigned short* __restrict__ Bbf,
                                                   float* __restrict__ partials)
{
    __shared__ float As[8][132];
    __shared__ float Bs[8][136];
    int n0 = blockIdx.x*128, m0 = blockIdx.y*128, v0 = blockIdx.z*4000;
    int tid = threadIdx.x;
    int tx = tid & 15, ty = tid >> 4;
    int mA = tid >> 1, kA = (tid & 1)*4;
    int vB = tid >> 5, nB = (tid & 31)*4;
    int mGA = m0 + mA;
    bool aok = mGA < 400;
    int nG = n0 + nB;
    bool bok = nG < 800;
    const unsigned short* aptr = aok ? (Wxbf + (size_t)mGA*NT_ + v0 + kA) : Wxbf;
    const unsigned short* bptr = Bbf + (size_t)(v0 + vB)*800 + (bok ? nG : 0);
    float acc[8][8] = {};
    for (int kk = 0; kk < 4000; kk += 8){
        float4 af = {0.f,0.f,0.f,0.f}, bq = {0.f,0.f,0.f,0.f};
        {
            ushort4 ua = *(const ushort4*)(aptr + kk);
            if (aok){ af.x=bfu(ua.x); af.y=bfu(ua.y); af.z=bfu(ua.z); af.w=bfu(ua.w); }
        }
        {
            ushort4 ub = *(const ushort4*)(bptr + (size_t)kk*800);
            if (bok){ bq.x=bfu(ub.x); bq.y=bfu(ub.y); bq.z=bfu(ub.z); bq.w=bfu(ub.w); }
        }
        __syncthreads();   // previous iteration's reads done
        As[kA+0][mA] = af.x; As[kA+1][mA] = af.y; As[kA+2][mA] = af.z; As[kA+3][mA] = af.w;
        *(float4*)&Bs[vB][nB] = bq;
        __syncthreads();
        #pragma unroll
        for (int k = 0; k < 8; ++k){
            float a[8], b[8];
            *(float4*)&a[0] = *(const float4*)&As[k][tx*8];
            *(float4*)&a[4] = *(const float4*)&As[k][tx*8+4];
            *(float4*)&b[0] = *(const float4*)&Bs[k][ty*8];
            *(float4*)&b[4] = *(const float4*)&Bs[k][ty*8+4];
            #pragma unroll
            for (int i = 0; i < 8; ++i)
                #pragma unroll
                for (int jj = 0; jj < 8; ++jj) acc[i][jj] += a[i]*b[jj];
        }
    }
    float* op = partials + (size_t)blockIdx.z*320000;
    #pragma unroll
    for (int i = 0; i < 8; ++i){
        int m = m0 + tx*8 + i; if (m >= 400) continue;
        #pragma unroll
        for (int jj = 0; jj < 8; ++jj){
            int n = n0 + ty*8 + jj; if (n >= 800) continue;
            op[m*800 + n] = acc[i][jj];
        }
    }
}

// sum 8 slabs; scatter C[:,0:400]->Q, C[:,400:800]->P
__global__ __launch_bounds__(256) void reduce8_k(const float* __restrict__ p,
                                                 float* __restrict__ Q, float* __restrict__ P)
{
    int i = blockIdx.x*256 + threadIdx.x;
    if (i >= 320000) return;
    float s = 0.f;
    #pragma unroll
    for (int k = 0; k < 8; ++k) s += p[(size_t)k*320000 + i];
    int m = i / 800, n = i - m*800;
    if (n < 400) Q[m*400 + n] = s;
    else         P[m*400 + (n-400)] = s;
}

// ---------------------------------------------------------------------------
// OUT[m,n] = maybe_softplus( dotc*sum_k A[m,k]*B[n,k] + Gbase + vcoef*vec[n] + tval*wt[n] + b1[n] )
__global__ __launch_bounds__(256) void fused_small_k(
    const float* __restrict__ A, const float* __restrict__ Bm,
    const float* __restrict__ Gbase, float* __restrict__ OUT,
    const float* __restrict__ vec, float vcoef,
    const float* __restrict__ wt, float tval,
    const float* __restrict__ b1, float dotc, int do_sp)
{
    __shared__ float As[16][68];
    __shared__ float Bs[16][68];
    int m0 = blockIdx.y*64, n0 = blockIdx.x*64;
    int tid = threadIdx.x, tx = tid & 15, ty = tid >> 4;
    int row = tid >> 2, kq = tid & 3;
    float acc[4][4] = {};
    for (int k0 = 0; k0 < 400; k0 += 16){
        int m = m0 + row;
        if (m < SB_){
            float4 va = *(const float4*)(A + (size_t)m*400 + k0 + kq*4);
            As[kq*4+0][row] = va.x; As[kq*4+1][row] = va.y;
            As[kq*4+2][row] = va.z; As[kq*4+3][row] = va.w;
        } else {
            As[kq*4+0][row] = 0.f; As[kq*4+1][row] = 0.f;
            As[kq*4+2][row] = 0.f; As[kq*4+3][row] = 0.f;
        }
        int n = n0 + row;
        if (n < 400){
            float4 vb = *(const float4*)(Bm + (size_t)n*400 + k0 + kq*4);
            Bs[kq*4+0][row] = vb.x; Bs[kq*4+1][row] = vb.y;
            Bs[kq*4+2][row] = vb.z; Bs[kq*4+3][row] = vb.w;
        } else {
            Bs[kq*4+0][row] = 0.f; Bs[kq*4+1][row] = 0.f;
            Bs[kq*4+2][row] = 0.f; Bs[kq*4+3][row] = 0.f;
        }
        __syncthreads();
        #pragma unroll
        for (int k = 0; k < 16; ++k){
            float4 a4 = *(const float4*)&As[k][tx*4];
            float4 b4 = *(const float4*)&Bs[k][ty*4];
            float av[4] = {a4.x,a4.y,a4.z,a4.w};
            float bv[4] = {b4.x,b4.y,b4.z,b4.w};
            #pragma unroll
            for (int i = 0; i < 4; ++i)
                #pragma unroll
                for (int jj = 0; jj < 4; ++jj) acc[i][jj] += av[i]*bv[jj];
        }
        __syncthreads();
    }
    #pragma unroll
    for (int i = 0; i < 4; ++i){
        int m = m0 + tx*4 + i; if (m >= SB_) continue;
        #pragma unroll
        for (int jj = 0; jj < 4; ++jj){
            int n = n0 + ty*4 + jj; if (n >= 400) continue;
            float s = dotc*acc[i][jj];
            if (Gbase) s += Gbase[(size_t)m*400 + n];
            if (vec)   s += vcoef*vec[n];
            if (wt)    s += tval*wt[n];
            if (b1)    s += b1[n];
            OUT[(size_t)m*400 + n] = do_sp ? softplusf(s) : s;
        }
    }
}

// H = softplus(Gy + t*wt + b1)
__global__ __launch_bounds__(256) void stage1_k(const float* __restrict__ Gy, float* __restrict__ H,
                                                const float* __restrict__ wt, float tval,
                                                const float* __restrict__ b1)
{
    int sb = blockIdx.x;
    for (int n = threadIdx.x; n < 400; n += 256){
        float s = Gy[(size_t)sb*400 + n] + tval*wt[n] + b1[n];
        H[(size_t)sb*400 + n] = softplusf(s);
    }
}

// Hs = dt/6*(H1+2H2+2H3+H4); Hacc += Hs
__global__ __launch_bounds__(256) void hs_k(const float* __restrict__ H1, const float* __restrict__ H2,
                                            const float* __restrict__ H3, const float* __restrict__ H4,
                                            float* __restrict__ Hs, float* __restrict__ Hacc, int n)
{
    int i = blockIdx.x*256 + threadIdx.x;
    if (i < n){
        float v = (1.f/12.f)*(H1[i] + 2.f*H2[i] + 2.f*H3[i] + H4[i]);  // dt/6 = 0.5/6
        Hs[i] = v;
        Hacc[i] += v;
    }
}

// ---------------------------------------------------------------------------
// MFMA decode: z[m,v] = Abf[m,:]·Bbf[v,:] + decb[v] + b2[v]   (M=1120,N=32000,K=800)
__global__ __launch_bounds__(256) void decode_mfma_k(
    const unsigned short* __restrict__ Abf,
    const unsigned short* __restrict__ Bbf,
    const float* __restrict__ decb, const float* __restrict__ b2v,
    float* __restrict__ z)
{
    __shared__ unsigned short As[128*40];
    __shared__ unsigned short Bs[128*40];
    int n0 = blockIdx.x*128, m0 = blockIdx.y*128;
    int tid = threadIdx.x;
    int lane = tid & 63, wid = tid >> 6;
    int wr = wid >> 1, wc = wid & 1;
    f32x4 acc[4][4] = {};

    int srow = tid >> 1;           // 0..127
    int sk   = (tid & 1) * 16;     // 0 or 16

    for (int k0 = 0; k0 < 800; k0 += 32){
        uint4 av0 = {0,0,0,0}, av1 = {0,0,0,0};
        int m = m0 + srow;
        if (m < SB_){
            const uint4* ap = (const uint4*)(Abf + (size_t)m*800 + k0 + sk);
            av0 = ap[0]; av1 = ap[1];
        }
        const uint4* bp = (const uint4*)(Bbf + (size_t)(n0 + srow)*800 + k0 + sk);
        uint4 bv0 = bp[0], bv1 = bp[1];

        __syncthreads();
        *(uint4*)&As[srow*40 + sk]     = av0;
        *(uint4*)&As[srow*40 + sk + 8] = av1;
        *(uint4*)&Bs[srow*40 + sk]     = bv0;
        *(uint4*)&Bs[srow*40 + sk + 8] = bv1;
        __syncthreads();

        int kq = (lane >> 4) * 8;
        int rA = wr*64 + (lane & 15);
        int rB = wc*64 + (lane & 15);
        bf16x8 af[4], bfv[4];
        #pragma unroll
        for (int f = 0; f < 4; ++f){
            af[f]  = *(const bf16x8*)&As[(rA + f*16)*40 + kq];
            bfv[f] = *(const bf16x8*)&Bs[(rB + f*16)*40 + kq];
        }
        #pragma unroll
        for (int fm = 0; fm < 4; ++fm)
            #pragma unroll
            for (int fn = 0; fn < 4; ++fn)
                acc[fm][fn] = __builtin_amdgcn_mfma_f32_16x16x32_bf16(af[fm], bfv[fn], acc[fm][fn], 0, 0, 0);
    }

    int cm = (lane >> 4) * 4;
    int cn = lane & 15;
    #pragma unroll
    for (int fm = 0; fm < 4; ++fm){
        int mrow0 = m0 + wr*64 + fm*16 + cm;
        #pragma unroll
        for (int fn = 0; fn < 4; ++fn){
            int n = n0 + wc*64 + fn*16 + cn;
            float db = decb[n] + b2v[n];
            #pragma unroll
            for (int r = 0; r < 4; ++r){
                int mr = mrow0 + r;
                if (mr < SB_) z[(size_t)mr*NT_ + n] = acc[fm][fn][r] + db;
            }
        }
    }
}

// per-row max and sum(exp(z-max))
__global__ __launch_bounds__(256) void rowred_k(const float* __restrict__ z,
                                                float* __restrict__ rowm, float* __restrict__ rowsum)
{
    int r = blockIdx.x;
    const float* zr = z + (size_t)r*NT_;
    __shared__ float sm[256];
    float m = -1e30f;
    for (int v = threadIdx.x; v < NT_; v += 256) m = fmaxf(m, zr[v]);
    sm[threadIdx.x] = m; __syncthreads();
    for (int s = 128; s > 0; s >>= 1){
        if (threadIdx.x < s) sm[threadIdx.x] = fmaxf(sm[threadIdx.x], sm[threadIdx.x+s]);
        __syncthreads();
    }
    m = sm[0]; __syncthreads();
    float s = 0.f;
    for (int v = threadIdx.x; v < NT_; v += 256) s += __expf(zr[v] - m);
    sm[threadIdx.x] = s; __syncthreads();
    for (int st = 128; st > 0; st >>= 1){
        if (threadIdx.x < st) sm[threadIdx.x] += sm[threadIdx.x+st];
        __syncthreads();
    }
    if (threadIdx.x == 0){ rowm[r] = m; rowsum[r] = sm[0]; }
}

// out = log(exp(z-m)/S + 1e-8), in place
__global__ __launch_bounds__(256) void finalmap_k(float* __restrict__ z,
                                                  const float* __restrict__ rowm,
                                                  const float* __restrict__ rowsum)
{
    int r = blockIdx.y;
    int v = (blockIdx.x*256 + threadIdx.x)*4;
    if (v >= NT_) return;
    float m = rowm[r];
    float sinv = 1.f/rowsum[r];
    float4* p = (float4*)(z + (size_t)r*NT_ + v);
    float4 x = *p;
    x.x = logf(__expf(x.x - m)*sinv + 1e-8f);
    x.y = logf(__expf(x.y - m)*sinv + 1e-8f);
    x.z = logf(__expf(x.z - m)*sinv + 1e-8f);
    x.w = logf(__expf(x.w - m)*sinv + 1e-8f);
    *p = x;
}

// ---------------------------------------------------------------------------
extern "C" void kernel_launch(void* const* d_in, const int* in_sizes, int n_in,
                              void* d_out, int out_size, void* d_ws, size_t ws_size,
                              hipStream_t stream)
{
    const int*   tokens = (const int*)  d_in[0];
    const float* h0_0 = (const float*)d_in[1];
    const float* c0_0 = (const float*)d_in[2];
    const float* Wih0 = (const float*)d_in[3];
    const float* Whh0 = (const float*)d_in[4];
    const float* bih0 = (const float*)d_in[5];
    const float* bhh0 = (const float*)d_in[6];
    const float* h0_1 = (const float*)d_in[7];
    const float* c0_1 = (const float*)d_in[8];
    const float* Wih1 = (const float*)d_in[9];
    const float* Whh1 = (const float*)d_in[10];
    const float* bih1 = (const float*)d_in[11];
    const float* bhh1 = (const float*)d_in[12];
    const float* h0_2 = (const float*)d_in[13];
    const float* c0_2 = (const float*)d_in[14];
    const float* Wih2 = (const float*)d_in[15];
    const float* Whh2 = (const float*)d_in[16];
    const float* bih2 = (const float*)d_in[17];
    const float* bhh2 = (const float*)d_in[18];
    const float* emb  = (const float*)d_in[19];
    const float* decW = (const float*)d_in[20];
    const float* decb = (const float*)d_in[21];
    const float* odeW1= (const float*)d_in[22];
    const float* odeb1= (const float*)d_in[23];
    const float* odeW2= (const float*)d_in[24];
    const float* odeb2= (const float*)d_in[25];

    // workspace carve-up (~156 MB), all chunks 16B-aligned
    float* w = (float*)d_ws;
    size_t off = 0;
    auto alloc = [&](size_t n){ float* p = w + off; off += n; return p; };
    auto allocU = [&](size_t nUsh){ return (unsigned short*)alloc(nUsh/2); };  // nUsh mult of 8
    unsigned short* x0A  = allocU((size_t)S_*16*416);
    unsigned short* ys0A = allocU((size_t)S_*16*1152);
    unsigned short* ys1A = allocU((size_t)S_*16*1152);
    float* x3   = alloc((size_t)SB_*400);
    unsigned short* h0b = allocU((size_t)2*16*1152); float* c0b = alloc(1152*16);
    unsigned short* h1b = allocU((size_t)2*16*1152); float* c1b = alloc(1152*16);
    unsigned short* h2b = allocU((size_t)2*16*416);  float* c2b = alloc(416*16);
    float* P    = alloc(160000);
    float* Q    = alloc(160000);
    float* dvec = alloc(512);
    float* bvec = alloc(512);
    float* wtd  = alloc(512);
    float* Gy   = alloc((size_t)SB_*400);
    float* Hacc = alloc((size_t)SB_*400);
    float* H1   = alloc((size_t)SB_*400);
    float* H2   = alloc((size_t)SB_*400);
    float* H3   = alloc((size_t)SB_*400);
    float* H4   = alloc((size_t)SB_*400);
    float* Hs   = alloc((size_t)SB_*400);
    float* rowm = alloc(1280);   // >= SB_ !  (round-3 bug: was 512 -> rowred_k overflow)
    float* rsum = alloc(1280);   // >= SB_ !
    float* partials = alloc((size_t)8*320000);
    unsigned short* Wih0p = allocU((size_t)4600*416);
    unsigned short* Whh0p = allocU((size_t)4600*1152);
    unsigned short* Wih1p = allocU((size_t)4600*1152);
    unsigned short* Whh1p = allocU((size_t)4600*1152);
    unsigned short* Wih2p = allocU((size_t)1600*1152);
    unsigned short* Whh2p = allocU((size_t)1600*416);
    unsigned short* Abf   = allocU((size_t)SB_*800);
    unsigned short* Bbf   = allocU((size_t)NT_*800);
    unsigned short* Wxbf  = allocU((size_t)400*NT_);
    (void)ws_size; (void)in_sizes; (void)n_in; (void)out_size;

    float* zout = (float*)d_out;

    hipMemsetAsync(Hacc, 0, (size_t)SB_*400*sizeof(float), stream);
    // zero activation buffers once per call: pad columns are read by MFMA and
    // multiplied by zero weight pads — must not contain NaN bit patterns.
    hipMemsetAsync(ys0A, 0, (size_t)S_*16*1152*2, stream);
    hipMemsetAsync(ys1A, 0, (size_t)S_*16*1152*2, stream);
    hipMemsetAsync(h0b,  0, (size_t)2*16*1152*2, stream);
    hipMemsetAsync(h1b,  0, (size_t)2*16*1152*2, stream);
    hipMemsetAsync(h2b,  0, (size_t)2*16*416*2, stream);

    // weight conversions (bf16, K zero-padded)
    auto cvtgrid = [](long long n){ return (unsigned)((n + 255) / 256); };
    cvt_pack_w_k<<<cvtgrid((long long)4600*416),  256, 0, stream>>>(Wih0, Wih0p, 4600, 400, 416);
    cvt_pack_w_k<<<cvtgrid((long long)4600*1152), 256, 0, stream>>>(Whh0, Whh0p, 4600, 1150, 1152);
    cvt_pack_w_k<<<cvtgrid((long long)4600*1152), 256, 0, stream>>>(Wih1, Wih1p, 4600, 1150, 1152);
    cvt_pack_w_k<<<cvtgrid((long long)4600*1152), 256, 0, stream>>>(Whh1, Whh1p, 4600, 1150, 1152);
    cvt_pack_w_k<<<cvtgrid((long long)1600*1152), 256, 0, stream>>>(Wih2, Wih2p, 1600, 1150, 1152);
    cvt_pack_w_k<<<cvtgrid((long long)1600*416),  256, 0, stream>>>(Whh2, Whh2p, 1600, 400, 416);
    cvt_catB_k<<<cvtgrid((long long)NT_*800), 256, 0, stream>>>(decW, odeW2, Bbf);
    cvt_wx_k<<<cvtgrid((long long)400*NT_), 256, 0, stream>>>(odeW1, Wxbf);

    // activations + state init
    embed_bf_k<<<S_, 256, 0, stream>>>(tokens, emb, x0A);
    cvt_h0_k<<<(16*1150+255)/256, 256, 0, stream>>>(h0_0, h0b, 1150, 1152);
    cvt_h0_k<<<(16*1150+255)/256, 256, 0, stream>>>(h0_1, h1b, 1150, 1152);
    cvt_h0_k<<<(16*400+255)/256,  256, 0, stream>>>(h0_2, h2b, 400, 416);
    transpose16_k<<<(1150*16+255)/256, 256, 0, stream>>>(c0_0, c0b, 1150);
    transpose16_k<<<(1150*16+255)/256, 256, 0, stream>>>(c0_1, c1b, 1150);
    transpose16_k<<<(400*16+255)/256,  256, 0, stream>>>(c0_2, c2b, 400);

    // 3-layer LSTM, layer-pipelined wavefront, MFMA
    for (int u = 0; u < S_ + 2; ++u)
        lstm_mfma_k<<<169, 256, 0, stream>>>(u, x0A, ys0A, ys1A, x3,
            h0b, c0b, h1b, c1b, h2b, c2b,
            Wih0p, Whh0p, bih0, bhh0, Wih1p, Whh1p, bih1, bhh1, Wih2p, Whh2p, bih2, bhh2);

    // ODE factorization precompute: [Q|P] = Wx @ Bbf (fused), vecs
    vecs_k<<<400, 256, 0, stream>>>(odeW1, decb, odeb2, dvec, bvec, wtd);
    gemm_ode2_k<<<dim3(7,4,8), 256, 0, stream>>>(Wxbf, Bbf, partials);
    reduce8_k<<<(320000+255)/256, 256, 0, stream>>>(partials, Q, P);

    // G0 = x3 @ Q^T + dvec
    fused_small_k<<<dim3(7,18), 256, 0, stream>>>(x3, Q, nullptr, Gy,
        dvec, 1.f, nullptr, 0.f, nullptr, 1.f, 0);

    // RK4 in G-space, 2 steps, dt = 0.5
    const float dt = 0.5f;
    for (int n = 0; n < 2; ++n){
        float t0 = n * dt;
        stage1_k<<<SB_, 256, 0, stream>>>(Gy, H1, wtd, t0, odeb1);
        fused_small_k<<<dim3(7,18), 256, 0, stream>>>(H1, P, Gy, H2,
            bvec, 0.25f, wtd, t0 + 0.25f, odeb1, 0.25f, 1);
        fused_small_k<<<dim3(7,18), 256, 0, stream>>>(H2, P, Gy, H3,
            bvec, 0.25f, wtd, t0 + 0.25f, odeb1, 0.25f, 1);
        fused_small_k<<<dim3(7,18), 256, 0, stream>>>(H3, P, Gy, H4,
            bvec, 0.5f, wtd, t0 + 0.5f, odeb1, 0.5f, 1);
        hs_k<<<((SB_*400)+255)/256, 256, 0, stream>>>(H1, H2, H3, H4, Hs, Hacc, SB_*400);
        if (n == 0)
            fused_small_k<<<dim3(7,18), 256, 0, stream>>>(Hs, P, Gy, Gy,
                bvec, dt, nullptr, 0.f, nullptr, 1.f, 0);
    }

    // A-concat (x3|Hacc) -> bf16, MFMA decode, log-softmax in place
    cvt_catA_k<<<cvtgrid((long long)SB_*800), 256, 0, stream>>>(x3, Hacc, Abf);
    decode_mfma_k<<<dim3(250,9), 256, 0, stream>>>(Abf, Bbf, decb, odeb2, zout);
    rowred_k<<<SB_, 256, 0, stream>>>(zout, rowm, rsum);
    finalmap_k<<<dim3(32,SB_), 256, 0, stream>>>(zout, rowm, rsum);
}

// Round 5
// 2375.414 us; speedup vs baseline: 3.6213x; 1.2789x over previous
//
#include <hip/hip_runtime.h>
#include <math.h>

// Problem dims
constexpr int S_   = 70;
constexpr int B_   = 16;
constexpr int SB_  = 1120;     // S*B
constexpr int NT_  = 32000;    // NTOKEN
constexpr int W1S_ = 32001;    // odeW1 row stride (NTOKEN+1)

typedef __attribute__((ext_vector_type(8))) short bf16x8;
typedef __attribute__((ext_vector_type(4))) float f32x4;

__device__ __forceinline__ float sigm(float x){ return 1.f/(1.f+__expf(-x)); }
__device__ __forceinline__ float softplusf(float x){ return x > 15.f ? x : log1pf(__expf(x)); }

__device__ __forceinline__ unsigned short f2bf(float f){
    union{float f; unsigned u;} c; c.f = f;
    unsigned u = c.u;
    unsigned r = (u + 0x7fffu + ((u >> 16) & 1u)) >> 16;
    return (unsigned short)r;
}
__device__ __forceinline__ float bfu(unsigned short us){
    union{unsigned u; float f;} c; c.u = ((unsigned)us) << 16; return c.f;
}

// ---------------------------------------------------------------------------
// fp32 [R][K] -> bf16 [R][Kp], zero-padded in K
__global__ __launch_bounds__(256) void cvt_pack_w_k(const float* __restrict__ src,
                                                    unsigned short* __restrict__ dst,
                                                    int R, int K, int Kp)
{
    long long idx = (long long)blockIdx.x*256 + threadIdx.x;
    long long tot = (long long)R*Kp;
    if (idx >= tot) return;
    int r = (int)(idx / Kp), kk = (int)(idx - (long long)r*Kp);
    float v = (kk < K) ? src[(size_t)r*K + kk] : 0.f;
    dst[idx] = f2bf(v);
}

// Abf[1120][800]: k<400 -> x3[m][k], else Hacc[m][k-400]
__global__ __launch_bounds__(256) void cvt_catA_k(const float* __restrict__ x3,
                                                  const float* __restrict__ Hacc,
                                                  unsigned short* __restrict__ Abf)
{
    int idx = blockIdx.x*256 + threadIdx.x;
    if (idx >= SB_*800) return;
    int m = idx / 800, k = idx - m*800;
    float v = (k < 400) ? x3[(size_t)m*400 + k] : Hacc[(size_t)m*400 + (k-400)];
    Abf[idx] = f2bf(v);
}

// Bbf[32000][800]: k<400 -> decW[v][k], else odeW2[v][k-400]
__global__ __launch_bounds__(256) void cvt_catB_k(const float* __restrict__ decW,
                                                  const float* __restrict__ odeW2,
                                                  unsigned short* __restrict__ Bbf)
{
    long long idx = (long long)blockIdx.x*256 + threadIdx.x;
    if (idx >= (long long)NT_*800) return;
    int v = (int)(idx / 800), k = (int)(idx - (long long)v*800);
    float x = (k < 400) ? decW[(size_t)v*400 + k] : odeW2[(size_t)v*400 + (k-400)];
    Bbf[idx] = f2bf(x);
}

// BbfT[800][32000]: BbfT[n][v] = bf16(n<400 ? decW[v][n] : odeW2[v][n-400])
// tiled transpose: 64 v x 32 n per block
__global__ __launch_bounds__(256) void cvt_catBT_k(const float* __restrict__ decW,
                                                   const float* __restrict__ odeW2,
                                                   unsigned short* __restrict__ BbfT)
{
    __shared__ unsigned short tile[32][72];
    int v0 = blockIdx.x*64, n0 = blockIdx.y*32;
    int tx = threadIdx.x & 31;        // n offset (load phase)
    int vy = threadIdx.x >> 5;        // 0..7
    #pragma unroll
    for (int i = 0; i < 8; ++i){
        int v = v0 + i*8 + vy;
        int n = n0 + tx;
        float val = (n < 400) ? decW[(size_t)v*400 + n] : odeW2[(size_t)v*400 + (n-400)];
        tile[tx][v - v0] = f2bf(val);
    }
    __syncthreads();
    int vx = threadIdx.x & 63;
    int ny = threadIdx.x >> 6;        // 0..3
    #pragma unroll
    for (int i = 0; i < 8; ++i){
        int n = n0 + i*4 + ny;
        BbfT[(size_t)n*NT_ + v0 + vx] = tile[n - n0][vx];
    }
}

// Wxbf[400][32000] = bf16(odeW1[:,1:])
__global__ __launch_bounds__(256) void cvt_wx_k(const float* __restrict__ odeW1,
                                                unsigned short* __restrict__ Wxbf)
{
    long long idx = (long long)blockIdx.x*256 + threadIdx.x;
    if (idx >= (long long)400*NT_) return;
    int m = (int)(idx / NT_), v = (int)(idx - (long long)m*NT_);
    Wxbf[idx] = f2bf(odeW1[(size_t)m*W1S_ + 1 + v]);
}

// ---------------------------------------------------------------------------
// Embedding gather -> bf16 A-layout: x0A[t][b][k] (stride 416, zero-padded)
__global__ __launch_bounds__(256) void embed_bf_k(const int* __restrict__ tok,
                                                  const float* __restrict__ emb,
                                                  unsigned short* __restrict__ x0A)
{
    int t = blockIdx.x;
    __shared__ int tk[16];
    if (threadIdx.x < 16) tk[threadIdx.x] = tok[t*16 + threadIdx.x];
    __syncthreads();
    for (int idx = threadIdx.x; idx < 16*416; idx += 256){
        int b = idx / 416, k = idx - b*416;
        float v = (k < 400) ? emb[(size_t)tk[b]*400 + k] : 0.f;
        x0A[(size_t)t*16*416 + idx] = f2bf(v);
    }
}

// dst[j*16+b] = src[b*dh+j]  (c-state init)
__global__ __launch_bounds__(256) void transpose16_k(const float* __restrict__ src,
                                                     float* __restrict__ dst, int dh)
{
    int idx = blockIdx.x*256 + threadIdx.x;
    if (idx < dh*16){ int j = idx >> 4, b = idx & 15; dst[idx] = src[b*dh + j]; }
}

// h0 [16][Dh] fp32 -> hb [16][SA] bf16 (parity-0 buffer; pads pre-zeroed by memset)
__global__ __launch_bounds__(256) void cvt_h0_k(const float* __restrict__ h0,
                                                unsigned short* __restrict__ hb, int Dh, int SA)
{
    int idx = blockIdx.x*256 + threadIdx.x;
    if (idx >= 16*Dh) return;
    int b = idx / Dh, j = idx - b*Dh;
    hb[(size_t)b*SA + j] = f2bf(h0[idx]);
}

// ---------------------------------------------------------------------------
// One wavefront step of the 3-layer LSTM pipeline, MFMA, K-split occupancy.
// Block = one 16-unit j-tile; 8 waves = 4 gates x 2 K-halves (512 threads).
__global__ __launch_bounds__(512) void lstm_mfma_k(int u,
    const unsigned short* __restrict__ x0A,
    unsigned short* __restrict__ ys0A, unsigned short* __restrict__ ys1A,
    float* __restrict__ x3,
    unsigned short* __restrict__ h0b, float* __restrict__ c0,
    unsigned short* __restrict__ h1b, float* __restrict__ c1,
    unsigned short* __restrict__ h2b, float* __restrict__ c2,
    const unsigned short* __restrict__ Wih0p, const unsigned short* __restrict__ Whh0p,
    const float* __restrict__ bih0, const float* __restrict__ bhh0,
    const unsigned short* __restrict__ Wih1p, const unsigned short* __restrict__ Whh1p,
    const float* __restrict__ bih1, const float* __restrict__ bhh1,
    const unsigned short* __restrict__ Wih2p, const unsigned short* __restrict__ Whh2p,
    const float* __restrict__ bih2, const float* __restrict__ bhh2)
{
    int blk = blockIdx.x;
    int layer, jt;
    if      (blk < 72) { layer = 0; jt = blk; }
    else if (blk < 144){ layer = 1; jt = blk - 72; }
    else               { layer = 2; jt = blk - 144; }
    int t = u - layer;
    if (t < 0 || t >= S_) return;
    int j0 = jt*16;

    const unsigned short *Ax, *Ah, *Wi, *Wh;
    const float *bih, *bhh;
    float *cst, *x3o = nullptr;
    unsigned short *yo = nullptr, *hrec;
    int Kx, Kh, Dh, SAx, SAh;
    if (layer == 0){
        Ax = x0A + (size_t)t*16*416; SAx = 416; Kx = 416;
        Ah = h0b + (size_t)(t&1)*16*1152; SAh = 1152; Kh = 1152;
        Wi = Wih0p; Wh = Whh0p; bih = bih0; bhh = bhh0; Dh = 1150;
        cst = c0; hrec = h0b + (size_t)((t+1)&1)*16*1152;
        yo = ys0A + (size_t)t*16*1152;
    } else if (layer == 1){
        Ax = ys0A + (size_t)t*16*1152; SAx = 1152; Kx = 1152;
        Ah = h1b + (size_t)(t&1)*16*1152; SAh = 1152; Kh = 1152;
        Wi = Wih1p; Wh = Whh1p; bih = bih1; bhh = bhh1; Dh = 1150;
        cst = c1; hrec = h1b + (size_t)((t+1)&1)*16*1152;
        yo = ys1A + (size_t)t*16*1152;
    } else {
        Ax = ys1A + (size_t)t*16*1152; SAx = 1152; Kx = 1152;
        Ah = h2b + (size_t)(t&1)*16*416; SAh = 416; Kh = 416;
        Wi = Wih2p; Wh = Whh2p; bih = bih2; bhh = bhh2; Dh = 400;
        cst = c2; hrec = h2b + (size_t)((t+1)&1)*16*416;
        x3o = x3 + (size_t)t*16*400;
    }

    int lane = threadIdx.x & 63, w = threadIdx.x >> 6;   // w = 0..7
    int gate = w & 3, khalf = w >> 2;
    int am = lane & 15;           // A row (batch)
    int kq = (lane >> 4) * 8;     // k offset within 32-step
    int jn = lane & 15;           // B row (local j)
    int jrow = j0 + jn; if (jrow > Dh-1) jrow = Dh-1;    // clamp (dup rows discarded on write)

    const unsigned short* ax = Ax + (size_t)am*SAx;
    const unsigned short* ah = Ah + (size_t)am*SAh;
    const unsigned short* wx = Wi + (size_t)(gate*Dh + jrow)*SAx;
    const unsigned short* wh = Wh + (size_t)(gate*Dh + jrow)*SAh;

    // K-split: wave khalf takes [xs,xe) of x-part and [hs,he) of h-part (32-mult)
    int cxa = ((Kx >> 5) + 1) >> 1;
    int xs = khalf ? cxa*32 : 0;
    int xe = khalf ? Kx : cxa*32;
    int cha = ((Kh >> 5) + 1) >> 1;
    int hs = khalf ? cha*32 : 0;
    int he = khalf ? Kh : cha*32;

    f32x4 acc0 = {0.f,0.f,0.f,0.f}, acc1 = {0.f,0.f,0.f,0.f};
    int k0 = xs;
    for (; k0 + 64 <= xe; k0 += 64){
        bf16x8 a0 = *(const bf16x8*)(ax + k0 + kq);
        bf16x8 b0 = *(const bf16x8*)(wx + k0 + kq);
        acc0 = __builtin_amdgcn_mfma_f32_16x16x32_bf16(a0, b0, acc0, 0,0,0);
        bf16x8 a1 = *(const bf16x8*)(ax + k0 + 32 + kq);
        bf16x8 b1 = *(const bf16x8*)(wx + k0 + 32 + kq);
        acc1 = __builtin_amdgcn_mfma_f32_16x16x32_bf16(a1, b1, acc1, 0,0,0);
    }
    if (k0 < xe){
        bf16x8 a0 = *(const bf16x8*)(ax + k0 + kq);
        bf16x8 b0 = *(const bf16x8*)(wx + k0 + kq);
        acc0 = __builtin_amdgcn_mfma_f32_16x16x32_bf16(a0, b0, acc0, 0,0,0);
    }
    k0 = hs;
    for (; k0 + 64 <= he; k0 += 64){
        bf16x8 a0 = *(const bf16x8*)(ah + k0 + kq);
        bf16x8 b0 = *(const bf16x8*)(wh + k0 + kq);
        acc0 = __builtin_amdgcn_mfma_f32_16x16x32_bf16(a0, b0, acc0, 0,0,0);
        bf16x8 a1 = *(const bf16x8*)(ah + k0 + 32 + kq);
        bf16x8 b1 = *(const bf16x8*)(wh + k0 + 32 + kq);
        acc1 = __builtin_amdgcn_mfma_f32_16x16x32_bf16(a1, b1, acc1, 0,0,0);
    }
    if (k0 < he){
        bf16x8 a0 = *(const bf16x8*)(ah + k0 + kq);
        bf16x8 b0 = *(const bf16x8*)(wh + k0 + kq);
        acc0 = __builtin_amdgcn_mfma_f32_16x16x32_bf16(a0, b0, acc0, 0,0,0);
    }
    f32x4 acc = acc0 + acc1;

    // C/D: row m = (lane>>4)*4 + r (batch), col = lane&15 (local j)
    __shared__ float g8[8][16][17];
    int bm = (lane >> 4) * 4;
    #pragma unroll
    for (int r = 0; r < 4; ++r) g8[w][bm + r][jn] = acc[r];
    __syncthreads();

    if (threadIdx.x < 256){
        int jl = threadIdx.x >> 4, b = threadIdx.x & 15;
        int j = j0 + jl;
        if (j < Dh){
            float pi = g8[0][b][jl] + g8[4][b][jl] + bih[j]      + bhh[j];
            float pf = g8[1][b][jl] + g8[5][b][jl] + bih[Dh+j]   + bhh[Dh+j];
            float pg = g8[2][b][jl] + g8[6][b][jl] + bih[2*Dh+j] + bhh[2*Dh+j];
            float po = g8[3][b][jl] + g8[7][b][jl] + bih[3*Dh+j] + bhh[3*Dh+j];
            float cold = cst[j*16 + b];
            float cnew = sigm(pf)*cold + sigm(pi)*tanhf(pg);
            float h    = sigm(po)*tanhf(cnew);
            cst[j*16 + b] = cnew;
            unsigned short hb16 = f2bf(h);
            hrec[(size_t)b*SAh + j] = hb16;
            if (yo)  yo[(size_t)b*1152 + j] = hb16;
            if (x3o) x3o[(size_t)b*400 + j] = h;
        }
    }
}

// ---------------------------------------------------------------------------
// dvec[j] = Wx[j,:]·decb ; bvec[j] = Wx[j,:]·b2 ; wtd[j] = odeW1[j,0]
__global__ __launch_bounds__(256) void vecs_k(const float* __restrict__ odeW1,
                                              const float* __restrict__ decb,
                                              const float* __restrict__ b2v,
                                              float* __restrict__ dvec,
                                              float* __restrict__ bvec,
                                              float* __restrict__ wtd)
{
    int jrow = blockIdx.x;
    __shared__ float r1[256], r2[256];
    const float* wx = odeW1 + (size_t)jrow*W1S_ + 1;
    float s1 = 0.f, s2 = 0.f;
    for (int v = threadIdx.x; v < NT_; v += 256){
        float w = wx[v]; s1 += w*decb[v]; s2 += w*b2v[v];
    }
    r1[threadIdx.x] = s1; r2[threadIdx.x] = s2; __syncthreads();
    for (int s = 128; s > 0; s >>= 1){
        if (threadIdx.x < s){ r1[threadIdx.x] += r1[threadIdx.x+s]; r2[threadIdx.x] += r2[threadIdx.x+s]; }
        __syncthreads();
    }
    if (threadIdx.x == 0){ dvec[jrow] = r1[0]; bvec[jrow] = r2[0]; wtd[jrow] = odeW1[(size_t)jrow*W1S_]; }
}

// ---------------------------------------------------------------------------
// MFMA ODE precompute: partials[z][m*800+n] = sum_{v in slab z} Wxbf[m][v]*BbfT[n][v]
// M=400 (4 tiles of 128, clamped), N=800 (7 tiles of 128, clamped), K=32000 (8 slabs)
__global__ __launch_bounds__(256) void gemm_odeT_k(
    const unsigned short* __restrict__ Wxbf,
    const unsigned short* __restrict__ BbfT,
    float* __restrict__ partials)
{
    __shared__ unsigned short As[128*40];
    __shared__ unsigned short Bs[128*40];
    int n0 = blockIdx.x*128, m0 = blockIdx.y*128, v0 = blockIdx.z*4000;
    int tid = threadIdx.x;
    int lane = tid & 63, wid = tid >> 6;
    int wr = wid >> 1, wc = wid & 1;
    f32x4 acc[4][4] = {};

    int srow = tid >> 1;           // 0..127
    int sk   = (tid & 1) * 16;     // 0 or 16
    int mL = m0 + srow; if (mL > 399) mL = 399;
    int nL = n0 + srow; if (nL > 799) nL = 799;
    const unsigned short* ap = Wxbf + (size_t)mL*NT_ + v0 + sk;
    const unsigned short* bp = BbfT + (size_t)nL*NT_ + v0 + sk;

    for (int k0 = 0; k0 < 4000; k0 += 32){
        uint4 av0 = *(const uint4*)(ap + k0);
        uint4 av1 = *(const uint4*)(ap + k0 + 8);
        uint4 bv0 = *(const uint4*)(bp + k0);
        uint4 bv1 = *(const uint4*)(bp + k0 + 8);

        __syncthreads();
        *(uint4*)&As[srow*40 + sk]     = av0;
        *(uint4*)&As[srow*40 + sk + 8] = av1;
        *(uint4*)&Bs[srow*40 + sk]     = bv0;
        *(uint4*)&Bs[srow*40 + sk + 8] = bv1;
        __syncthreads();

        int kq = (lane >> 4) * 8;
        int rA = wr*64 + (lane & 15);
        int rB = wc*64 + (lane & 15);
        bf16x8 af[4], bfv[4];
        #pragma unroll
        for (int f = 0; f < 4; ++f){
            af[f]  = *(const bf16x8*)&As[(rA + f*16)*40 + kq];
            bfv[f] = *(const bf16x8*)&Bs[(rB + f*16)*40 + kq];
        }
        #pragma unroll
        for (int fm = 0; fm < 4; ++fm)
            #pragma unroll
            for (int fn = 0; fn < 4; ++fn)
                acc[fm][fn] = __builtin_amdgcn_mfma_f32_16x16x32_bf16(af[fm], bfv[fn], acc[fm][fn], 0, 0, 0);
    }

    float* op = partials + (size_t)blockIdx.z*320000;
    int cm = (lane >> 4) * 4;
    int cn = lane & 15;
    #pragma unroll
    for (int fm = 0; fm < 4; ++fm){
        int mrow0 = m0 + wr*64 + fm*16 + cm;
        #pragma unroll
        for (int fn = 0; fn < 4; ++fn){
            int n = n0 + wc*64 + fn*16 + cn;
            if (n >= 800) continue;
            #pragma unroll
            for (int r = 0; r < 4; ++r){
                int mr = mrow0 + r;
                if (mr < 400) op[mr*800 + n] = acc[fm][fn][r];
            }
        }
    }
}

// sum 8 slabs; scatter C[:,0:400]->Q, C[:,400:800]->P
__global__ __launch_bounds__(256) void reduce8_k(const float* __restrict__ p,
                                                 float* __restrict__ Q, float* __restrict__ P)
{
    int i = blockIdx.x*256 + threadIdx.x;
    if (i >= 320000) return;
    float s = 0.f;
    #pragma unroll
    for (int k = 0; k < 8; ++k) s += p[(size_t)k*320000 + i];
    int m = i / 800, n = i - m*800;
    if (n < 400) Q[m*400 + n] = s;
    else         P[m*400 + (n-400)] = s;
}

// ---------------------------------------------------------------------------
// OUT[m,n] = maybe_softplus( dotc*sum_k A[m,k]*B[n,k] + Gbase + vcoef*vec[n] + tval*wt[n] + b1[n] )
__global__ __launch_bounds__(256) void fused_small_k(
    const float* __restrict__ A, const float* __restrict__ Bm,
    const float* __restrict__ Gbase, float* __restrict__ OUT,
    const float* __restrict__ vec, float vcoef,
    const float* __restrict__ wt, float tval,
    const float* __restrict__ b1, float dotc, int do_sp)
{
    __shared__ float As[16][68];
    __shared__ float Bs[16][68];
    int m0 = blockIdx.y*64, n0 = blockIdx.x*64;
    int tid = threadIdx.x, tx = tid & 15, ty = tid >> 4;
    int row = tid >> 2, kq = tid & 3;
    float acc[4][4] = {};
    for (int k0 = 0; k0 < 400; k0 += 16){
        int m = m0 + row;
        if (m < SB_){
            float4 va = *(const float4*)(A + (size_t)m*400 + k0 + kq*4);
            As[kq*4+0][row] = va.x; As[kq*4+1][row] = va.y;
            As[kq*4+2][row] = va.z; As[kq*4+3][row] = va.w;
        } else {
            As[kq*4+0][row] = 0.f; As[kq*4+1][row] = 0.f;
            As[kq*4+2][row] = 0.f; As[kq*4+3][row] = 0.f;
        }
        int n = n0 + row;
        if (n < 400){
            float4 vb = *(const float4*)(Bm + (size_t)n*400 + k0 + kq*4);
            Bs[kq*4+0][row] = vb.x; Bs[kq*4+1][row] = vb.y;
            Bs[kq*4+2][row] = vb.z; Bs[kq*4+3][row] = vb.w;
        } else {
            Bs[kq*4+0][row] = 0.f; Bs[kq*4+1][row] = 0.f;
            Bs[kq*4+2][row] = 0.f; Bs[kq*4+3][row] = 0.f;
        }
        __syncthreads();
        #pragma unroll
        for (int k = 0; k < 16; ++k){
            float4 a4 = *(const float4*)&As[k][tx*4];
            float4 b4 = *(const float4*)&Bs[k][ty*4];
            float av[4] = {a4.x,a4.y,a4.z,a4.w};
            float bv[4] = {b4.x,b4.y,b4.z,b4.w};
            #pragma unroll
            for (int i = 0; i < 4; ++i)
                #pragma unroll
                for (int jj = 0; jj < 4; ++jj) acc[i][jj] += av[i]*bv[jj];
        }
        __syncthreads();
    }
    #pragma unroll
    for (int i = 0; i < 4; ++i){
        int m = m0 + tx*4 + i; if (m >= SB_) continue;
        #pragma unroll
        for (int jj = 0; jj < 4; ++jj){
            int n = n0 + ty*4 + jj; if (n >= 400) continue;
            float s = dotc*acc[i][jj];
            if (Gbase) s += Gbase[(size_t)m*400 + n];
            if (vec)   s += vcoef*vec[n];
            if (wt)    s += tval*wt[n];
            if (b1)    s += b1[n];
            OUT[(size_t)m*400 + n] = do_sp ? softplusf(s) : s;
        }
    }
}

// H = softplus(Gy + t*wt + b1)
__global__ __launch_bounds__(256) void stage1_k(const float* __restrict__ Gy, float* __restrict__ H,
                                                const float* __restrict__ wt, float tval,
                                                const float* __restrict__ b1)
{
    int sb = blockIdx.x;
    for (int n = threadIdx.x; n < 400; n += 256){
        float s = Gy[(size_t)sb*400 + n] + tval*wt[n] + b1[n];
        H[(size_t)sb*400 + n] = softplusf(s);
    }
}

// Hs = dt/6*(H1+2H2+2H3+H4); Hacc += Hs
__global__ __launch_bounds__(256) void hs_k(const float* __restrict__ H1, const float* __restrict__ H2,
                                            const float* __restrict__ H3, const float* __restrict__ H4,
                                            float* __restrict__ Hs, float* __restrict__ Hacc, int n)
{
    int i = blockIdx.x*256 + threadIdx.x;
    if (i < n){
        float v = (1.f/12.f)*(H1[i] + 2.f*H2[i] + 2.f*H3[i] + H4[i]);  // dt/6 = 0.5/6
        Hs[i] = v;
        Hacc[i] += v;
    }
}

// ---------------------------------------------------------------------------
// MFMA decode: z[m,v] = Abf[m,:]·Bbf[v,:] + decb[v] + b2[v]   (M=1120,N=32000,K=800)
__global__ __launch_bounds__(256) void decode_mfma_k(
    const unsigned short* __restrict__ Abf,
    const unsigned short* __restrict__ Bbf,
    const float* __restrict__ decb, const float* __restrict__ b2v,
    float* __restrict__ z)
{
    __shared__ unsigned short As[128*40];
    __shared__ unsigned short Bs[128*40];
    int n0 = blockIdx.x*128, m0 = blockIdx.y*128;
    int tid = threadIdx.x;
    int lane = tid & 63, wid = tid >> 6;
    int wr = wid >> 1, wc = wid & 1;
    f32x4 acc[4][4] = {};

    int srow = tid >> 1;           // 0..127
    int sk   = (tid & 1) * 16;     // 0 or 16

    for (int k0 = 0; k0 < 800; k0 += 32){
        uint4 av0 = {0,0,0,0}, av1 = {0,0,0,0};
        int m = m0 + srow;
        if (m < SB_){
            const uint4* ap = (const uint4*)(Abf + (size_t)m*800 + k0 + sk);
            av0 = ap[0]; av1 = ap[1];
        }
        const uint4* bp = (const uint4*)(Bbf + (size_t)(n0 + srow)*800 + k0 + sk);
        uint4 bv0 = bp[0], bv1 = bp[1];

        __syncthreads();
        *(uint4*)&As[srow*40 + sk]     = av0;
        *(uint4*)&As[srow*40 + sk + 8] = av1;
        *(uint4*)&Bs[srow*40 + sk]     = bv0;
        *(uint4*)&Bs[srow*40 + sk + 8] = bv1;
        __syncthreads();

        int kq = (lane >> 4) * 8;
        int rA = wr*64 + (lane & 15);
        int rB = wc*64 + (lane & 15);
        bf16x8 af[4], bfv[4];
        #pragma unroll
        for (int f = 0; f < 4; ++f){
            af[f]  = *(const bf16x8*)&As[(rA + f*16)*40 + kq];
            bfv[f] = *(const bf16x8*)&Bs[(rB + f*16)*40 + kq];
        }
        #pragma unroll
        for (int fm = 0; fm < 4; ++fm)
            #pragma unroll
            for (int fn = 0; fn < 4; ++fn)
                acc[fm][fn] = __builtin_amdgcn_mfma_f32_16x16x32_bf16(af[fm], bfv[fn], acc[fm][fn], 0, 0, 0);
    }

    int cm = (lane >> 4) * 4;
    int cn = lane & 15;
    #pragma unroll
    for (int fm = 0; fm < 4; ++fm){
        int mrow0 = m0 + wr*64 + fm*16 + cm;
        #pragma unroll
        for (int fn = 0; fn < 4; ++fn){
            int n = n0 + wc*64 + fn*16 + cn;
            float db = decb[n] + b2v[n];
            #pragma unroll
            for (int r = 0; r < 4; ++r){
                int mr = mrow0 + r;
                if (mr < SB_) z[(size_t)mr*NT_ + n] = acc[fm][fn][r] + db;
            }
        }
    }
}

// per-row max and sum(exp(z-max))
__global__ __launch_bounds__(256) void rowred_k(const float* __restrict__ z,
                                                float* __restrict__ rowm, float* __restrict__ rowsum)
{
    int r = blockIdx.x;
    const float* zr = z + (size_t)r*NT_;
    __shared__ float sm[256];
    float m = -1e30f;
    for (int v = threadIdx.x; v < NT_; v += 256) m = fmaxf(m, zr[v]);
    sm[threadIdx.x] = m; __syncthreads();
    for (int s = 128; s > 0; s >>= 1){
        if (threadIdx.x < s) sm[threadIdx.x] = fmaxf(sm[threadIdx.x], sm[threadIdx.x+s]);
        __syncthreads();
    }
    m = sm[0]; __syncthreads();
    float s = 0.f;
    for (int v = threadIdx.x; v < NT_; v += 256) s += __expf(zr[v] - m);
    sm[threadIdx.x] = s; __syncthreads();
    for (int st = 128; st > 0; st >>= 1){
        if (threadIdx.x < st) sm[threadIdx.x] += sm[threadIdx.x+st];
        __syncthreads();
    }
    if (threadIdx.x == 0){ rowm[r] = m; rowsum[r] = sm[0]; }
}

// out = log(exp(z-m)/S + 1e-8), in place
__global__ __launch_bounds__(256) void finalmap_k(float* __restrict__ z,
                                                  const float* __restrict__ rowm,
                                                  const float* __restrict__ rowsum)
{
    int r = blockIdx.y;
    int v = (blockIdx.x*256 + threadIdx.x)*4;
    if (v >= NT_) return;
    float m = rowm[r];
    float sinv = 1.f/rowsum[r];
    float4* p = (float4*)(z + (size_t)r*NT_ + v);
    float4 x = *p;
    x.x = logf(__expf(x.x - m)*sinv + 1e-8f);
    x.y = logf(__expf(x.y - m)*sinv + 1e-8f);
    x.z = logf(__expf(x.z - m)*sinv + 1e-8f);
    x.w = logf(__expf(x.w - m)*sinv + 1e-8f);
    *p = x;
}

// ---------------------------------------------------------------------------
extern "C" void kernel_launch(void* const* d_in, const int* in_sizes, int n_in,
                              void* d_out, int out_size, void* d_ws, size_t ws_size,
                              hipStream_t stream)
{
    const int*   tokens = (const int*)  d_in[0];
    const float* h0_0 = (const float*)d_in[1];
    const float* c0_0 = (const float*)d_in[2];
    const float* Wih0 = (const float*)d_in[3];
    const float* Whh0 = (const float*)d_in[4];
    const float* bih0 = (const float*)d_in[5];
    const float* bhh0 = (const float*)d_in[6];
    const float* h0_1 = (const float*)d_in[7];
    const float* c0_1 = (const float*)d_in[8];
    const float* Wih1 = (const float*)d_in[9];
    const float* Whh1 = (const float*)d_in[10];
    const float* bih1 = (const float*)d_in[11];
    const float* bhh1 = (const float*)d_in[12];
    const float* h0_2 = (const float*)d_in[13];
    const float* c0_2 = (const float*)d_in[14];
    const float* Wih2 = (const float*)d_in[15];
    const float* Whh2 = (const float*)d_in[16];
    const float* bih2 = (const float*)d_in[17];
    const float* bhh2 = (const float*)d_in[18];
    const float* emb  = (const float*)d_in[19];
    const float* decW = (const float*)d_in[20];
    const float* decb = (const float*)d_in[21];
    const float* odeW1= (const float*)d_in[22];
    const float* odeb1= (const float*)d_in[23];
    const float* odeW2= (const float*)d_in[24];
    const float* odeb2= (const float*)d_in[25];

    // workspace carve-up (~203 MB), all chunks 16B-aligned
    float* w = (float*)d_ws;
    size_t off = 0;
    auto alloc = [&](size_t n){ float* p = w + off; off += n; return p; };
    auto allocU = [&](size_t nUsh){ return (unsigned short*)alloc(nUsh/2); };  // nUsh mult of 8
    unsigned short* x0A  = allocU((size_t)S_*16*416);
    unsigned short* ys0A = allocU((size_t)S_*16*1152);
    unsigned short* ys1A = allocU((size_t)S_*16*1152);
    float* x3   = alloc((size_t)SB_*400);
    unsigned short* h0b = allocU((size_t)2*16*1152); float* c0b = alloc(1152*16);
    unsigned short* h1b = allocU((size_t)2*16*1152); float* c1b = alloc(1152*16);
    unsigned short* h2b = allocU((size_t)2*16*416);  float* c2b = alloc(416*16);
    float* P    = alloc(160000);
    float* Q    = alloc(160000);
    float* dvec = alloc(512);
    float* bvec = alloc(512);
    float* wtd  = alloc(512);
    float* Gy   = alloc((size_t)SB_*400);
    float* Hacc = alloc((size_t)SB_*400);
    float* H1   = alloc((size_t)SB_*400);
    float* H2   = alloc((size_t)SB_*400);
    float* H3   = alloc((size_t)SB_*400);
    float* H4   = alloc((size_t)SB_*400);
    float* Hs   = alloc((size_t)SB_*400);
    float* rowm = alloc(1280);   // >= SB_
    float* rsum = alloc(1280);   // >= SB_
    float* partials = alloc((size_t)8*320000);
    unsigned short* Wih0p = allocU((size_t)4600*416);
    unsigned short* Whh0p = allocU((size_t)4600*1152);
    unsigned short* Wih1p = allocU((size_t)4600*1152);
    unsigned short* Whh1p = allocU((size_t)4600*1152);
    unsigned short* Wih2p = allocU((size_t)1600*1152);
    unsigned short* Whh2p = allocU((size_t)1600*416);
    unsigned short* Abf   = allocU((size_t)SB_*800);
    unsigned short* Bbf   = allocU((size_t)NT_*800);
    unsigned short* BbfT  = allocU((size_t)800*NT_);
    unsigned short* Wxbf  = allocU((size_t)400*NT_);
    (void)ws_size; (void)in_sizes; (void)n_in; (void)out_size;

    float* zout = (float*)d_out;

    hipMemsetAsync(Hacc, 0, (size_t)SB_*400*sizeof(float), stream);
    // zero activation buffers once per call: pad columns are read by MFMA and
    // multiplied by zero weight pads — must not contain NaN bit patterns.
    hipMemsetAsync(ys0A, 0, (size_t)S_*16*1152*2, stream);
    hipMemsetAsync(ys1A, 0, (size_t)S_*16*1152*2, stream);
    hipMemsetAsync(h0b,  0, (size_t)2*16*1152*2, stream);
    hipMemsetAsync(h1b,  0, (size_t)2*16*1152*2, stream);
    hipMemsetAsync(h2b,  0, (size_t)2*16*416*2, stream);

    // weight conversions (bf16, K zero-padded)
    auto cvtgrid = [](long long n){ return (unsigned)((n + 255) / 256); };
    cvt_pack_w_k<<<cvtgrid((long long)4600*416),  256, 0, stream>>>(Wih0, Wih0p, 4600, 400, 416);
    cvt_pack_w_k<<<cvtgrid((long long)4600*1152), 256, 0, stream>>>(Whh0, Whh0p, 4600, 1150, 1152);
    cvt_pack_w_k<<<cvtgrid((long long)4600*1152), 256, 0, stream>>>(Wih1, Wih1p, 4600, 1150, 1152);
    cvt_pack_w_k<<<cvtgrid((long long)4600*1152), 256, 0, stream>>>(Whh1, Whh1p, 4600, 1150, 1152);
    cvt_pack_w_k<<<cvtgrid((long long)1600*1152), 256, 0, stream>>>(Wih2, Wih2p, 1600, 1150, 1152);
    cvt_pack_w_k<<<cvtgrid((long long)1600*416),  256, 0, stream>>>(Whh2, Whh2p, 1600, 400, 416);
    cvt_catB_k<<<cvtgrid((long long)NT_*800), 256, 0, stream>>>(decW, odeW2, Bbf);
    cvt_catBT_k<<<dim3(500, 25), 256, 0, stream>>>(decW, odeW2, BbfT);
    cvt_wx_k<<<cvtgrid((long long)400*NT_), 256, 0, stream>>>(odeW1, Wxbf);

    // activations + state init
    embed_bf_k<<<S_, 256, 0, stream>>>(tokens, emb, x0A);
    cvt_h0_k<<<(16*1150+255)/256, 256, 0, stream>>>(h0_0, h0b, 1150, 1152);
    cvt_h0_k<<<(16*1150+255)/256, 256, 0, stream>>>(h0_1, h1b, 1150, 1152);
    cvt_h0_k<<<(16*400+255)/256,  256, 0, stream>>>(h0_2, h2b, 400, 416);
    transpose16_k<<<(1150*16+255)/256, 256, 0, stream>>>(c0_0, c0b, 1150);
    transpose16_k<<<(1150*16+255)/256, 256, 0, stream>>>(c0_1, c1b, 1150);
    transpose16_k<<<(400*16+255)/256,  256, 0, stream>>>(c0_2, c2b, 400);

    // 3-layer LSTM, layer-pipelined wavefront, MFMA, 8 waves (gate x k-half)
    for (int u = 0; u < S_ + 2; ++u)
        lstm_mfma_k<<<169, 512, 0, stream>>>(u, x0A, ys0A, ys1A, x3,
            h0b, c0b, h1b, c1b, h2b, c2b,
            Wih0p, Whh0p, bih0, bhh0, Wih1p, Whh1p, bih1, bhh1, Wih2p, Whh2p, bih2, bhh2);

    // ODE factorization precompute: [Q|P] = Wx @ BbfT^T via MFMA, 8 K-slabs
    vecs_k<<<400, 256, 0, stream>>>(odeW1, decb, odeb2, dvec, bvec, wtd);
    gemm_odeT_k<<<dim3(7,4,8), 256, 0, stream>>>(Wxbf, BbfT, partials);
    reduce8_k<<<(320000+255)/256, 256, 0, stream>>>(partials, Q, P);

    // G0 = x3 @ Q^T + dvec
    fused_small_k<<<dim3(7,18), 256, 0, stream>>>(x3, Q, nullptr, Gy,
        dvec, 1.f, nullptr, 0.f, nullptr, 1.f, 0);

    // RK4 in G-space, 2 steps, dt = 0.5
    const float dt = 0.5f;
    for (int n = 0; n < 2; ++n){
        float t0 = n * dt;
        stage1_k<<<SB_, 256, 0, stream>>>(Gy, H1, wtd, t0, odeb1);
        fused_small_k<<<dim3(7,18), 256, 0, stream>>>(H1, P, Gy, H2,
            bvec, 0.25f, wtd, t0 + 0.25f, odeb1, 0.25f, 1);
        fused_small_k<<<dim3(7,18), 256, 0, stream>>>(H2, P, Gy, H3,
            bvec, 0.25f, wtd, t0 + 0.25f, odeb1, 0.25f, 1);
        fused_small_k<<<dim3(7,18), 256, 0, stream>>>(H3, P, Gy, H4,
            bvec, 0.5f, wtd, t0 + 0.5f, odeb1, 0.5f, 1);
        hs_k<<<((SB_*400)+255)/256, 256, 0, stream>>>(H1, H2, H3, H4, Hs, Hacc, SB_*400);
        if (n == 0)
            fused_small_k<<<dim3(7,18), 256, 0, stream>>>(Hs, P, Gy, Gy,
                bvec, dt, nullptr, 0.f, nullptr, 1.f, 0);
    }

    // A-concat (x3|Hacc) -> bf16, MFMA decode, log-softmax in place
    cvt_catA_k<<<cvtgrid((long long)SB_*800), 256, 0, stream>>>(x3, Hacc, Abf);
    decode_mfma_k<<<dim3(250,9), 256, 0, stream>>>(Abf, Bbf, decb, odeb2, zout);
    rowred_k<<<SB_, 256, 0, stream>>>(zout, rowm, rsum);
    finalmap_k<<<dim3(32,SB_), 256, 0, stream>>>(zout, rowm, rsum);
}

// Round 6
// 2140.832 us; speedup vs baseline: 4.0181x; 1.1096x over previous
//
#include <hip/hip_runtime.h>
#include <math.h>

// Problem dims
constexpr int S_   = 70;
constexpr int B_   = 16;
constexpr int SB_  = 1120;     // S*B
constexpr int NT_  = 32000;    // NTOKEN
constexpr int W1S_ = 32001;    // odeW1 row stride (NTOKEN+1)

typedef __attribute__((ext_vector_type(8))) short bf16x8;
typedef __attribute__((ext_vector_type(4))) float f32x4;

__device__ __forceinline__ float sigm(float x){ return 1.f/(1.f+__expf(-x)); }
__device__ __forceinline__ float softplusf(float x){ return x > 15.f ? x : log1pf(__expf(x)); }

__device__ __forceinline__ unsigned short f2bf(float f){
    union{float f; unsigned u;} c; c.f = f;
    unsigned u = c.u;
    unsigned r = (u + 0x7fffu + ((u >> 16) & 1u)) >> 16;
    return (unsigned short)r;
}
__device__ __forceinline__ float bfu(unsigned short us){
    union{unsigned u; float f;} c; c.u = ((unsigned)us) << 16; return c.f;
}

// ---------------------------------------------------------------------------
// fp32 [R][K] -> bf16 [R][Kp], zero-padded in K
__global__ __launch_bounds__(256) void cvt_pack_w_k(const float* __restrict__ src,
                                                    unsigned short* __restrict__ dst,
                                                    int R, int K, int Kp)
{
    long long idx = (long long)blockIdx.x*256 + threadIdx.x;
    long long tot = (long long)R*Kp;
    if (idx >= tot) return;
    int r = (int)(idx / Kp), kk = (int)(idx - (long long)r*Kp);
    float v = (kk < K) ? src[(size_t)r*K + kk] : 0.f;
    dst[idx] = f2bf(v);
}

// Abf[1120][800]: k<400 -> x3[m][k], else Hacc[m][k-400]
__global__ __launch_bounds__(256) void cvt_catA_k(const float* __restrict__ x3,
                                                  const float* __restrict__ Hacc,
                                                  unsigned short* __restrict__ Abf)
{
    int idx = blockIdx.x*256 + threadIdx.x;
    if (idx >= SB_*800) return;
    int m = idx / 800, k = idx - m*800;
    float v = (k < 400) ? x3[(size_t)m*400 + k] : Hacc[(size_t)m*400 + (k-400)];
    Abf[idx] = f2bf(v);
}

// Fused: Bbf[32000][800] row-major AND BbfT[800][32000] transposed, single read.
__global__ __launch_bounds__(256) void cvt_catB2_k(const float* __restrict__ decW,
                                                   const float* __restrict__ odeW2,
                                                   unsigned short* __restrict__ Bbf,
                                                   unsigned short* __restrict__ BbfT)
{
    __shared__ unsigned short tile[32][72];
    int v0 = blockIdx.x*64, n0 = blockIdx.y*32;
    int tx = threadIdx.x & 31;        // n offset (load phase)
    int vy = threadIdx.x >> 5;        // 0..7
    #pragma unroll
    for (int i = 0; i < 8; ++i){
        int v = v0 + i*8 + vy;
        int n = n0 + tx;
        float val = (n < 400) ? decW[(size_t)v*400 + n] : odeW2[(size_t)v*400 + (n-400)];
        unsigned short us = f2bf(val);
        tile[tx][v - v0] = us;
        Bbf[(size_t)v*800 + n] = us;
    }
    __syncthreads();
    int vx = threadIdx.x & 63;
    int ny = threadIdx.x >> 6;        // 0..3
    #pragma unroll
    for (int i = 0; i < 8; ++i){
        int n = n0 + i*4 + ny;
        BbfT[(size_t)n*NT_ + v0 + vx] = tile[n - n0][vx];
    }
}

// Wxbf[400][32000] = bf16(odeW1[:,1:])
__global__ __launch_bounds__(256) void cvt_wx_k(const float* __restrict__ odeW1,
                                                unsigned short* __restrict__ Wxbf)
{
    long long idx = (long long)blockIdx.x*256 + threadIdx.x;
    if (idx >= (long long)400*NT_) return;
    int m = (int)(idx / NT_), v = (int)(idx - (long long)m*NT_);
    Wxbf[idx] = f2bf(odeW1[(size_t)m*W1S_ + 1 + v]);
}

// ---------------------------------------------------------------------------
// Embedding gather -> bf16 A-layout: x0A[t][b][k] (stride 416, zero-padded)
__global__ __launch_bounds__(256) void embed_bf_k(const int* __restrict__ tok,
                                                  const float* __restrict__ emb,
                                                  unsigned short* __restrict__ x0A)
{
    int t = blockIdx.x;
    __shared__ int tk[16];
    if (threadIdx.x < 16) tk[threadIdx.x] = tok[t*16 + threadIdx.x];
    __syncthreads();
    for (int idx = threadIdx.x; idx < 16*416; idx += 256){
        int b = idx / 416, k = idx - b*416;
        float v = (k < 400) ? emb[(size_t)tk[b]*400 + k] : 0.f;
        x0A[(size_t)t*16*416 + idx] = f2bf(v);
    }
}

// dst[j*16+b] = src[b*dh+j]  (c-state init)
__global__ __launch_bounds__(256) void transpose16_k(const float* __restrict__ src,
                                                     float* __restrict__ dst, int dh)
{
    int idx = blockIdx.x*256 + threadIdx.x;
    if (idx < dh*16){ int j = idx >> 4, b = idx & 15; dst[idx] = src[b*dh + j]; }
}

// h0 [16][Dh] fp32 -> hb [16][SA] bf16 (parity-0 buffer; pads pre-zeroed by memset)
__global__ __launch_bounds__(256) void cvt_h0_k(const float* __restrict__ h0,
                                                unsigned short* __restrict__ hb, int Dh, int SA)
{
    int idx = blockIdx.x*256 + threadIdx.x;
    if (idx >= 16*Dh) return;
    int b = idx / Dh, j = idx - b*Dh;
    hb[(size_t)b*SA + j] = f2bf(h0[idx]);
}

// ---------------------------------------------------------------------------
// One wavefront step of the 3-layer LSTM pipeline, MFMA, 4-way K-split.
// Block = one 16-unit j-tile; 16 waves = 4 gates x 4 K-quarters (1024 threads).
__global__ __launch_bounds__(1024) void lstm_mfma_k(int u,
    const unsigned short* __restrict__ x0A,
    unsigned short* __restrict__ ys0A, unsigned short* __restrict__ ys1A,
    float* __restrict__ x3,
    unsigned short* __restrict__ h0b, float* __restrict__ c0,
    unsigned short* __restrict__ h1b, float* __restrict__ c1,
    unsigned short* __restrict__ h2b, float* __restrict__ c2,
    const unsigned short* __restrict__ Wih0p, const unsigned short* __restrict__ Whh0p,
    const float* __restrict__ bih0, const float* __restrict__ bhh0,
    const unsigned short* __restrict__ Wih1p, const unsigned short* __restrict__ Whh1p,
    const float* __restrict__ bih1, const float* __restrict__ bhh1,
    const unsigned short* __restrict__ Wih2p, const unsigned short* __restrict__ Whh2p,
    const float* __restrict__ bih2, const float* __restrict__ bhh2)
{
    int blk = blockIdx.x;
    int layer, jt;
    if      (blk < 72) { layer = 0; jt = blk; }
    else if (blk < 144){ layer = 1; jt = blk - 72; }
    else               { layer = 2; jt = blk - 144; }
    int t = u - layer;
    if (t < 0 || t >= S_) return;
    int j0 = jt*16;

    const unsigned short *Ax, *Ah, *Wi, *Wh;
    const float *bih, *bhh;
    float *cst, *x3o = nullptr;
    unsigned short *yo = nullptr, *hrec;
    int Kx, Kh, Dh, SAx, SAh;
    if (layer == 0){
        Ax = x0A + (size_t)t*16*416; SAx = 416; Kx = 416;
        Ah = h0b + (size_t)(t&1)*16*1152; SAh = 1152; Kh = 1152;
        Wi = Wih0p; Wh = Whh0p; bih = bih0; bhh = bhh0; Dh = 1150;
        cst = c0; hrec = h0b + (size_t)((t+1)&1)*16*1152;
        yo = ys0A + (size_t)t*16*1152;
    } else if (layer == 1){
        Ax = ys0A + (size_t)t*16*1152; SAx = 1152; Kx = 1152;
        Ah = h1b + (size_t)(t&1)*16*1152; SAh = 1152; Kh = 1152;
        Wi = Wih1p; Wh = Whh1p; bih = bih1; bhh = bhh1; Dh = 1150;
        cst = c1; hrec = h1b + (size_t)((t+1)&1)*16*1152;
        yo = ys1A + (size_t)t*16*1152;
    } else {
        Ax = ys1A + (size_t)t*16*1152; SAx = 1152; Kx = 1152;
        Ah = h2b + (size_t)(t&1)*16*416; SAh = 416; Kh = 416;
        Wi = Wih2p; Wh = Whh2p; bih = bih2; bhh = bhh2; Dh = 400;
        cst = c2; hrec = h2b + (size_t)((t+1)&1)*16*416;
        x3o = x3 + (size_t)t*16*400;
    }

    int lane = threadIdx.x & 63, w = threadIdx.x >> 6;   // w = 0..15
    int gate = w & 3, kq4 = w >> 2;                      // gate, K-quarter
    int am = lane & 15;           // A row (batch)
    int kq = (lane >> 4) * 8;     // k offset within 32-step
    int jn = lane & 15;           // B row (local j)
    int jrow = j0 + jn; if (jrow > Dh-1) jrow = Dh-1;    // clamp (dup rows discarded on write)

    const unsigned short* ax = Ax + (size_t)am*SAx;
    const unsigned short* ah = Ah + (size_t)am*SAh;
    const unsigned short* wx = Wi + (size_t)(gate*Dh + jrow)*SAx;
    const unsigned short* wh = Wh + (size_t)(gate*Dh + jrow)*SAh;

    // K-quarter bounds (32-chunk granular)
    int nx = Kx >> 5, nh = Kh >> 5;
    int xq0 = ((nx *  kq4     ) >> 2) << 5;
    int xq1 = ((nx * (kq4 + 1)) >> 2) << 5;
    int hq0 = ((nh *  kq4     ) >> 2) << 5;
    int hq1 = ((nh * (kq4 + 1)) >> 2) << 5;

    f32x4 acc0 = {0.f,0.f,0.f,0.f}, acc1 = {0.f,0.f,0.f,0.f};
    int k0 = xq0;
    for (; k0 + 64 <= xq1; k0 += 64){
        bf16x8 a0 = *(const bf16x8*)(ax + k0 + kq);
        bf16x8 b0 = *(const bf16x8*)(wx + k0 + kq);
        acc0 = __builtin_amdgcn_mfma_f32_16x16x32_bf16(a0, b0, acc0, 0,0,0);
        bf16x8 a1 = *(const bf16x8*)(ax + k0 + 32 + kq);
        bf16x8 b1 = *(const bf16x8*)(wx + k0 + 32 + kq);
        acc1 = __builtin_amdgcn_mfma_f32_16x16x32_bf16(a1, b1, acc1, 0,0,0);
    }
    if (k0 < xq1){
        bf16x8 a0 = *(const bf16x8*)(ax + k0 + kq);
        bf16x8 b0 = *(const bf16x8*)(wx + k0 + kq);
        acc0 = __builtin_amdgcn_mfma_f32_16x16x32_bf16(a0, b0, acc0, 0,0,0);
    }
    k0 = hq0;
    for (; k0 + 64 <= hq1; k0 += 64){
        bf16x8 a0 = *(const bf16x8*)(ah + k0 + kq);
        bf16x8 b0 = *(const bf16x8*)(wh + k0 + kq);
        acc0 = __builtin_amdgcn_mfma_f32_16x16x32_bf16(a0, b0, acc0, 0,0,0);
        bf16x8 a1 = *(const bf16x8*)(ah + k0 + 32 + kq);
        bf16x8 b1 = *(const bf16x8*)(wh + k0 + 32 + kq);
        acc1 = __builtin_amdgcn_mfma_f32_16x16x32_bf16(a1, b1, acc1, 0,0,0);
    }
    if (k0 < hq1){
        bf16x8 a0 = *(const bf16x8*)(ah + k0 + kq);
        bf16x8 b0 = *(const bf16x8*)(wh + k0 + kq);
        acc0 = __builtin_amdgcn_mfma_f32_16x16x32_bf16(a0, b0, acc0, 0,0,0);
    }
    f32x4 acc = acc0 + acc1;

    // C/D: row m = (lane>>4)*4 + r (batch), col = lane&15 (local j)
    __shared__ float g16[16][16][17];
    int bm = (lane >> 4) * 4;
    #pragma unroll
    for (int r = 0; r < 4; ++r) g16[w][bm + r][jn] = acc[r];
    __syncthreads();

    if (threadIdx.x < 256){
        int jl = threadIdx.x >> 4, b = threadIdx.x & 15;
        int j = j0 + jl;
        if (j < Dh){
            float pi = g16[0][b][jl] + g16[4][b][jl] + g16[8][b][jl]  + g16[12][b][jl] + bih[j]      + bhh[j];
            float pf = g16[1][b][jl] + g16[5][b][jl] + g16[9][b][jl]  + g16[13][b][jl] + bih[Dh+j]   + bhh[Dh+j];
            float pg = g16[2][b][jl] + g16[6][b][jl] + g16[10][b][jl] + g16[14][b][jl] + bih[2*Dh+j] + bhh[2*Dh+j];
            float po = g16[3][b][jl] + g16[7][b][jl] + g16[11][b][jl] + g16[15][b][jl] + bih[3*Dh+j] + bhh[3*Dh+j];
            float cold = cst[j*16 + b];
            float cnew = sigm(pf)*cold + sigm(pi)*tanhf(pg);
            float h    = sigm(po)*tanhf(cnew);
            cst[j*16 + b] = cnew;
            unsigned short hb16 = f2bf(h);
            hrec[(size_t)b*SAh + j] = hb16;
            if (yo)  yo[(size_t)b*1152 + j] = hb16;
            if (x3o) x3o[(size_t)b*400 + j] = h;
        }
    }
}

// ---------------------------------------------------------------------------
// dvec[j] = Wx[j,:]·decb ; bvec[j] = Wx[j,:]·b2 ; wtd[j] = odeW1[j,0]  (bf16 Wx read)
__global__ __launch_bounds__(256) void vecs_k(const unsigned short* __restrict__ Wxbf,
                                              const float* __restrict__ odeW1,
                                              const float* __restrict__ decb,
                                              const float* __restrict__ b2v,
                                              float* __restrict__ dvec,
                                              float* __restrict__ bvec,
                                              float* __restrict__ wtd)
{
    int jrow = blockIdx.x;
    __shared__ float r1[256], r2[256];
    const unsigned short* wx = Wxbf + (size_t)jrow*NT_;
    float s1 = 0.f, s2 = 0.f;
    for (int v = threadIdx.x; v < NT_; v += 256){
        float w = bfu(wx[v]); s1 += w*decb[v]; s2 += w*b2v[v];
    }
    r1[threadIdx.x] = s1; r2[threadIdx.x] = s2; __syncthreads();
    for (int s = 128; s > 0; s >>= 1){
        if (threadIdx.x < s){ r1[threadIdx.x] += r1[threadIdx.x+s]; r2[threadIdx.x] += r2[threadIdx.x+s]; }
        __syncthreads();
    }
    if (threadIdx.x == 0){ dvec[jrow] = r1[0]; bvec[jrow] = r2[0]; wtd[jrow] = odeW1[(size_t)jrow*W1S_]; }
}

// ---------------------------------------------------------------------------
// MFMA ODE precompute: partials[z][m*800+n] = sum_{v in slab z} Wxbf[m][v]*BbfT[n][v]
__global__ __launch_bounds__(256) void gemm_odeT_k(
    const unsigned short* __restrict__ Wxbf,
    const unsigned short* __restrict__ BbfT,
    float* __restrict__ partials)
{
    __shared__ unsigned short As[128*40];
    __shared__ unsigned short Bs[128*40];
    int n0 = blockIdx.x*128, m0 = blockIdx.y*128, v0 = blockIdx.z*4000;
    int tid = threadIdx.x;
    int lane = tid & 63, wid = tid >> 6;
    int wr = wid >> 1, wc = wid & 1;
    f32x4 acc[4][4] = {};

    int srow = tid >> 1;
    int sk   = (tid & 1) * 16;
    int mL = m0 + srow; if (mL > 399) mL = 399;
    int nL = n0 + srow; if (nL > 799) nL = 799;
    const unsigned short* ap = Wxbf + (size_t)mL*NT_ + v0 + sk;
    const unsigned short* bp = BbfT + (size_t)nL*NT_ + v0 + sk;

    for (int k0 = 0; k0 < 4000; k0 += 32){
        uint4 av0 = *(const uint4*)(ap + k0);
        uint4 av1 = *(const uint4*)(ap + k0 + 8);
        uint4 bv0 = *(const uint4*)(bp + k0);
        uint4 bv1 = *(const uint4*)(bp + k0 + 8);

        __syncthreads();
        *(uint4*)&As[srow*40 + sk]     = av0;
        *(uint4*)&As[srow*40 + sk + 8] = av1;
        *(uint4*)&Bs[srow*40 + sk]     = bv0;
        *(uint4*)&Bs[srow*40 + sk + 8] = bv1;
        __syncthreads();

        int kq = (lane >> 4) * 8;
        int rA = wr*64 + (lane & 15);
        int rB = wc*64 + (lane & 15);
        bf16x8 af[4], bfv[4];
        #pragma unroll
        for (int f = 0; f < 4; ++f){
            af[f]  = *(const bf16x8*)&As[(rA + f*16)*40 + kq];
            bfv[f] = *(const bf16x8*)&Bs[(rB + f*16)*40 + kq];
        }
        #pragma unroll
        for (int fm = 0; fm < 4; ++fm)
            #pragma unroll
            for (int fn = 0; fn < 4; ++fn)
                acc[fm][fn] = __builtin_amdgcn_mfma_f32_16x16x32_bf16(af[fm], bfv[fn], acc[fm][fn], 0, 0, 0);
    }

    float* op = partials + (size_t)blockIdx.z*320000;
    int cm = (lane >> 4) * 4;
    int cn = lane & 15;
    #pragma unroll
    for (int fm = 0; fm < 4; ++fm){
        int mrow0 = m0 + wr*64 + fm*16 + cm;
        #pragma unroll
        for (int fn = 0; fn < 4; ++fn){
            int n = n0 + wc*64 + fn*16 + cn;
            if (n >= 800) continue;
            #pragma unroll
            for (int r = 0; r < 4; ++r){
                int mr = mrow0 + r;
                if (mr < 400) op[mr*800 + n] = acc[fm][fn][r];
            }
        }
    }
}

// sum 8 slabs; scatter to PADDED bf16: C[:,0:400]->Qbf[400][416], C[:,400:800]->Pbf[400][416]
__global__ __launch_bounds__(256) void reduce8bf_k(const float* __restrict__ p,
                                                   unsigned short* __restrict__ Qbf,
                                                   unsigned short* __restrict__ Pbf)
{
    int i = blockIdx.x*256 + threadIdx.x;
    if (i >= 320000) return;
    float s = 0.f;
    #pragma unroll
    for (int k = 0; k < 8; ++k) s += p[(size_t)k*320000 + i];
    int m = i / 800, n = i - m*800;
    if (n < 400) Qbf[m*416 + n] = f2bf(s);
    else         Pbf[m*416 + (n-400)] = f2bf(s);
}

// ---------------------------------------------------------------------------
// MFMA small GEMM: OUT[m,n] = maybe_sp( dotc*sum_k A[m,k]*Bb[n,k] + Gbase + vcoef*vec + tval*wt + b1 )
// A fp32 [SB_][400] converted on the fly; Bb bf16 [400][416] padded. 64x64 tiles, 4 waves of 32x32.
__global__ __launch_bounds__(256) void fused_small_mfma_k(
    const float* __restrict__ A, const unsigned short* __restrict__ Bb,
    const float* __restrict__ Gbase, float* __restrict__ OUT,
    const float* __restrict__ vec, float vcoef,
    const float* __restrict__ wt, float tval,
    const float* __restrict__ b1, float dotc, int do_sp)
{
    __shared__ unsigned short As[64*40];
    __shared__ unsigned short Bs[64*40];
    int m0 = blockIdx.y*64, n0 = blockIdx.x*64;
    int tid = threadIdx.x;
    int lane = tid & 63, wid = tid >> 6;
    int wr = wid >> 1, wc = wid & 1;          // 2x2 waves of 32x32
    f32x4 acc[2][2] = {};

    int rowL = tid >> 2;                       // 0..63
    int kL   = (tid & 3) * 8;                  // 0,8,16,24
    int mG = m0 + rowL;
    int nG = n0 + rowL;

    for (int k0 = 0; k0 < 416; k0 += 32){
        unsigned short a8[8];
        int kb = k0 + kL;
        if (mG < SB_ && kb + 8 <= 400){
            float4 u0 = *(const float4*)(A + (size_t)mG*400 + kb);
            float4 u1 = *(const float4*)(A + (size_t)mG*400 + kb + 4);
            a8[0]=f2bf(u0.x); a8[1]=f2bf(u0.y); a8[2]=f2bf(u0.z); a8[3]=f2bf(u0.w);
            a8[4]=f2bf(u1.x); a8[5]=f2bf(u1.y); a8[6]=f2bf(u1.z); a8[7]=f2bf(u1.w);
        } else {
            #pragma unroll
            for (int i = 0; i < 8; ++i){
                int k = kb + i;
                float v = (mG < SB_ && k < 400) ? A[(size_t)mG*400 + k] : 0.f;
                a8[i] = f2bf(v);
            }
        }
        uint4 bv = {0,0,0,0};
        if (nG < 400) bv = *(const uint4*)(Bb + (size_t)nG*416 + kb);
        __syncthreads();
        #pragma unroll
        for (int i = 0; i < 4; ++i)
            *(unsigned*)&As[rowL*40 + kL + 2*i] = (unsigned)a8[2*i] | ((unsigned)a8[2*i+1] << 16);
        *(uint4*)&Bs[rowL*40 + kL] = bv;
        __syncthreads();

        int kq = (lane >> 4) * 8;
        int rA = wr*32 + (lane & 15);
        int rB = wc*32 + (lane & 15);
        bf16x8 af[2], bfv[2];
        af[0]  = *(const bf16x8*)&As[(rA     )*40 + kq];
        af[1]  = *(const bf16x8*)&As[(rA + 16)*40 + kq];
        bfv[0] = *(const bf16x8*)&Bs[(rB     )*40 + kq];
        bfv[1] = *(const bf16x8*)&Bs[(rB + 16)*40 + kq];
        #pragma unroll
        for (int fm = 0; fm < 2; ++fm)
            #pragma unroll
            for (int fn = 0; fn < 2; ++fn)
                acc[fm][fn] = __builtin_amdgcn_mfma_f32_16x16x32_bf16(af[fm], bfv[fn], acc[fm][fn], 0, 0, 0);
    }

    int cm = (lane >> 4) * 4, cn = lane & 15;
    #pragma unroll
    for (int fm = 0; fm < 2; ++fm){
        #pragma unroll
        for (int fn = 0; fn < 2; ++fn){
            int n = n0 + wc*32 + fn*16 + cn;
            if (n >= 400) continue;
            #pragma unroll
            for (int r = 0; r < 4; ++r){
                int m = m0 + wr*32 + fm*16 + cm + r;
                if (m >= SB_) continue;
                float s = dotc*acc[fm][fn][r];
                if (Gbase) s += Gbase[(size_t)m*400 + n];
                if (vec)   s += vcoef*vec[n];
                if (wt)    s += tval*wt[n];
                if (b1)    s += b1[n];
                OUT[(size_t)m*400 + n] = do_sp ? softplusf(s) : s;
            }
        }
    }
}

// H = softplus(Gy + t*wt + b1)
__global__ __launch_bounds__(256) void stage1_k(const float* __restrict__ Gy, float* __restrict__ H,
                                                const float* __restrict__ wt, float tval,
                                                const float* __restrict__ b1)
{
    int sb = blockIdx.x;
    for (int n = threadIdx.x; n < 400; n += 256){
        float s = Gy[(size_t)sb*400 + n] + tval*wt[n] + b1[n];
        H[(size_t)sb*400 + n] = softplusf(s);
    }
}

// Hs = dt/6*(H1+2H2+2H3+H4); Hacc += Hs
__global__ __launch_bounds__(256) void hs_k(const float* __restrict__ H1, const float* __restrict__ H2,
                                            const float* __restrict__ H3, const float* __restrict__ H4,
                                            float* __restrict__ Hs, float* __restrict__ Hacc, int n)
{
    int i = blockIdx.x*256 + threadIdx.x;
    if (i < n){
        float v = (1.f/12.f)*(H1[i] + 2.f*H2[i] + 2.f*H3[i] + H4[i]);  // dt/6 = 0.5/6
        Hs[i] = v;
        Hacc[i] += v;
    }
}

// ---------------------------------------------------------------------------
// MFMA decode, 256x128 tiles (B streamed 5x instead of 9x):
// z[m,v] = Abf[m,:]·Bbf[v,:] + decb[v] + b2[v]   (M=1120,N=32000,K=800)
__global__ __launch_bounds__(512) void decode_mfma_k(
    const unsigned short* __restrict__ Abf,
    const unsigned short* __restrict__ Bbf,
    const float* __restrict__ decb, const float* __restrict__ b2v,
    float* __restrict__ z)
{
    __shared__ unsigned short As[256*40];
    __shared__ unsigned short Bs[128*40];
    int n0 = blockIdx.x*128, m0 = blockIdx.y*256;
    int tid = threadIdx.x;
    int lane = tid & 63, wid = tid >> 6;   // 8 waves
    int wr = wid >> 1, wc = wid & 1;       // 4 (M) x 2 (N), each 64x64
    f32x4 acc[4][4] = {};

    int srA = tid >> 1, skA = (tid & 1)*16;   // 256 rows x 32k
    int srB = tid >> 2, skB = (tid & 3)*8;    // 128 rows x 32k

    for (int k0 = 0; k0 < 800; k0 += 32){
        uint4 av0 = {0,0,0,0}, av1 = {0,0,0,0};
        int m = m0 + srA;
        if (m < SB_){
            const uint4* ap = (const uint4*)(Abf + (size_t)m*800 + k0 + skA);
            av0 = ap[0]; av1 = ap[1];
        }
        uint4 bv = *(const uint4*)(Bbf + (size_t)(n0 + srB)*800 + k0 + skB);

        __syncthreads();
        *(uint4*)&As[srA*40 + skA]     = av0;
        *(uint4*)&As[srA*40 + skA + 8] = av1;
        *(uint4*)&Bs[srB*40 + skB]     = bv;
        __syncthreads();

        int kq = (lane >> 4) * 8;
        int rA = wr*64 + (lane & 15);
        int rB = wc*64 + (lane & 15);
        bf16x8 af[4], bfv[4];
        #pragma unroll
        for (int f = 0; f < 4; ++f){
            af[f]  = *(const bf16x8*)&As[(rA + f*16)*40 + kq];
            bfv[f] = *(const bf16x8*)&Bs[(rB + f*16)*40 + kq];
        }
        #pragma unroll
        for (int fm = 0; fm < 4; ++fm)
            #pragma unroll
            for (int fn = 0; fn < 4; ++fn)
                acc[fm][fn] = __builtin_amdgcn_mfma_f32_16x16x32_bf16(af[fm], bfv[fn], acc[fm][fn], 0, 0, 0);
    }

    int cm = (lane >> 4) * 4;
    int cn = lane & 15;
    #pragma unroll
    for (int fm = 0; fm < 4; ++fm){
        int mrow0 = m0 + wr*64 + fm*16 + cm;
        #pragma unroll
        for (int fn = 0; fn < 4; ++fn){
            int n = n0 + wc*64 + fn*16 + cn;
            float db = decb[n] + b2v[n];
            #pragma unroll
            for (int r = 0; r < 4; ++r){
                int mr = mrow0 + r;
                if (mr < SB_) z[(size_t)mr*NT_ + n] = acc[fm][fn][r] + db;
            }
        }
    }
}

// per-row max and sum(exp(z-max))
__global__ __launch_bounds__(256) void rowred_k(const float* __restrict__ z,
                                                float* __restrict__ rowm, float* __restrict__ rowsum)
{
    int r = blockIdx.x;
    const float* zr = z + (size_t)r*NT_;
    __shared__ float sm[256];
    float m = -1e30f;
    for (int v = threadIdx.x; v < NT_; v += 256) m = fmaxf(m, zr[v]);
    sm[threadIdx.x] = m; __syncthreads();
    for (int s = 128; s > 0; s >>= 1){
        if (threadIdx.x < s) sm[threadIdx.x] = fmaxf(sm[threadIdx.x], sm[threadIdx.x+s]);
        __syncthreads();
    }
    m = sm[0]; __syncthreads();
    float s = 0.f;
    for (int v = threadIdx.x; v < NT_; v += 256) s += __expf(zr[v] - m);
    sm[threadIdx.x] = s; __syncthreads();
    for (int st = 128; st > 0; st >>= 1){
        if (threadIdx.x < st) sm[threadIdx.x] += sm[threadIdx.x+st];
        __syncthreads();
    }
    if (threadIdx.x == 0){ rowm[r] = m; rowsum[r] = sm[0]; }
}

// out = log(exp(z-m)/S + 1e-8), in place
__global__ __launch_bounds__(256) void finalmap_k(float* __restrict__ z,
                                                  const float* __restrict__ rowm,
                                                  const float* __restrict__ rowsum)
{
    int r = blockIdx.y;
    int v = (blockIdx.x*256 + threadIdx.x)*4;
    if (v >= NT_) return;
    float m = rowm[r];
    float sinv = 1.f/rowsum[r];
    float4* p = (float4*)(z + (size_t)r*NT_ + v);
    float4 x = *p;
    x.x = logf(__expf(x.x - m)*sinv + 1e-8f);
    x.y = logf(__expf(x.y - m)*sinv + 1e-8f);
    x.z = logf(__expf(x.z - m)*sinv + 1e-8f);
    x.w = logf(__expf(x.w - m)*sinv + 1e-8f);
    *p = x;
}

// ---------------------------------------------------------------------------
extern "C" void kernel_launch(void* const* d_in, const int* in_sizes, int n_in,
                              void* d_out, int out_size, void* d_ws, size_t ws_size,
                              hipStream_t stream)
{
    const int*   tokens = (const int*)  d_in[0];
    const float* h0_0 = (const float*)d_in[1];
    const float* c0_0 = (const float*)d_in[2];
    const float* Wih0 = (const float*)d_in[3];
    const float* Whh0 = (const float*)d_in[4];
    const float* bih0 = (const float*)d_in[5];
    const float* bhh0 = (const float*)d_in[6];
    const float* h0_1 = (const float*)d_in[7];
    const float* c0_1 = (const float*)d_in[8];
    const float* Wih1 = (const float*)d_in[9];
    const float* Whh1 = (const float*)d_in[10];
    const float* bih1 = (const float*)d_in[11];
    const float* bhh1 = (const float*)d_in[12];
    const float* h0_2 = (const float*)d_in[13];
    const float* c0_2 = (const float*)d_in[14];
    const float* Wih2 = (const float*)d_in[15];
    const float* Whh2 = (const float*)d_in[16];
    const float* bih2 = (const float*)d_in[17];
    const float* bhh2 = (const float*)d_in[18];
    const float* emb  = (const float*)d_in[19];
    const float* decW = (const float*)d_in[20];
    const float* decb = (const float*)d_in[21];
    const float* odeW1= (const float*)d_in[22];
    const float* odeb1= (const float*)d_in[23];
    const float* odeW2= (const float*)d_in[24];
    const float* odeb2= (const float*)d_in[25];

    // workspace carve-up (~205 MB), all chunks 16B-aligned
    float* w = (float*)d_ws;
    size_t off = 0;
    auto alloc = [&](size_t n){ float* p = w + off; off += n; return p; };
    auto allocU = [&](size_t nUsh){ return (unsigned short*)alloc(nUsh/2); };  // nUsh mult of 8
    unsigned short* x0A  = allocU((size_t)S_*16*416);
    unsigned short* ys0A = allocU((size_t)S_*16*1152);
    unsigned short* ys1A = allocU((size_t)S_*16*1152);
    float* x3   = alloc((size_t)SB_*400);
    unsigned short* h0b = allocU((size_t)2*16*1152); float* c0b = alloc(1152*16);
    unsigned short* h1b = allocU((size_t)2*16*1152); float* c1b = alloc(1152*16);
    unsigned short* h2b = allocU((size_t)2*16*416);  float* c2b = alloc(416*16);
    unsigned short* Qbf = allocU((size_t)400*416);
    unsigned short* Pbf = allocU((size_t)400*416);
    float* dvec = alloc(512);
    float* bvec = alloc(512);
    float* wtd  = alloc(512);
    float* Gy   = alloc((size_t)SB_*400);
    float* Hacc = alloc((size_t)SB_*400);
    float* H1   = alloc((size_t)SB_*400);
    float* H2   = alloc((size_t)SB_*400);
    float* H3   = alloc((size_t)SB_*400);
    float* H4   = alloc((size_t)SB_*400);
    float* Hs   = alloc((size_t)SB_*400);
    float* rowm = alloc(1280);   // >= SB_
    float* rsum = alloc(1280);   // >= SB_
    float* partials = alloc((size_t)8*320000);
    unsigned short* Wih0p = allocU((size_t)4600*416);
    unsigned short* Whh0p = allocU((size_t)4600*1152);
    unsigned short* Wih1p = allocU((size_t)4600*1152);
    unsigned short* Whh1p = allocU((size_t)4600*1152);
    unsigned short* Wih2p = allocU((size_t)1600*1152);
    unsigned short* Whh2p = allocU((size_t)1600*416);
    unsigned short* Abf   = allocU((size_t)SB_*800);
    unsigned short* Bbf   = allocU((size_t)NT_*800);
    unsigned short* BbfT  = allocU((size_t)800*NT_);
    unsigned short* Wxbf  = allocU((size_t)400*NT_);
    (void)ws_size; (void)in_sizes; (void)n_in; (void)out_size;

    float* zout = (float*)d_out;

    hipMemsetAsync(Hacc, 0, (size_t)SB_*400*sizeof(float), stream);
    // zero pad-sensitive buffers once per call (MFMA reads pads; must not be NaN)
    hipMemsetAsync(ys0A, 0, (size_t)S_*16*1152*2, stream);
    hipMemsetAsync(ys1A, 0, (size_t)S_*16*1152*2, stream);
    hipMemsetAsync(h0b,  0, (size_t)2*16*1152*2, stream);
    hipMemsetAsync(h1b,  0, (size_t)2*16*1152*2, stream);
    hipMemsetAsync(h2b,  0, (size_t)2*16*416*2, stream);
    hipMemsetAsync(Qbf,  0, (size_t)400*416*2, stream);
    hipMemsetAsync(Pbf,  0, (size_t)400*416*2, stream);

    // weight conversions (bf16, K zero-padded)
    auto cvtgrid = [](long long n){ return (unsigned)((n + 255) / 256); };
    cvt_pack_w_k<<<cvtgrid((long long)4600*416),  256, 0, stream>>>(Wih0, Wih0p, 4600, 400, 416);
    cvt_pack_w_k<<<cvtgrid((long long)4600*1152), 256, 0, stream>>>(Whh0, Whh0p, 4600, 1150, 1152);
    cvt_pack_w_k<<<cvtgrid((long long)4600*1152), 256, 0, stream>>>(Wih1, Wih1p, 4600, 1150, 1152);
    cvt_pack_w_k<<<cvtgrid((long long)4600*1152), 256, 0, stream>>>(Whh1, Whh1p, 4600, 1150, 1152);
    cvt_pack_w_k<<<cvtgrid((long long)1600*1152), 256, 0, stream>>>(Wih2, Wih2p, 1600, 1150, 1152);
    cvt_pack_w_k<<<cvtgrid((long long)1600*416),  256, 0, stream>>>(Whh2, Whh2p, 1600, 400, 416);
    cvt_catB2_k<<<dim3(500, 25), 256, 0, stream>>>(decW, odeW2, Bbf, BbfT);
    cvt_wx_k<<<cvtgrid((long long)400*NT_), 256, 0, stream>>>(odeW1, Wxbf);

    // activations + state init
    embed_bf_k<<<S_, 256, 0, stream>>>(tokens, emb, x0A);
    cvt_h0_k<<<(16*1150+255)/256, 256, 0, stream>>>(h0_0, h0b, 1150, 1152);
    cvt_h0_k<<<(16*1150+255)/256, 256, 0, stream>>>(h0_1, h1b, 1150, 1152);
    cvt_h0_k<<<(16*400+255)/256,  256, 0, stream>>>(h0_2, h2b, 400, 416);
    transpose16_k<<<(1150*16+255)/256, 256, 0, stream>>>(c0_0, c0b, 1150);
    transpose16_k<<<(1150*16+255)/256, 256, 0, stream>>>(c0_1, c1b, 1150);
    transpose16_k<<<(400*16+255)/256,  256, 0, stream>>>(c0_2, c2b, 400);

    // 3-layer LSTM, layer-pipelined wavefront, MFMA, 16 waves (gate x k-quarter)
    for (int u = 0; u < S_ + 2; ++u)
        lstm_mfma_k<<<169, 1024, 0, stream>>>(u, x0A, ys0A, ys1A, x3,
            h0b, c0b, h1b, c1b, h2b, c2b,
            Wih0p, Whh0p, bih0, bhh0, Wih1p, Whh1p, bih1, bhh1, Wih2p, Whh2p, bih2, bhh2);

    // ODE factorization precompute: [Q|P] = Wx @ BbfT^T via MFMA, 8 K-slabs
    vecs_k<<<400, 256, 0, stream>>>(Wxbf, odeW1, decb, odeb2, dvec, bvec, wtd);
    gemm_odeT_k<<<dim3(7,4,8), 256, 0, stream>>>(Wxbf, BbfT, partials);
    reduce8bf_k<<<(320000+255)/256, 256, 0, stream>>>(partials, Qbf, Pbf);

    // G0 = x3 @ Q^T + dvec
    fused_small_mfma_k<<<dim3(7,18), 256, 0, stream>>>(x3, Qbf, nullptr, Gy,
        dvec, 1.f, nullptr, 0.f, nullptr, 1.f, 0);

    // RK4 in G-space, 2 steps, dt = 0.5
    const float dt = 0.5f;
    for (int n = 0; n < 2; ++n){
        float t0 = n * dt;
        stage1_k<<<SB_, 256, 0, stream>>>(Gy, H1, wtd, t0, odeb1);
        fused_small_mfma_k<<<dim3(7,18), 256, 0, stream>>>(H1, Pbf, Gy, H2,
            bvec, 0.25f, wtd, t0 + 0.25f, odeb1, 0.25f, 1);
        fused_small_mfma_k<<<dim3(7,18), 256, 0, stream>>>(H2, Pbf, Gy, H3,
            bvec, 0.25f, wtd, t0 + 0.25f, odeb1, 0.25f, 1);
        fused_small_mfma_k<<<dim3(7,18), 256, 0, stream>>>(H3, Pbf, Gy, H4,
            bvec, 0.5f, wtd, t0 + 0.5f, odeb1, 0.5f, 1);
        hs_k<<<((SB_*400)+255)/256, 256, 0, stream>>>(H1, H2, H3, H4, Hs, Hacc, SB_*400);
        if (n == 0)
            fused_small_mfma_k<<<dim3(7,18), 256, 0, stream>>>(Hs, Pbf, Gy, Gy,
                bvec, dt, nullptr, 0.f, nullptr, 1.f, 0);
    }

    // A-concat (x3|Hacc) -> bf16, MFMA decode (256x128 tiles), log-softmax in place
    cvt_catA_k<<<cvtgrid((long long)SB_*800), 256, 0, stream>>>(x3, Hacc, Abf);
    decode_mfma_k<<<dim3(250,5), 512, 0, stream>>>(Abf, Bbf, decb, odeb2, zout);
    rowred_k<<<SB_, 256, 0, stream>>>(zout, rowm, rsum);
    finalmap_k<<<dim3(32,SB_), 256, 0, stream>>>(zout, rowm, rsum);
}

// Round 7
// 2050.780 us; speedup vs baseline: 4.1945x; 1.0439x over previous
//
#include <hip/hip_runtime.h>
#include <math.h>

// Problem dims
constexpr int S_   = 70;
constexpr int B_   = 16;
constexpr int SB_  = 1120;     // S*B
constexpr int NT_  = 32000;    // NTOKEN
constexpr int W1S_ = 32001;    // odeW1 row stride (NTOKEN+1)

typedef __attribute__((ext_vector_type(8))) short bf16x8;
typedef __attribute__((ext_vector_type(4))) float f32x4;

__device__ __forceinline__ float sigm(float x){ return 1.f/(1.f+__expf(-x)); }
__device__ __forceinline__ float softplusf(float x){ return x > 15.f ? x : log1pf(__expf(x)); }

__device__ __forceinline__ unsigned short f2bf(float f){
    union{float f; unsigned u;} c; c.f = f;
    unsigned u = c.u;
    unsigned r = (u + 0x7fffu + ((u >> 16) & 1u)) >> 16;
    return (unsigned short)r;
}
__device__ __forceinline__ float bfu(unsigned short us){
    union{unsigned u; float f;} c; c.u = ((unsigned)us) << 16; return c.f;
}

// ---------------------------------------------------------------------------
// fp32 [R][K] -> bf16 [R][Kp], zero-padded in K
__global__ __launch_bounds__(256) void cvt_pack_w_k(const float* __restrict__ src,
                                                    unsigned short* __restrict__ dst,
                                                    int R, int K, int Kp)
{
    long long idx = (long long)blockIdx.x*256 + threadIdx.x;
    long long tot = (long long)R*Kp;
    if (idx >= tot) return;
    int r = (int)(idx / Kp), kk = (int)(idx - (long long)r*Kp);
    float v = (kk < K) ? src[(size_t)r*K + kk] : 0.f;
    dst[idx] = f2bf(v);
}

// Abf[1120][800]: k<400 -> x3[m][k], else Hacc[m][k-400]
__global__ __launch_bounds__(256) void cvt_catA_k(const float* __restrict__ x3,
                                                  const float* __restrict__ Hacc,
                                                  unsigned short* __restrict__ Abf)
{
    int idx = blockIdx.x*256 + threadIdx.x;
    if (idx >= SB_*800) return;
    int m = idx / 800, k = idx - m*800;
    float v = (k < 400) ? x3[(size_t)m*400 + k] : Hacc[(size_t)m*400 + (k-400)];
    Abf[idx] = f2bf(v);
}

// Fused: Bbf[32000][800] row-major AND BbfT[800][32000] transposed, single read.
__global__ __launch_bounds__(256) void cvt_catB2_k(const float* __restrict__ decW,
                                                   const float* __restrict__ odeW2,
                                                   unsigned short* __restrict__ Bbf,
                                                   unsigned short* __restrict__ BbfT)
{
    __shared__ unsigned short tile[32][72];
    int v0 = blockIdx.x*64, n0 = blockIdx.y*32;
    int tx = threadIdx.x & 31;        // n offset (load phase)
    int vy = threadIdx.x >> 5;        // 0..7
    #pragma unroll
    for (int i = 0; i < 8; ++i){
        int v = v0 + i*8 + vy;
        int n = n0 + tx;
        float val = (n < 400) ? decW[(size_t)v*400 + n] : odeW2[(size_t)v*400 + (n-400)];
        unsigned short us = f2bf(val);
        tile[tx][v - v0] = us;
        Bbf[(size_t)v*800 + n] = us;
    }
    __syncthreads();
    int vx = threadIdx.x & 63;
    int ny = threadIdx.x >> 6;        // 0..3
    #pragma unroll
    for (int i = 0; i < 8; ++i){
        int n = n0 + i*4 + ny;
        BbfT[(size_t)n*NT_ + v0 + vx] = tile[n - n0][vx];
    }
}

// Wxbf[400][32000] = bf16(odeW1[:,1:])
__global__ __launch_bounds__(256) void cvt_wx_k(const float* __restrict__ odeW1,
                                                unsigned short* __restrict__ Wxbf)
{
    long long idx = (long long)blockIdx.x*256 + threadIdx.x;
    if (idx >= (long long)400*NT_) return;
    int m = (int)(idx / NT_), v = (int)(idx - (long long)m*NT_);
    Wxbf[idx] = f2bf(odeW1[(size_t)m*W1S_ + 1 + v]);
}

// ---------------------------------------------------------------------------
// Embedding gather -> bf16 A-layout: x0A[t][b][k] (stride 416, zero-padded)
__global__ __launch_bounds__(256) void embed_bf_k(const int* __restrict__ tok,
                                                  const float* __restrict__ emb,
                                                  unsigned short* __restrict__ x0A)
{
    int t = blockIdx.x;
    __shared__ int tk[16];
    if (threadIdx.x < 16) tk[threadIdx.x] = tok[t*16 + threadIdx.x];
    __syncthreads();
    for (int idx = threadIdx.x; idx < 16*416; idx += 256){
        int b = idx / 416, k = idx - b*416;
        float v = (k < 400) ? emb[(size_t)tk[b]*400 + k] : 0.f;
        x0A[(size_t)t*16*416 + idx] = f2bf(v);
    }
}

// dst[j*16+b] = src[b*dh+j]  (c-state init)
__global__ __launch_bounds__(256) void transpose16_k(const float* __restrict__ src,
                                                     float* __restrict__ dst, int dh)
{
    int idx = blockIdx.x*256 + threadIdx.x;
    if (idx < dh*16){ int j = idx >> 4, b = idx & 15; dst[idx] = src[b*dh + j]; }
}

// h0 [16][Dh] fp32 -> hb [16][SA] bf16 (parity-0 buffer; pads pre-zeroed by memset)
__global__ __launch_bounds__(256) void cvt_h0_k(const float* __restrict__ h0,
                                                unsigned short* __restrict__ hb, int Dh, int SA)
{
    int idx = blockIdx.x*256 + threadIdx.x;
    if (idx >= 16*Dh) return;
    int b = idx / Dh, j = idx - b*Dh;
    hb[(size_t)b*SA + j] = f2bf(h0[idx]);
}

// ---------------------------------------------------------------------------
// K-segment dot with 4 accumulator chains (128 K per main iter, 8 loads in flight).
// Tails (rem in {32,64,96}) statically unrolled (no runtime-indexed reg arrays).
__device__ __forceinline__ void dotseg(const unsigned short* __restrict__ a,
                                       const unsigned short* __restrict__ b,
                                       int s, int e, int kq,
                                       f32x4& c0, f32x4& c1, f32x4& c2, f32x4& c3)
{
    int k0 = s;
    for (; k0 + 128 <= e; k0 += 128){
        bf16x8 a0 = *(const bf16x8*)(a + k0 + kq);
        bf16x8 b0 = *(const bf16x8*)(b + k0 + kq);
        bf16x8 a1 = *(const bf16x8*)(a + k0 + 32 + kq);
        bf16x8 b1 = *(const bf16x8*)(b + k0 + 32 + kq);
        bf16x8 a2 = *(const bf16x8*)(a + k0 + 64 + kq);
        bf16x8 b2 = *(const bf16x8*)(b + k0 + 64 + kq);
        bf16x8 a3 = *(const bf16x8*)(a + k0 + 96 + kq);
        bf16x8 b3 = *(const bf16x8*)(b + k0 + 96 + kq);
        c0 = __builtin_amdgcn_mfma_f32_16x16x32_bf16(a0, b0, c0, 0,0,0);
        c1 = __builtin_amdgcn_mfma_f32_16x16x32_bf16(a1, b1, c1, 0,0,0);
        c2 = __builtin_amdgcn_mfma_f32_16x16x32_bf16(a2, b2, c2, 0,0,0);
        c3 = __builtin_amdgcn_mfma_f32_16x16x32_bf16(a3, b3, c3, 0,0,0);
    }
    int rem = e - k0;
    if (rem >= 32){
        bf16x8 a0 = *(const bf16x8*)(a + k0 + kq);
        bf16x8 b0 = *(const bf16x8*)(b + k0 + kq);
        c0 = __builtin_amdgcn_mfma_f32_16x16x32_bf16(a0, b0, c0, 0,0,0);
    }
    if (rem >= 64){
        bf16x8 a1 = *(const bf16x8*)(a + k0 + 32 + kq);
        bf16x8 b1 = *(const bf16x8*)(b + k0 + 32 + kq);
        c1 = __builtin_amdgcn_mfma_f32_16x16x32_bf16(a1, b1, c1, 0,0,0);
    }
    if (rem >= 96){
        bf16x8 a2 = *(const bf16x8*)(a + k0 + 64 + kq);
        bf16x8 b2 = *(const bf16x8*)(b + k0 + 64 + kq);
        c2 = __builtin_amdgcn_mfma_f32_16x16x32_bf16(a2, b2, c2, 0,0,0);
    }
}

// One wavefront step of the 3-layer LSTM pipeline, MFMA, 4-way K-split.
// Block = one 16-unit j-tile; 16 waves = 4 gates x 4 K-quarters (1024 threads).
__global__ __launch_bounds__(1024) void lstm_mfma_k(int u,
    const unsigned short* __restrict__ x0A,
    unsigned short* __restrict__ ys0A, unsigned short* __restrict__ ys1A,
    float* __restrict__ x3,
    unsigned short* __restrict__ h0b, float* __restrict__ c0,
    unsigned short* __restrict__ h1b, float* __restrict__ c1,
    unsigned short* __restrict__ h2b, float* __restrict__ c2,
    const unsigned short* __restrict__ Wih0p, const unsigned short* __restrict__ Whh0p,
    const float* __restrict__ bih0, const float* __restrict__ bhh0,
    const unsigned short* __restrict__ Wih1p, const unsigned short* __restrict__ Whh1p,
    const float* __restrict__ bih1, const float* __restrict__ bhh1,
    const unsigned short* __restrict__ Wih2p, const unsigned short* __restrict__ Whh2p,
    const float* __restrict__ bih2, const float* __restrict__ bhh2)
{
    int blk = blockIdx.x;
    int layer, jt;
    if      (blk < 72) { layer = 0; jt = blk; }
    else if (blk < 144){ layer = 1; jt = blk - 72; }
    else               { layer = 2; jt = blk - 144; }
    int t = u - layer;
    if (t < 0 || t >= S_) return;
    int j0 = jt*16;

    const unsigned short *Ax, *Ah, *Wi, *Wh;
    const float *bih, *bhh;
    float *cst, *x3o = nullptr;
    unsigned short *yo = nullptr, *hrec;
    int Kx, Kh, Dh, SAx, SAh;
    if (layer == 0){
        Ax = x0A + (size_t)t*16*416; SAx = 416; Kx = 416;
        Ah = h0b + (size_t)(t&1)*16*1152; SAh = 1152; Kh = 1152;
        Wi = Wih0p; Wh = Whh0p; bih = bih0; bhh = bhh0; Dh = 1150;
        cst = c0; hrec = h0b + (size_t)((t+1)&1)*16*1152;
        yo = ys0A + (size_t)t*16*1152;
    } else if (layer == 1){
        Ax = ys0A + (size_t)t*16*1152; SAx = 1152; Kx = 1152;
        Ah = h1b + (size_t)(t&1)*16*1152; SAh = 1152; Kh = 1152;
        Wi = Wih1p; Wh = Whh1p; bih = bih1; bhh = bhh1; Dh = 1150;
        cst = c1; hrec = h1b + (size_t)((t+1)&1)*16*1152;
        yo = ys1A + (size_t)t*16*1152;
    } else {
        Ax = ys1A + (size_t)t*16*1152; SAx = 1152; Kx = 1152;
        Ah = h2b + (size_t)(t&1)*16*416; SAh = 416; Kh = 416;
        Wi = Wih2p; Wh = Whh2p; bih = bih2; bhh = bhh2; Dh = 400;
        cst = c2; hrec = h2b + (size_t)((t+1)&1)*16*416;
        x3o = x3 + (size_t)t*16*400;
    }

    int lane = threadIdx.x & 63, w = threadIdx.x >> 6;   // w = 0..15
    int gate = w & 3, kq4 = w >> 2;                      // gate, K-quarter
    int am = lane & 15;           // A row (batch)
    int kq = (lane >> 4) * 8;     // k offset within 32-step
    int jn = lane & 15;           // B row (local j)
    int jrow = j0 + jn; if (jrow > Dh-1) jrow = Dh-1;    // clamp (dup rows discarded on write)

    const unsigned short* ax = Ax + (size_t)am*SAx;
    const unsigned short* ah = Ah + (size_t)am*SAh;
    const unsigned short* wx = Wi + (size_t)(gate*Dh + jrow)*SAx;
    const unsigned short* wh = Wh + (size_t)(gate*Dh + jrow)*SAh;

    // K-quarter bounds (32-chunk granular)
    int nx = Kx >> 5, nh = Kh >> 5;
    int xq0 = ((nx *  kq4     ) >> 2) << 5;
    int xq1 = ((nx * (kq4 + 1)) >> 2) << 5;
    int hq0 = ((nh *  kq4     ) >> 2) << 5;
    int hq1 = ((nh * (kq4 + 1)) >> 2) << 5;

    f32x4 c0v = {0.f,0.f,0.f,0.f}, c1v = {0.f,0.f,0.f,0.f};
    f32x4 c2v = {0.f,0.f,0.f,0.f}, c3v = {0.f,0.f,0.f,0.f};
    dotseg(ax, wx, xq0, xq1, kq, c0v, c1v, c2v, c3v);
    dotseg(ah, wh, hq0, hq1, kq, c0v, c1v, c2v, c3v);
    f32x4 acc = (c0v + c1v) + (c2v + c3v);

    // C/D: row m = (lane>>4)*4 + r (batch), col = lane&15 (local j)
    __shared__ float g16[16][16][17];
    int bm = (lane >> 4) * 4;
    #pragma unroll
    for (int r = 0; r < 4; ++r) g16[w][bm + r][jn] = acc[r];
    __syncthreads();

    if (threadIdx.x < 256){
        int jl = threadIdx.x >> 4, b = threadIdx.x & 15;
        int j = j0 + jl;
        if (j < Dh){
            float pi = g16[0][b][jl] + g16[4][b][jl] + g16[8][b][jl]  + g16[12][b][jl] + bih[j]      + bhh[j];
            float pf = g16[1][b][jl] + g16[5][b][jl] + g16[9][b][jl]  + g16[13][b][jl] + bih[Dh+j]   + bhh[Dh+j];
            float pg = g16[2][b][jl] + g16[6][b][jl] + g16[10][b][jl] + g16[14][b][jl] + bih[2*Dh+j] + bhh[2*Dh+j];
            float po = g16[3][b][jl] + g16[7][b][jl] + g16[11][b][jl] + g16[15][b][jl] + bih[3*Dh+j] + bhh[3*Dh+j];
            float cold = cst[j*16 + b];
            float cnew = sigm(pf)*cold + sigm(pi)*tanhf(pg);
            float h    = sigm(po)*tanhf(cnew);
            cst[j*16 + b] = cnew;
            unsigned short hb16 = f2bf(h);
            hrec[(size_t)b*SAh + j] = hb16;
            if (yo)  yo[(size_t)b*1152 + j] = hb16;
            if (x3o) x3o[(size_t)b*400 + j] = h;
        }
    }
}

// ---------------------------------------------------------------------------
// dvec[j] = Wx[j,:]·decb ; bvec[j] = Wx[j,:]·b2 ; wtd[j] = odeW1[j,0]  (bf16 Wx read)
__global__ __launch_bounds__(256) void vecs_k(const unsigned short* __restrict__ Wxbf,
                                              const float* __restrict__ odeW1,
                                              const float* __restrict__ decb,
                                              const float* __restrict__ b2v,
                                              float* __restrict__ dvec,
                                              float* __restrict__ bvec,
                                              float* __restrict__ wtd)
{
    int jrow = blockIdx.x;
    __shared__ float r1[256], r2[256];
    const unsigned short* wx = Wxbf + (size_t)jrow*NT_;
    float s1 = 0.f, s2 = 0.f;
    for (int v = threadIdx.x; v < NT_; v += 256){
        float w = bfu(wx[v]); s1 += w*decb[v]; s2 += w*b2v[v];
    }
    r1[threadIdx.x] = s1; r2[threadIdx.x] = s2; __syncthreads();
    for (int s = 128; s > 0; s >>= 1){
        if (threadIdx.x < s){ r1[threadIdx.x] += r1[threadIdx.x+s]; r2[threadIdx.x] += r2[threadIdx.x+s]; }
        __syncthreads();
    }
    if (threadIdx.x == 0){ dvec[jrow] = r1[0]; bvec[jrow] = r2[0]; wtd[jrow] = odeW1[(size_t)jrow*W1S_]; }
}

// ---------------------------------------------------------------------------
// MFMA ODE precompute: partials[z][m*800+n] = sum_{v in slab z} Wxbf[m][v]*BbfT[n][v]
// 16 K-slabs of 2000 for occupancy (448 blocks).
__global__ __launch_bounds__(256) void gemm_odeT_k(
    const unsigned short* __restrict__ Wxbf,
    const unsigned short* __restrict__ BbfT,
    float* __restrict__ partials)
{
    __shared__ unsigned short As[128*40];
    __shared__ unsigned short Bs[128*40];
    int n0 = blockIdx.x*128, m0 = blockIdx.y*128, v0 = blockIdx.z*2000;
    int tid = threadIdx.x;
    int lane = tid & 63, wid = tid >> 6;
    int wr = wid >> 1, wc = wid & 1;
    f32x4 acc[4][4] = {};

    int srow = tid >> 1;
    int sk   = (tid & 1) * 16;
    int mL = m0 + srow; if (mL > 399) mL = 399;
    int nL = n0 + srow; if (nL > 799) nL = 799;
    const unsigned short* ap = Wxbf + (size_t)mL*NT_ + v0 + sk;
    const unsigned short* bp = BbfT + (size_t)nL*NT_ + v0 + sk;

    for (int k0 = 0; k0 < 2000; k0 += 32){
        uint4 av0 = *(const uint4*)(ap + k0);
        uint4 av1 = *(const uint4*)(ap + k0 + 8);
        uint4 bv0 = *(const uint4*)(bp + k0);
        uint4 bv1 = *(const uint4*)(bp + k0 + 8);

        __syncthreads();
        *(uint4*)&As[srow*40 + sk]     = av0;
        *(uint4*)&As[srow*40 + sk + 8] = av1;
        *(uint4*)&Bs[srow*40 + sk]     = bv0;
        *(uint4*)&Bs[srow*40 + sk + 8] = bv1;
        __syncthreads();

        int kq = (lane >> 4) * 8;
        int rA = wr*64 + (lane & 15);
        int rB = wc*64 + (lane & 15);
        bf16x8 af[4], bfv[4];
        #pragma unroll
        for (int f = 0; f < 4; ++f){
            af[f]  = *(const bf16x8*)&As[(rA + f*16)*40 + kq];
            bfv[f] = *(const bf16x8*)&Bs[(rB + f*16)*40 + kq];
        }
        #pragma unroll
        for (int fm = 0; fm < 4; ++fm)
            #pragma unroll
            for (int fn = 0; fn < 4; ++fn)
                acc[fm][fn] = __builtin_amdgcn_mfma_f32_16x16x32_bf16(af[fm], bfv[fn], acc[fm][fn], 0, 0, 0);
    }

    float* op = partials + (size_t)blockIdx.z*320000;
    int cm = (lane >> 4) * 4;
    int cn = lane & 15;
    #pragma unroll
    for (int fm = 0; fm < 4; ++fm){
        int mrow0 = m0 + wr*64 + fm*16 + cm;
        #pragma unroll
        for (int fn = 0; fn < 4; ++fn){
            int n = n0 + wc*64 + fn*16 + cn;
            if (n >= 800) continue;
            #pragma unroll
            for (int r = 0; r < 4; ++r){
                int mr = mrow0 + r;
                if (mr < 400) op[mr*800 + n] = acc[fm][fn][r];
            }
        }
    }
}

// sum 16 slabs; scatter to PADDED bf16: C[:,0:400]->Qbf[400][416], C[:,400:800]->Pbf[400][416]
__global__ __launch_bounds__(256) void reduce16bf_k(const float* __restrict__ p,
                                                    unsigned short* __restrict__ Qbf,
                                                    unsigned short* __restrict__ Pbf)
{
    int i = blockIdx.x*256 + threadIdx.x;
    if (i >= 320000) return;
    float s = 0.f;
    #pragma unroll
    for (int k = 0; k < 16; ++k) s += p[(size_t)k*320000 + i];
    int m = i / 800, n = i - m*800;
    if (n < 400) Qbf[m*416 + n] = f2bf(s);
    else         Pbf[m*416 + (n-400)] = f2bf(s);
}

// ---------------------------------------------------------------------------
// MFMA small GEMM: OUT[m,n] = maybe_sp( dotc*sum_k A[m,k]*Bb[n,k] + Gbase + vcoef*vec + tval*wt + b1 )
// A fp32 [SB_][400] converted on the fly; Bb bf16 [400][416] padded. 64x64 tiles, 4 waves of 32x32.
__global__ __launch_bounds__(256) void fused_small_mfma_k(
    const float* __restrict__ A, const unsigned short* __restrict__ Bb,
    const float* __restrict__ Gbase, float* __restrict__ OUT,
    const float* __restrict__ vec, float vcoef,
    const float* __restrict__ wt, float tval,
    const float* __restrict__ b1, float dotc, int do_sp)
{
    __shared__ unsigned short As[64*40];
    __shared__ unsigned short Bs[64*40];
    int m0 = blockIdx.y*64, n0 = blockIdx.x*64;
    int tid = threadIdx.x;
    int lane = tid & 63, wid = tid >> 6;
    int wr = wid >> 1, wc = wid & 1;          // 2x2 waves of 32x32
    f32x4 acc[2][2] = {};

    int rowL = tid >> 2;                       // 0..63
    int kL   = (tid & 3) * 8;                  // 0,8,16,24
    int mG = m0 + rowL;
    int nG = n0 + rowL;

    for (int k0 = 0; k0 < 416; k0 += 32){
        unsigned short a8[8];
        int kb = k0 + kL;
        if (mG < SB_ && kb + 8 <= 400){
            float4 u0 = *(const float4*)(A + (size_t)mG*400 + kb);
            float4 u1 = *(const float4*)(A + (size_t)mG*400 + kb + 4);
            a8[0]=f2bf(u0.x); a8[1]=f2bf(u0.y); a8[2]=f2bf(u0.z); a8[3]=f2bf(u0.w);
            a8[4]=f2bf(u1.x); a8[5]=f2bf(u1.y); a8[6]=f2bf(u1.z); a8[7]=f2bf(u1.w);
        } else {
            #pragma unroll
            for (int i = 0; i < 8; ++i){
                int k = kb + i;
                float v = (mG < SB_ && k < 400) ? A[(size_t)mG*400 + k] : 0.f;
                a8[i] = f2bf(v);
            }
        }
        uint4 bv = {0,0,0,0};
        if (nG < 400) bv = *(const uint4*)(Bb + (size_t)nG*416 + kb);
        __syncthreads();
        #pragma unroll
        for (int i = 0; i < 4; ++i)
            *(unsigned*)&As[rowL*40 + kL + 2*i] = (unsigned)a8[2*i] | ((unsigned)a8[2*i+1] << 16);
        *(uint4*)&Bs[rowL*40 + kL] = bv;
        __syncthreads();

        int kq = (lane >> 4) * 8;
        int rA = wr*32 + (lane & 15);
        int rB = wc*32 + (lane & 15);
        bf16x8 af[2], bfv[2];
        af[0]  = *(const bf16x8*)&As[(rA     )*40 + kq];
        af[1]  = *(const bf16x8*)&As[(rA + 16)*40 + kq];
        bfv[0] = *(const bf16x8*)&Bs[(rB     )*40 + kq];
        bfv[1] = *(const bf16x8*)&Bs[(rB + 16)*40 + kq];
        #pragma unroll
        for (int fm = 0; fm < 2; ++fm)
            #pragma unroll
            for (int fn = 0; fn < 2; ++fn)
                acc[fm][fn] = __builtin_amdgcn_mfma_f32_16x16x32_bf16(af[fm], bfv[fn], acc[fm][fn], 0, 0, 0);
    }

    int cm = (lane >> 4) * 4, cn = lane & 15;
    #pragma unroll
    for (int fm = 0; fm < 2; ++fm){
        #pragma unroll
        for (int fn = 0; fn < 2; ++fn){
            int n = n0 + wc*32 + fn*16 + cn;
            if (n >= 400) continue;
            #pragma unroll
            for (int r = 0; r < 4; ++r){
                int m = m0 + wr*32 + fm*16 + cm + r;
                if (m >= SB_) continue;
                float s = dotc*acc[fm][fn][r];
                if (Gbase) s += Gbase[(size_t)m*400 + n];
                if (vec)   s += vcoef*vec[n];
                if (wt)    s += tval*wt[n];
                if (b1)    s += b1[n];
                OUT[(size_t)m*400 + n] = do_sp ? softplusf(s) : s;
            }
        }
    }
}

// H = softplus(Gy + t*wt + b1)
__global__ __launch_bounds__(256) void stage1_k(const float* __restrict__ Gy, float* __restrict__ H,
                                                const float* __restrict__ wt, float tval,
                                                const float* __restrict__ b1)
{
    int sb = blockIdx.x;
    for (int n = threadIdx.x; n < 400; n += 256){
        float s = Gy[(size_t)sb*400 + n] + tval*wt[n] + b1[n];
        H[(size_t)sb*400 + n] = softplusf(s);
    }
}

// Hs = dt/6*(H1+2H2+2H3+H4); Hacc += Hs
__global__ __launch_bounds__(256) void hs_k(const float* __restrict__ H1, const float* __restrict__ H2,
                                            const float* __restrict__ H3, const float* __restrict__ H4,
                                            float* __restrict__ Hs, float* __restrict__ Hacc, int n)
{
    int i = blockIdx.x*256 + threadIdx.x;
    if (i < n){
        float v = (1.f/12.f)*(H1[i] + 2.f*H2[i] + 2.f*H3[i] + H4[i]);  // dt/6 = 0.5/6
        Hs[i] = v;
        Hacc[i] += v;
    }
}

// ---------------------------------------------------------------------------
// MFMA decode, 256x128 tiles (B streamed 5x; L3 covers after 1st m-wave):
// z[m,v] = Abf[m,:]·Bbf[v,:] + decb[v] + b2[v]   (M=1120,N=32000,K=800)
__global__ __launch_bounds__(512) void decode_mfma_k(
    const unsigned short* __restrict__ Abf,
    const unsigned short* __restrict__ Bbf,
    const float* __restrict__ decb, const float* __restrict__ b2v,
    float* __restrict__ z)
{
    __shared__ unsigned short As[256*40];
    __shared__ unsigned short Bs[128*40];
    int n0 = blockIdx.x*128, m0 = blockIdx.y*256;
    int tid = threadIdx.x;
    int lane = tid & 63, wid = tid >> 6;   // 8 waves
    int wr = wid >> 1, wc = wid & 1;       // 4 (M) x 2 (N), each 64x64
    f32x4 acc[4][4] = {};

    int srA = tid >> 1, skA = (tid & 1)*16;   // 256 rows x 32k
    int srB = tid >> 2, skB = (tid & 3)*8;    // 128 rows x 32k

    for (int k0 = 0; k0 < 800; k0 += 32){
        uint4 av0 = {0,0,0,0}, av1 = {0,0,0,0};
        int m = m0 + srA;
        if (m < SB_){
            const uint4* ap = (const uint4*)(Abf + (size_t)m*800 + k0 + skA);
            av0 = ap[0]; av1 = ap[1];
        }
        uint4 bv = *(const uint4*)(Bbf + (size_t)(n0 + srB)*800 + k0 + skB);

        __syncthreads();
        *(uint4*)&As[srA*40 + skA]     = av0;
        *(uint4*)&As[srA*40 + skA + 8] = av1;
        *(uint4*)&Bs[srB*40 + skB]     = bv;
        __syncthreads();

        int kq = (lane >> 4) * 8;
        int rA = wr*64 + (lane & 15);
        int rB = wc*64 + (lane & 15);
        bf16x8 af[4], bfv[4];
        #pragma unroll
        for (int f = 0; f < 4; ++f){
            af[f]  = *(const bf16x8*)&As[(rA + f*16)*40 + kq];
            bfv[f] = *(const bf16x8*)&Bs[(rB + f*16)*40 + kq];
        }
        #pragma unroll
        for (int fm = 0; fm < 4; ++fm)
            #pragma unroll
            for (int fn = 0; fn < 4; ++fn)
                acc[fm][fn] = __builtin_amdgcn_mfma_f32_16x16x32_bf16(af[fm], bfv[fn], acc[fm][fn], 0, 0, 0);
    }

    int cm = (lane >> 4) * 4;
    int cn = lane & 15;
    #pragma unroll
    for (int fm = 0; fm < 4; ++fm){
        int mrow0 = m0 + wr*64 + fm*16 + cm;
        #pragma unroll
        for (int fn = 0; fn < 4; ++fn){
            int n = n0 + wc*64 + fn*16 + cn;
            float db = decb[n] + b2v[n];
            #pragma unroll
            for (int r = 0; r < 4; ++r){
                int mr = mrow0 + r;
                if (mr < SB_) z[(size_t)mr*NT_ + n] = acc[fm][fn][r] + db;
            }
        }
    }
}

// ---------------------------------------------------------------------------
// Fused log-softmax: row resident in registers (8x guarded float4 per thread).
// One read pass + one write pass (vs rowred+finalmap's 2 reads + 1 write).
__global__ __launch_bounds__(1024) void softmax_k(float* __restrict__ z)
{
    int r = blockIdx.x;
    float* zr = z + (size_t)r*NT_;
    int tid = threadIdx.x;
    __shared__ float sm[1024];
    float4 v[8];
    float mx = -1e30f;
    #pragma unroll
    for (int i = 0; i < 8; ++i){
        int base = i*4096 + tid*4;
        if (base < NT_){
            v[i] = *(const float4*)(zr + base);
            mx = fmaxf(mx, fmaxf(fmaxf(v[i].x, v[i].y), fmaxf(v[i].z, v[i].w)));
        } else {
            v[i].x = v[i].y = v[i].z = v[i].w = 0.f;
        }
    }
    sm[tid] = mx; __syncthreads();
    for (int s = 512; s > 0; s >>= 1){
        if (tid < s) sm[tid] = fmaxf(sm[tid], sm[tid+s]);
        __syncthreads();
    }
    mx = sm[0]; __syncthreads();
    float sum = 0.f;
    #pragma unroll
    for (int i = 0; i < 8; ++i){
        int base = i*4096 + tid*4;
        if (base < NT_){
            sum += __expf(v[i].x - mx) + __expf(v[i].y - mx)
                 + __expf(v[i].z - mx) + __expf(v[i].w - mx);
        }
    }
    sm[tid] = sum; __syncthreads();
    for (int s = 512; s > 0; s >>= 1){
        if (tid < s) sm[tid] += sm[tid+s];
        __syncthreads();
    }
    float sinv = 1.f / sm[0];
    #pragma unroll
    for (int i = 0; i < 8; ++i){
        int base = i*4096 + tid*4;
        if (base < NT_){
            float4 o;
            o.x = logf(__expf(v[i].x - mx)*sinv + 1e-8f);
            o.y = logf(__expf(v[i].y - mx)*sinv + 1e-8f);
            o.z = logf(__expf(v[i].z - mx)*sinv + 1e-8f);
            o.w = logf(__expf(v[i].w - mx)*sinv + 1e-8f);
            *(float4*)(zr + base) = o;
        }
    }
}

// ---------------------------------------------------------------------------
extern "C" void kernel_launch(void* const* d_in, const int* in_sizes, int n_in,
                              void* d_out, int out_size, void* d_ws, size_t ws_size,
                              hipStream_t stream)
{
    const int*   tokens = (const int*)  d_in[0];
    const float* h0_0 = (const float*)d_in[1];
    const float* c0_0 = (const float*)d_in[2];
    const float* Wih0 = (const float*)d_in[3];
    const float* Whh0 = (const float*)d_in[4];
    const float* bih0 = (const float*)d_in[5];
    const float* bhh0 = (const float*)d_in[6];
    const float* h0_1 = (const float*)d_in[7];
    const float* c0_1 = (const float*)d_in[8];
    const float* Wih1 = (const float*)d_in[9];
    const float* Whh1 = (const float*)d_in[10];
    const float* bih1 = (const float*)d_in[11];
    const float* bhh1 = (const float*)d_in[12];
    const float* h0_2 = (const float*)d_in[13];
    const float* c0_2 = (const float*)d_in[14];
    const float* Wih2 = (const float*)d_in[15];
    const float* Whh2 = (const float*)d_in[16];
    const float* bih2 = (const float*)d_in[17];
    const float* bhh2 = (const float*)d_in[18];
    const float* emb  = (const float*)d_in[19];
    const float* decW = (const float*)d_in[20];
    const float* decb = (const float*)d_in[21];
    const float* odeW1= (const float*)d_in[22];
    const float* odeb1= (const float*)d_in[23];
    const float* odeW2= (const float*)d_in[24];
    const float* odeb2= (const float*)d_in[25];

    // workspace carve-up (~215 MB), all chunks 16B-aligned
    float* w = (float*)d_ws;
    size_t off = 0;
    auto alloc = [&](size_t n){ float* p = w + off; off += n; return p; };
    auto allocU = [&](size_t nUsh){ return (unsigned short*)alloc(nUsh/2); };  // nUsh mult of 8
    unsigned short* x0A  = allocU((size_t)S_*16*416);
    unsigned short* ys0A = allocU((size_t)S_*16*1152);
    unsigned short* ys1A = allocU((size_t)S_*16*1152);
    float* x3   = alloc((size_t)SB_*400);
    unsigned short* h0b = allocU((size_t)2*16*1152); float* c0b = alloc(1152*16);
    unsigned short* h1b = allocU((size_t)2*16*1152); float* c1b = alloc(1152*16);
    unsigned short* h2b = allocU((size_t)2*16*416);  float* c2b = alloc(416*16);
    unsigned short* Qbf = allocU((size_t)400*416);
    unsigned short* Pbf = allocU((size_t)400*416);
    float* dvec = alloc(512);
    float* bvec = alloc(512);
    float* wtd  = alloc(512);
    float* Gy   = alloc((size_t)SB_*400);
    float* Hacc = alloc((size_t)SB_*400);
    float* H1   = alloc((size_t)SB_*400);
    float* H2   = alloc((size_t)SB_*400);
    float* H3   = alloc((size_t)SB_*400);
    float* H4   = alloc((size_t)SB_*400);
    float* Hs   = alloc((size_t)SB_*400);
    float* partials = alloc((size_t)16*320000);
    unsigned short* Wih0p = allocU((size_t)4600*416);
    unsigned short* Whh0p = allocU((size_t)4600*1152);
    unsigned short* Wih1p = allocU((size_t)4600*1152);
    unsigned short* Whh1p = allocU((size_t)4600*1152);
    unsigned short* Wih2p = allocU((size_t)1600*1152);
    unsigned short* Whh2p = allocU((size_t)1600*416);
    unsigned short* Abf   = allocU((size_t)SB_*800);
    unsigned short* Bbf   = allocU((size_t)NT_*800);
    unsigned short* BbfT  = allocU((size_t)800*NT_);
    unsigned short* Wxbf  = allocU((size_t)400*NT_);
    (void)ws_size; (void)in_sizes; (void)n_in; (void)out_size;

    float* zout = (float*)d_out;

    hipMemsetAsync(Hacc, 0, (size_t)SB_*400*sizeof(float), stream);
    // zero pad-sensitive buffers once per call (MFMA reads pads; must not be NaN)
    hipMemsetAsync(ys0A, 0, (size_t)S_*16*1152*2, stream);
    hipMemsetAsync(ys1A, 0, (size_t)S_*16*1152*2, stream);
    hipMemsetAsync(h0b,  0, (size_t)2*16*1152*2, stream);
    hipMemsetAsync(h1b,  0, (size_t)2*16*1152*2, stream);
    hipMemsetAsync(h2b,  0, (size_t)2*16*416*2, stream);
    hipMemsetAsync(Qbf,  0, (size_t)400*416*2, stream);
    hipMemsetAsync(Pbf,  0, (size_t)400*416*2, stream);

    // weight conversions (bf16, K zero-padded)
    auto cvtgrid = [](long long n){ return (unsigned)((n + 255) / 256); };
    cvt_pack_w_k<<<cvtgrid((long long)4600*416),  256, 0, stream>>>(Wih0, Wih0p, 4600, 400, 416);
    cvt_pack_w_k<<<cvtgrid((long long)4600*1152), 256, 0, stream>>>(Whh0, Whh0p, 4600, 1150, 1152);
    cvt_pack_w_k<<<cvtgrid((long long)4600*1152), 256, 0, stream>>>(Wih1, Wih1p, 4600, 1150, 1152);
    cvt_pack_w_k<<<cvtgrid((long long)4600*1152), 256, 0, stream>>>(Whh1, Whh1p, 4600, 1150, 1152);
    cvt_pack_w_k<<<cvtgrid((long long)1600*1152), 256, 0, stream>>>(Wih2, Wih2p, 1600, 1150, 1152);
    cvt_pack_w_k<<<cvtgrid((long long)1600*416),  256, 0, stream>>>(Whh2, Whh2p, 1600, 400, 416);
    cvt_catB2_k<<<dim3(500, 25), 256, 0, stream>>>(decW, odeW2, Bbf, BbfT);
    cvt_wx_k<<<cvtgrid((long long)400*NT_), 256, 0, stream>>>(odeW1, Wxbf);

    // activations + state init
    embed_bf_k<<<S_, 256, 0, stream>>>(tokens, emb, x0A);
    cvt_h0_k<<<(16*1150+255)/256, 256, 0, stream>>>(h0_0, h0b, 1150, 1152);
    cvt_h0_k<<<(16*1150+255)/256, 256, 0, stream>>>(h0_1, h1b, 1150, 1152);
    cvt_h0_k<<<(16*400+255)/256,  256, 0, stream>>>(h0_2, h2b, 400, 416);
    transpose16_k<<<(1150*16+255)/256, 256, 0, stream>>>(c0_0, c0b, 1150);
    transpose16_k<<<(1150*16+255)/256, 256, 0, stream>>>(c0_1, c1b, 1150);
    transpose16_k<<<(400*16+255)/256,  256, 0, stream>>>(c0_2, c2b, 400);

    // 3-layer LSTM, layer-pipelined wavefront, MFMA, 16 waves (gate x k-quarter)
    for (int u = 0; u < S_ + 2; ++u)
        lstm_mfma_k<<<169, 1024, 0, stream>>>(u, x0A, ys0A, ys1A, x3,
            h0b, c0b, h1b, c1b, h2b, c2b,
            Wih0p, Whh0p, bih0, bhh0, Wih1p, Whh1p, bih1, bhh1, Wih2p, Whh2p, bih2, bhh2);

    // ODE factorization precompute: [Q|P] = Wx @ BbfT^T via MFMA, 16 K-slabs
    vecs_k<<<400, 256, 0, stream>>>(Wxbf, odeW1, decb, odeb2, dvec, bvec, wtd);
    gemm_odeT_k<<<dim3(7,4,16), 256, 0, stream>>>(Wxbf, BbfT, partials);
    reduce16bf_k<<<(320000+255)/256, 256, 0, stream>>>(partials, Qbf, Pbf);

    // G0 = x3 @ Q^T + dvec
    fused_small_mfma_k<<<dim3(7,18), 256, 0, stream>>>(x3, Qbf, nullptr, Gy,
        dvec, 1.f, nullptr, 0.f, nullptr, 1.f, 0);

    // RK4 in G-space, 2 steps, dt = 0.5
    const float dt = 0.5f;
    for (int n = 0; n < 2; ++n){
        float t0 = n * dt;
        stage1_k<<<SB_, 256, 0, stream>>>(Gy, H1, wtd, t0, odeb1);
        fused_small_mfma_k<<<dim3(7,18), 256, 0, stream>>>(H1, Pbf, Gy, H2,
            bvec, 0.25f, wtd, t0 + 0.25f, odeb1, 0.25f, 1);
        fused_small_mfma_k<<<dim3(7,18), 256, 0, stream>>>(H2, Pbf, Gy, H3,
            bvec, 0.25f, wtd, t0 + 0.25f, odeb1, 0.25f, 1);
        fused_small_mfma_k<<<dim3(7,18), 256, 0, stream>>>(H3, Pbf, Gy, H4,
            bvec, 0.5f, wtd, t0 + 0.5f, odeb1, 0.5f, 1);
        hs_k<<<((SB_*400)+255)/256, 256, 0, stream>>>(H1, H2, H3, H4, Hs, Hacc, SB_*400);
        if (n == 0)
            fused_small_mfma_k<<<dim3(7,18), 256, 0, stream>>>(Hs, Pbf, Gy, Gy,
                bvec, dt, nullptr, 0.f, nullptr, 1.f, 0);
    }

    // A-concat (x3|Hacc) -> bf16, MFMA decode (256x128 tiles), fused log-softmax
    cvt_catA_k<<<cvtgrid((long long)SB_*800), 256, 0, stream>>>(x3, Hacc, Abf);
    decode_mfma_k<<<dim3(250,5), 512, 0, stream>>>(Abf, Bbf, decb, odeb2, zout);
    softmax_k<<<SB_, 1024, 0, stream>>>(zout);
}